// Round 1
// baseline (26982.043 us; speedup 1.0000x reference)
//
#include <hip/hip_runtime.h>
#include <math.h>
#include <limits.h>

typedef long long ll;

#define MAXCHAIN 4096
#define MAXP 49152
#define MAXOPS 49152
#define MAXR 64
#define PART_OFF 4096
#define CHAINS_OFF 16384
#define PEAKS_OFF (CHAINS_OFF + 128 * MAXCHAIN * 4)
#define OPS_OFF (PEAKS_OFF + MAXP * 4)

static __device__ const double TWOPI = 6.283185307179586;

struct Ctrl {
  double gpeak, max_w, ps64;
  long long k_rem, tail;
  float mean32, median_raw, md32, minv_scaled32;
  unsigned amax_bits, minf0_bits, prefix;
  int cnt_pos, shift, n_starts, n_ends, nregions, n_peaks, n_ops;
  int hist[256];
  int region_start[MAXR], region_end[MAXR];
  int chain_cnt[128];
  int chain_off[129];
};

// ---------- exact-arith helpers (no FMA contraction) ----------
__device__ __forceinline__ double dmul(double a, double b) { return __dmul_rn(a, b); }
__device__ __forceinline__ double dadd(double a, double b) { return __dadd_rn(a, b); }
__device__ __forceinline__ double dsub(double a, double b) { return __dadd_rn(a, -b); }
__device__ __forceinline__ float fmul(float a, float b) { return __fmul_rn(a, b); }
__device__ __forceinline__ float fadd(float a, float b) { return __fadd_rn(a, b); }
__device__ __forceinline__ float fsub(float a, float b) { return __fadd_rn(a, -b); }

__device__ __forceinline__ float xval(const float* snd, float mean, ll t) {
  return fsub(snd[t], mean);
}

// f0 = linear interp of pitch, computed exactly as numpy (f64 ops, one f32 round)
__device__ float f0_at(const float* pitch, ll t, ll S, double ratio) {
  double pos = dsub(dmul(dadd((double)t, 0.5), ratio), 0.5);
  double hi = (double)(S - 1);
  pos = fmin(fmax(pos, 0.0), hi);
  double fl = floor(pos);
  ll lo = (ll)fl;
  if (lo < 0) lo = 0;
  if (lo > S - 1) lo = S - 1;
  ll hii = lo + 1; if (hii > S - 1) hii = S - 1;
  double frac = dsub(pos, fl);
  double om = dsub(1.0, frac);
  double v = dadd(dmul((double)pitch[lo], om), dmul((double)pitch[hii], frac));
  return (float)v;
}

__device__ __forceinline__ float f0s_at(const float* pitch, ll t, ll S, double ratio,
                                        float psv, float prv, float md32) {
  float f = f0_at(pitch, t, S, ratio);
  float u = fmul(f, psv);                       // f0 * pitch_shift  (f32, like numpy)
  if (!(u > 0.0f)) return 0.0f;
  return fadd(md32, fmul(fsub(u, md32), prv));  // median + (f0-median)*pitch_range
}

// numpy pairwise sum of squares of x[base..base+n) -- exact replication
__device__ float pw_sq(const float* snd, float mean, ll base, int n) {
  if (n <= 128) {
    if (n < 8) {
      float res = 0.0f;
      for (int i = 0; i < n; ++i) { float x = xval(snd, mean, base + i); res = fadd(res, fmul(x, x)); }
      return res;
    }
    float x0 = xval(snd, mean, base + 0), x1 = xval(snd, mean, base + 1),
          x2 = xval(snd, mean, base + 2), x3 = xval(snd, mean, base + 3),
          x4 = xval(snd, mean, base + 4), x5 = xval(snd, mean, base + 5),
          x6 = xval(snd, mean, base + 6), x7 = xval(snd, mean, base + 7);
    float r0 = fmul(x0, x0), r1 = fmul(x1, x1), r2 = fmul(x2, x2), r3 = fmul(x3, x3);
    float r4 = fmul(x4, x4), r5 = fmul(x5, x5), r6 = fmul(x6, x6), r7 = fmul(x7, x7);
    int i = 8, lim = n - (n & 7);
    for (; i < lim; i += 8) {
      float y;
      y = xval(snd, mean, base + i + 0); r0 = fadd(r0, fmul(y, y));
      y = xval(snd, mean, base + i + 1); r1 = fadd(r1, fmul(y, y));
      y = xval(snd, mean, base + i + 2); r2 = fadd(r2, fmul(y, y));
      y = xval(snd, mean, base + i + 3); r3 = fadd(r3, fmul(y, y));
      y = xval(snd, mean, base + i + 4); r4 = fadd(r4, fmul(y, y));
      y = xval(snd, mean, base + i + 5); r5 = fadd(r5, fmul(y, y));
      y = xval(snd, mean, base + i + 6); r6 = fadd(r6, fmul(y, y));
      y = xval(snd, mean, base + i + 7); r7 = fadd(r7, fmul(y, y));
    }
    float res = fadd(fadd(fadd(r0, r1), fadd(r2, r3)), fadd(fadd(r4, r5), fadd(r6, r7)));
    for (; i < n; ++i) { float y = xval(snd, mean, base + i); res = fadd(res, fmul(y, y)); }
    return res;
  }
  int n2 = (n >> 1); n2 -= (n2 & 7);
  float a = pw_sq(snd, mean, base, n2);
  float b = pw_sq(snd, mean, base + n2, n - n2);
  return fadd(a, b);
}

// BLAS-sgemv mimic: 8-lane f32 FMA accumulation, pairwise combine.
__device__ float dot_mimic(const float* snd, float mean, ll sb, float divr,
                           const float* tN, int w) {
  float a0 = 0.f, a1 = 0.f, a2 = 0.f, a3 = 0.f, a4 = 0.f, a5 = 0.f, a6 = 0.f, a7 = 0.f;
  int k = 0;
  for (; k + 8 <= w; k += 8) {
    a0 = __fmaf_rn(__fdiv_rn(xval(snd, mean, sb + k + 0), divr), tN[k + 0], a0);
    a1 = __fmaf_rn(__fdiv_rn(xval(snd, mean, sb + k + 1), divr), tN[k + 1], a1);
    a2 = __fmaf_rn(__fdiv_rn(xval(snd, mean, sb + k + 2), divr), tN[k + 2], a2);
    a3 = __fmaf_rn(__fdiv_rn(xval(snd, mean, sb + k + 3), divr), tN[k + 3], a3);
    a4 = __fmaf_rn(__fdiv_rn(xval(snd, mean, sb + k + 4), divr), tN[k + 4], a4);
    a5 = __fmaf_rn(__fdiv_rn(xval(snd, mean, sb + k + 5), divr), tN[k + 5], a5);
    a6 = __fmaf_rn(__fdiv_rn(xval(snd, mean, sb + k + 6), divr), tN[k + 6], a6);
    a7 = __fmaf_rn(__fdiv_rn(xval(snd, mean, sb + k + 7), divr), tN[k + 7], a7);
  }
  if (k + 0 < w) a0 = __fmaf_rn(__fdiv_rn(xval(snd, mean, sb + k + 0), divr), tN[k + 0], a0);
  if (k + 1 < w) a1 = __fmaf_rn(__fdiv_rn(xval(snd, mean, sb + k + 1), divr), tN[k + 1], a1);
  if (k + 2 < w) a2 = __fmaf_rn(__fdiv_rn(xval(snd, mean, sb + k + 2), divr), tN[k + 2], a2);
  if (k + 3 < w) a3 = __fmaf_rn(__fdiv_rn(xval(snd, mean, sb + k + 3), divr), tN[k + 3], a3);
  if (k + 4 < w) a4 = __fmaf_rn(__fdiv_rn(xval(snd, mean, sb + k + 4), divr), tN[k + 4], a4);
  if (k + 5 < w) a5 = __fmaf_rn(__fdiv_rn(xval(snd, mean, sb + k + 5), divr), tN[k + 5], a5);
  if (k + 6 < w) a6 = __fmaf_rn(__fdiv_rn(xval(snd, mean, sb + k + 6), divr), tN[k + 6], a6);
  return fadd(fadd(fadd(a0, a1), fadd(a2, a3)), fadd(fadd(a4, a5), fadd(a6, a7)));
}

// ---------- kernels ----------
__global__ void k_init(char* wsb) {
  Ctrl* c = (Ctrl*)wsb;
  int t = threadIdx.x;
  for (int b = t; b < 256; b += blockDim.x) c->hist[b] = 0;
  for (int b = t; b < 128; b += blockDim.x) c->chain_cnt[b] = 0;
  if (t == 0) {
    c->amax_bits = 0u; c->minf0_bits = 0xFFFFFFFFu;
    c->cnt_pos = 0; c->n_starts = 0; c->n_ends = 0; c->n_ops = 0;
    c->nregions = 0; c->n_peaks = 0; c->tail = 0;
  }
}

__global__ void k_sum_partial(const float* __restrict__ snd, ll T, char* wsb) {
  __shared__ double sd[256];
  double local = 0.0;
  ll stride = (ll)gridDim.x * blockDim.x;
  for (ll t = (ll)blockIdx.x * blockDim.x + threadIdx.x; t < T; t += stride)
    local += (double)snd[t];
  sd[threadIdx.x] = local; __syncthreads();
  for (int o = 128; o > 0; o >>= 1) {
    if ((int)threadIdx.x < o) sd[threadIdx.x] += sd[threadIdx.x + o];
    __syncthreads();
  }
  if (threadIdx.x == 0) ((double*)(wsb + PART_OFF))[blockIdx.x] = sd[0];
}

__global__ void k_sum_final(char* wsb, ll T, int nparts) {
  __shared__ double sd[256];
  double local = 0.0;
  const double* p = (const double*)(wsb + PART_OFF);
  for (int i = threadIdx.x; i < nparts; i += blockDim.x) local += p[i];
  sd[threadIdx.x] = local; __syncthreads();
  for (int o = 128; o > 0; o >>= 1) {
    if ((int)threadIdx.x < o) sd[threadIdx.x] += sd[threadIdx.x + o];
    __syncthreads();
  }
  if (threadIdx.x == 0) ((Ctrl*)wsb)->mean32 = (float)(sd[0] / (double)T);
}

__global__ void k_scan(const float* __restrict__ snd, const float* __restrict__ pitch,
                       ll T, ll S, double ratio, char* wsb) {
  Ctrl* c = (Ctrl*)wsb;
  float mean = c->mean32;
  __shared__ unsigned smax[256]; __shared__ unsigned smin[256]; __shared__ int scnt[256];
  unsigned mymax = 0u, mymin = 0xFFFFFFFFu; int mycnt = 0;
  ll stride = (ll)gridDim.x * blockDim.x;
  for (ll t = (ll)blockIdx.x * blockDim.x + threadIdx.x; t < T; t += stride) {
    float xv = xval(snd, mean, t);
    unsigned ab = __float_as_uint(fabsf(xv));
    if (ab > mymax) mymax = ab;
    float f = f0_at(pitch, t, S, ratio);
    bool pos = (f > 0.0f);
    if (pos) { ++mycnt; unsigned fb = __float_as_uint(f); if (fb < mymin) mymin = fb; }
    if (t >= 1) {
      float fp = f0_at(pitch, t - 1, S, ratio);
      bool posp = (fp > 0.0f);
      if (pos && (t == 1 || !posp)) {
        int id = atomicAdd(&c->n_starts, 1);
        if (id < MAXR) c->region_start[id] = (int)t;
      }
      if (!pos && posp && (t - 1) >= 1) {
        int id = atomicAdd(&c->n_ends, 1);
        if (id < MAXR) c->region_end[id] = (int)t;
      }
    }
    if (t == T - 1 && pos) {
      int id = atomicAdd(&c->n_ends, 1);
      if (id < MAXR) c->region_end[id] = (int)T;
    }
  }
  smax[threadIdx.x] = mymax; smin[threadIdx.x] = mymin; scnt[threadIdx.x] = mycnt;
  __syncthreads();
  for (int o = 128; o > 0; o >>= 1) {
    if ((int)threadIdx.x < o) {
      if (smax[threadIdx.x + o] > smax[threadIdx.x]) smax[threadIdx.x] = smax[threadIdx.x + o];
      if (smin[threadIdx.x + o] < smin[threadIdx.x]) smin[threadIdx.x] = smin[threadIdx.x + o];
      scnt[threadIdx.x] += scnt[threadIdx.x + o];
    }
    __syncthreads();
  }
  if (threadIdx.x == 0) {
    atomicMax(&c->amax_bits, smax[0]);
    atomicMin(&c->minf0_bits, smin[0]);
    atomicAdd(&c->cnt_pos, scnt[0]);
  }
}

__global__ void k_prep(char* wsb, const float* ps) {
  Ctrl* c = (Ctrl*)wsb;
  int ns = c->n_starts; if (ns > MAXR) ns = MAXR;
  int ne = c->n_ends; if (ne > MAXR) ne = MAXR;
  for (int a = 1; a < ns; ++a) {
    int v = c->region_start[a]; int b = a - 1;
    while (b >= 0 && c->region_start[b] > v) { c->region_start[b + 1] = c->region_start[b]; --b; }
    c->region_start[b + 1] = v;
  }
  for (int a = 1; a < ne; ++a) {
    int v = c->region_end[a]; int b = a - 1;
    while (b >= 0 && c->region_end[b] > v) { c->region_end[b + 1] = c->region_end[b]; --b; }
    c->region_end[b + 1] = v;
  }
  int nr = ns < ne ? ns : ne;
  c->nregions = nr;
  c->tail = (nr > 0) ? (ll)c->region_end[nr - 1] : 0;
  c->gpeak = (double)__uint_as_float(c->amax_bits);
  ll cnt = (ll)c->cnt_pos; if (cnt < 1) cnt = 1;
  c->k_rem = (cnt - 1) / 2;
  c->prefix = 0u; c->shift = 24;
  // snap f32 scalar back to the original python f64 (e.g. 1.2f -> 1.2)
  double p64 = (double)ps[0];
  c->ps64 = round(p64 * 1e7) / 1e7;
}

__global__ void k_hist(const float* __restrict__ pitch, ll T, ll S, double ratio, char* wsb) {
  Ctrl* c = (Ctrl*)wsb;
  __shared__ int h[256];
  for (int b = threadIdx.x; b < 256; b += blockDim.x) h[b] = 0;
  __syncthreads();
  int shift = c->shift;
  unsigned pref = c->prefix;
  unsigned himask = (shift == 24) ? 0u : ((~0u) << (shift + 8));
  ll stride = (ll)gridDim.x * blockDim.x;
  for (ll t = (ll)blockIdx.x * blockDim.x + threadIdx.x; t < T; t += stride) {
    float f = f0_at(pitch, t, S, ratio);
    if (f > 0.0f) {
      unsigned bits = __float_as_uint(f);
      if ((bits & himask) == (pref & himask)) atomicAdd(&h[(bits >> shift) & 255], 1);
    }
  }
  __syncthreads();
  for (int b = threadIdx.x; b < 256; b += blockDim.x) if (h[b]) atomicAdd(&c->hist[b], h[b]);
}

__global__ void k_sel(char* wsb, const float* ps, const float* pr) {
  Ctrl* c = (Ctrl*)wsb;
  int shift = c->shift;
  ll k = c->k_rem;
  ll run = 0; int pick = 255;
  for (int b = 0; b < 256; ++b) {
    ll h = (ll)c->hist[b];
    if (run + h > k) { pick = b; break; }
    run += h;
  }
  c->prefix |= ((unsigned)pick) << shift;
  c->k_rem = k - run;
  for (int b = 0; b < 256; ++b) c->hist[b] = 0;
  if (shift == 0) {
    float mraw = __uint_as_float(c->prefix);
    c->median_raw = mraw;
    double md = dmul((double)mraw, c->ps64);     // float(v) * pitch_shift  (f64)
    float md32 = (float)md;
    c->md32 = md32;
    float minf = __uint_as_float(c->minf0_bits); // min over unscaled positives
    float u = fmul(minf, ps[0]);
    float sc = fadd(md32, fmul(fsub(u, md32), pr[0])); // monotone -> scaled min
    c->minv_scaled32 = sc;
    c->max_w = 20000.0 / (double)sc;             // 1.25 * 16000 / float(min)
  }
  c->shift = shift - 8;
}

#define WALK_MAXI 400000

__global__ __launch_bounds__(64) void k_walks(const float* __restrict__ snd,
                                              const float* __restrict__ pitch,
                                              ll T, ll S, double ratio, char* wsb) {
  Ctrl* c = (Ctrl*)wsb;
  int chain = blockIdx.x;
  int reg = chain >> 1, dir = chain & 1;  // dir 0 = left walk, 1 = right walk
  if (reg >= c->nregions) return;
  int* mybuf = ((int*)(wsb + CHAINS_OFF)) + (ll)chain * MAXCHAIN;
  ll left = (ll)c->region_start[reg];
  ll right = (ll)c->region_end[reg];
  float mean = c->mean32;
  double gpeak = c->gpeak;
  int tid = threadIdx.x;

  __shared__ float tmplN[272];
  __shared__ float s_divr[144];
  __shared__ float s_corr[144];
  __shared__ ll sh_i, sh_cl, sh_s;
  __shared__ int sh_w, sh_ncand, sh_valid, sh_stop, sh_cnt;
  __shared__ float sh_tdiv;

  if (tid == 0) {
    ll middle = (left + right) / 2;
    float f0m = f0_at(pitch, middle, S, ratio);
    int w0 = (int)(16000.0 / (double)f0m);
    ll s0 = middle - (ll)(w0 / 2); if (s0 < 0) s0 = 0;
    ll len = T - s0; if (len > (ll)w0) len = w0;
    float mn = 0.f, mx = 0.f; ll imn = 0, imx = 0; bool first = true;
    for (ll k = 0; k < len; ++k) {
      float v = xval(snd, mean, s0 + k);
      if (first) { mn = mx = v; imn = imx = 0; first = false; }
      else {
        if (v < mn) { mn = v; imn = k; }
        if (v > mx) { mx = v; imx = k; }
      }
    }
    ll i0;
    if (mn == mx) i0 = middle;
    else i0 = s0 + ((fabs((double)mn) > fabs((double)mx)) ? imn : imx);
    sh_i = i0; sh_stop = 0; sh_cnt = 0;
  }
  __syncthreads();

  double added_right = -1e308;  // previous regions' value is always > 0.8w away
  int cnt = 0;

  for (int iter = 0; iter < WALK_MAXI; ++iter) {
    if (tid == 0) {
      ll i = sh_i;
      float f0v = f0_at(pitch, i, S, ratio);
      int w = (int)(16000.0 / fmax((double)f0v, 60.0));
      ll cl, cr;
      if (dir == 0) {
        cl = (ll)dsub((double)i, dmul(1.75, (double)w)); if (cl < 0) cl = 0;
        cr = (ll)dsub((double)i, dmul(1.3, (double)w)); if (cr < 0) cr = 0;
      } else {
        cl = (ll)dadd((double)i, dmul(0.3, (double)w));
        cr = (ll)dadd((double)i, dmul(0.75, (double)w));
      }
      ll s = i - (ll)(w / 2); if (s < 0) s = 0;
      int valid = !(cl == cr || (T - cl) < (ll)w || (s + (ll)w) > T);
      int ncand = 0;
      if (valid) {
        ll L = cr + (ll)w; if (L > T) L = T; L -= cl;
        ncand = (int)(L - (ll)w + 1);
        float tn = __fsqrt_rn(pw_sq(snd, mean, s, w));
        sh_tdiv = (float)fmax((double)tn, 1e-12);
      }
      sh_w = w; sh_cl = cl; sh_s = s; sh_valid = valid; sh_ncand = ncand;
    }
    __syncthreads();
    int w = sh_w, ncand = sh_ncand;
    if (sh_valid) {
      ll cl = sh_cl, s = sh_s;
      float tdiv = sh_tdiv;
      for (int k = tid; k < w; k += 64)
        tmplN[k] = __fdiv_rn(xval(snd, mean, s + k), tdiv);
      for (int r = tid; r < ncand; r += 64) {
        float nr = __fsqrt_rn(pw_sq(snd, mean, cl + r, w));
        s_divr[r] = fmaxf(nr, (float)1e-12);
      }
      __syncthreads();
      for (int r = tid; r < ncand; r += 64)
        s_corr[r] = dot_mimic(snd, mean, cl + r, s_divr[r], tmplN, w);
    }
    __syncthreads();
    if (tid == 0) {
      ll i = sh_i;
      double corrd; ll ipos; double peakd;
      if (!sh_valid) { corrd = -1.0; ipos = i; peakd = 0.0; }
      else {
        int rb = 0; float bc = s_corr[0];
        for (int r = 1; r < ncand; ++r) if (s_corr[r] > bc) { bc = s_corr[r]; rb = r; }
        corrd = (double)bc;
        ipos = i + ((ll)rb + sh_cl) - sh_s;
        float pk = 0.0f;
        for (int k = 0; k < w; ++k) {
          float a = fabsf(xval(snd, mean, sh_cl + rb + k));
          if (a > pk) pk = a;
        }
        peakd = (double)pk;
      }
      ll inew;
      if (dir == 0) {
        inew = (corrd == -1.0) ? (i - (ll)w) : ipos;
        if (inew < left) {
          if (corrd > 0.7 && peakd > dmul(0.023333, gpeak) &&
              (dsub((double)inew, added_right) > dmul(0.8, (double)w))) {
            if (cnt < MAXCHAIN) mybuf[cnt++] = (int)inew;
          }
          sh_stop = 1;
        } else {
          if (corrd > 0.3 && (peakd == 0.0 || peakd > dmul(0.01, gpeak))) {
            if (dsub((double)inew, added_right) > dmul(0.8, (double)w)) {
              if (cnt < MAXCHAIN) mybuf[cnt++] = (int)inew;
            }
          }
          sh_i = inew;
        }
      } else {
        inew = (corrd == -1.0) ? (i + (ll)w) : ipos;
        if (inew >= right) {
          if (corrd > 0.7 && peakd > dmul(0.023333, gpeak)) {
            if (cnt < MAXCHAIN) mybuf[cnt++] = (int)inew;
          }
          sh_stop = 1;
        } else {
          if (corrd > 0.3 && (peakd == 0.0 || peakd > dmul(0.01, gpeak))) {
            if (cnt < MAXCHAIN) mybuf[cnt++] = (int)inew;
            added_right = (double)inew;
          }
          sh_i = inew;
        }
      }
      sh_cnt = cnt;
    }
    __syncthreads();
    if (sh_stop) break;
  }
  int total = sh_cnt;
  __syncthreads();
  if (dir == 0) {  // left chains were appended in descending order -> reverse
    for (int k = tid; k < total / 2; k += 64) {
      int a = mybuf[k], b = mybuf[total - 1 - k];
      mybuf[k] = b; mybuf[total - 1 - k] = a;
    }
  }
  if (tid == 0) c->chain_cnt[chain] = total;
}

__global__ void k_offsets(char* wsb) {
  Ctrl* c = (Ctrl*)wsb;
  int off = 0;
  for (int ch = 0; ch < 128; ++ch) {
    c->chain_off[ch] = off;
    off += c->chain_cnt[ch];
  }
  c->chain_off[128] = off;
  c->n_peaks = (off > MAXP) ? MAXP : off;
}

__global__ void k_gather(char* wsb, ll T) {
  Ctrl* c = (Ctrl*)wsb;
  int chain = blockIdx.x;
  int cnt = c->chain_cnt[chain];
  int off = c->chain_off[chain];
  const int* mybuf = ((const int*)(wsb + CHAINS_OFF)) + (ll)chain * MAXCHAIN;
  int* peaks = (int*)(wsb + PEAKS_OFF);
  for (int k = threadIdx.x; k < cnt; k += blockDim.x) {
    if (off + k < MAXP) {
      int v = mybuf[k];
      if (v < 0) v = 0;
      if ((ll)v > T - 1) v = (int)(T - 1);
      peaks[off + k] = v;
    }
  }
}

__global__ void k_psola(const float* __restrict__ pitch, ll T, ll S, double ratio,
                        char* wsb, const float* ps, const float* pr) {
  if (threadIdx.x != 0) return;
  Ctrl* c = (Ctrl*)wsb;
  int r = blockIdx.x;
  if (r >= c->nregions) return;
  const int* peaks = (const int*)(wsb + PEAKS_OFF);
  int np = c->n_peaks;
  int4* ops = (int4*)(wsb + OPS_OFF);
  ll prev_end = (r == 0) ? 0 : (ll)c->region_end[r - 1];
  ll lv = (ll)c->region_start[r], rv = (ll)c->region_end[r];
  double max_w = c->max_w;
  float md32 = c->md32, psv = ps[0], prv = pr[0];

  ll gapn = lv - prev_end;  // add_op(i, i, hann(left_v - i))
  if (gapn > 0) {
    int o = atomicAdd(&c->n_ops, 1);
    if (o < MAXOPS) ops[o] = make_int4((int)prev_end, (int)prev_end, (int)gapn, (int)gapn);
  }
  if (np <= 0) return;
  int j = 0;
  for (long itc = 0; itc < 2000000 && lv < rv; ++itc) {
    float fs = f0s_at(pitch, lv, S, ratio, psv, prv, md32);
    int period = (int)(16000.0 / fmax((double)fs, 60.0));
    int lw = period / 2, rw = period / 2;
    while (j < np && (ll)peaks[j] < lv) ++j;
    ll dl = (j > 0) ? (lv - (ll)peaks[j - 1]) : LLONG_MAX;
    ll dr = (j < np) ? ((ll)peaks[j] - lv) : LLONG_MAX;
    int p;
    if (dl <= dr) {  // first occurrence of the minimum (np.argmin semantics)
      int q = j - 1; int v = peaks[q];
      while (q > 0 && peaks[q - 1] == v) --q;
      p = q;
    } else {
      int q = j; int v = peaks[q];
      while (q > 0 && peaks[q - 1] == v) --q;
      p = q;
    }
    if (p > 0) {
      ll g = (ll)peaks[p] - (ll)peaks[p - 1];
      if ((double)g <= max_w && g < (ll)lw) lw = (int)g;
    }
    if (p < np - 1) {
      ll g = (ll)peaks[p + 1] - (ll)peaks[p];
      if ((double)g <= max_w && g < (ll)rw) rw = (int)g;
    }
    ll li = (ll)peaks[p] - (ll)lw; if (li < 0) li = 0;
    ll ri = (ll)peaks[p] + (ll)rw;
    ll ival = (ri - li) / 2;
    if (ival <= 0) { lv += (period > 1 ? (ll)period : 1); continue; }
    ll a = lv - ival, b = lv + ival;
    ll st = (a < 0) ? ((a + T > 0) ? a + T : 0) : ((a < T) ? a : T);  // slice.indices
    ll sp = (b < 0) ? ((b + T > 0) ? b + T : 0) : ((b < T) ? b : T);
    ll dst_len = sp - st; if (dst_len < 0) dst_len = 0;
    ll se = li + 2 * ival; if (se > T) se = T;
    ll src_len = se - li; if (src_len < 0) src_len = 0;
    ll seglen = dst_len < src_len ? dst_len : src_len;
    if (seglen > 0) {
      int o = atomicAdd(&c->n_ops, 1);
      if (o < MAXOPS) ops[o] = make_int4((int)st, (int)li, (int)seglen, (int)(2 * ival));
    }
    lv += 2 * ival;
  }
}

__global__ void k_scatter(const float* __restrict__ snd, char* wsb, float* out, ll T) {
  Ctrl* c = (Ctrl*)wsb;
  float mean = c->mean32;
  int nops = c->n_ops; if (nops > MAXOPS) nops = MAXOPS;
  const int4* ops = (const int4*)(wsb + OPS_OFF);
  for (int o = blockIdx.x; o < nops; o += gridDim.x) {
    int4 op = ops[o];
    ll dst = (ll)op.x, src = (ll)op.y; int n = op.z, m = op.w;
    for (int k = threadIdx.x; k < n; k += blockDim.x) {
      double ang = dmul(TWOPI, (double)k) / (double)m;  // (2pi*k)/m like numpy
      float w32 = (float)dsub(0.5, dmul(0.5, cos(ang)));
      float val = fmul(w32, xval(snd, mean, src + k));
      atomicAdd(&out[dst + k], val);
    }
  }
}

__global__ void k_final(const float* __restrict__ snd, char* wsb, float* out, ll T) {
  Ctrl* c = (Ctrl*)wsb;
  float mean = c->mean32;
  ll tail = c->tail;
  ll stride = (ll)gridDim.x * blockDim.x;
  for (ll t = (ll)blockIdx.x * blockDim.x + threadIdx.x; t < T; t += stride)
    if (t >= tail) out[t] = xval(snd, mean, t);
}

extern "C" void kernel_launch(void* const* d_in, const int* in_sizes, int n_in,
                              void* d_out, int out_size, void* d_ws, size_t ws_size,
                              hipStream_t stream) {
  ll T = (ll)in_sizes[0];
  ll S = (ll)in_sizes[1];
  const float* snd = (const float*)d_in[0];
  const float* pitch = (const float*)d_in[1];
  const float* ps = (const float*)d_in[2];
  const float* pr = (const float*)d_in[3];
  float* out = (float*)d_out;
  char* wsb = (char*)d_ws;
  double ratio = (double)S / (double)T;

  k_init<<<1, 256, 0, stream>>>(wsb);
  k_sum_partial<<<1024, 256, 0, stream>>>(snd, T, wsb);
  k_sum_final<<<1, 256, 0, stream>>>(wsb, T, 1024);
  k_scan<<<2048, 256, 0, stream>>>(snd, pitch, T, S, ratio, wsb);
  k_prep<<<1, 1, 0, stream>>>(wsb, ps);
  for (int pass = 0; pass < 4; ++pass) {
    k_hist<<<2048, 256, 0, stream>>>(pitch, T, S, ratio, wsb);
    k_sel<<<1, 1, 0, stream>>>(wsb, ps, pr);
  }
  k_walks<<<128, 64, 0, stream>>>(snd, pitch, T, S, ratio, wsb);
  k_offsets<<<1, 1, 0, stream>>>(wsb);
  k_gather<<<128, 64, 0, stream>>>(wsb, T);
  k_psola<<<64, 64, 0, stream>>>(pitch, T, S, ratio, wsb, ps, pr);
  hipMemsetAsync(d_out, 0, (size_t)out_size * sizeof(float), stream);
  k_scatter<<<8192, 128, 0, stream>>>(snd, wsb, out, T);
  k_final<<<2048, 256, 0, stream>>>(snd, wsb, out, T);
}

// Round 2
// 18602.071 us; speedup vs baseline: 1.4505x; 1.4505x over previous
//
#include <hip/hip_runtime.h>
#include <math.h>
#include <limits.h>

typedef long long ll;

#define MAXCHAIN 4096
#define MAXP 49152
#define MAXOPS 49152
#define MAXR 64
#define PART_OFF 4096
#define CHAINS_OFF 16384
#define PEAKS_OFF (CHAINS_OFF + 128 * MAXCHAIN * 4)
#define OPS_OFF (PEAKS_OFF + MAXP * 4)
#define F0_OFF (OPS_OFF + (size_t)MAXOPS * 16)

static __device__ const double TWOPI = 6.283185307179586;

struct Ctrl {
  double gpeak, max_w, ps64;
  long long k_rem, tail;
  float mean32, median_raw, md32, minv_scaled32;
  unsigned amax_bits, minf0_bits, prefix;
  int cnt_pos, shift, n_starts, n_ends, nregions, n_peaks, n_ops;
  int hist[256];
  int region_start[MAXR], region_end[MAXR];
  int chain_cnt[128];
  int chain_off[129];
};

// ---------- exact-arith helpers (no FMA contraction) ----------
__device__ __forceinline__ double dmul(double a, double b) { return __dmul_rn(a, b); }
__device__ __forceinline__ double dadd(double a, double b) { return __dadd_rn(a, b); }
__device__ __forceinline__ double dsub(double a, double b) { return __dadd_rn(a, -b); }
__device__ __forceinline__ float fmul(float a, float b) { return __fmul_rn(a, b); }
__device__ __forceinline__ float fadd(float a, float b) { return __fadd_rn(a, b); }
__device__ __forceinline__ float fsub(float a, float b) { return __fadd_rn(a, -b); }

__device__ __forceinline__ float xval(const float* snd, float mean, ll t) {
  return fsub(snd[t], mean);
}

// f0 = linear interp of pitch, computed exactly as numpy (f64 ops, one f32 round)
__device__ float f0_at(const float* pitch, ll t, ll S, double ratio) {
  double pos = dsub(dmul(dadd((double)t, 0.5), ratio), 0.5);
  double hi = (double)(S - 1);
  pos = fmin(fmax(pos, 0.0), hi);
  double fl = floor(pos);
  ll lo = (ll)fl;
  if (lo < 0) lo = 0;
  if (lo > S - 1) lo = S - 1;
  ll hii = lo + 1; if (hii > S - 1) hii = S - 1;
  double frac = dsub(pos, fl);
  double om = dsub(1.0, frac);
  double v = dadd(dmul((double)pitch[lo], om), dmul((double)pitch[hii], frac));
  return (float)v;
}

__device__ __forceinline__ float f0s_at(const float* pitch, ll t, ll S, double ratio,
                                        float psv, float prv, float md32) {
  float f = f0_at(pitch, t, S, ratio);
  float u = fmul(f, psv);
  if (!(u > 0.0f)) return 0.0f;
  return fadd(md32, fmul(fsub(u, md32), prv));
}

// ---- numpy pairwise sum-of-squares, flattened (n <= 266), + running max|x| ----
// Block for n <= 128 (exact replica of numpy's 8-accumulator scheme).
__device__ float pw_blk(const float* snd, float mean, ll base, int n, float& pk) {
  if (n < 8) {
    float res = 0.0f;
    for (int i = 0; i < n; ++i) {
      float x = xval(snd, mean, base + i);
      pk = fmaxf(pk, fabsf(x));
      res = fadd(res, fmul(x, x));
    }
    return res;
  }
  float x0 = xval(snd, mean, base + 0), x1 = xval(snd, mean, base + 1),
        x2 = xval(snd, mean, base + 2), x3 = xval(snd, mean, base + 3),
        x4 = xval(snd, mean, base + 4), x5 = xval(snd, mean, base + 5),
        x6 = xval(snd, mean, base + 6), x7 = xval(snd, mean, base + 7);
  pk = fmaxf(pk, fabsf(x0)); pk = fmaxf(pk, fabsf(x1));
  pk = fmaxf(pk, fabsf(x2)); pk = fmaxf(pk, fabsf(x3));
  pk = fmaxf(pk, fabsf(x4)); pk = fmaxf(pk, fabsf(x5));
  pk = fmaxf(pk, fabsf(x6)); pk = fmaxf(pk, fabsf(x7));
  float r0 = fmul(x0, x0), r1 = fmul(x1, x1), r2 = fmul(x2, x2), r3 = fmul(x3, x3);
  float r4 = fmul(x4, x4), r5 = fmul(x5, x5), r6 = fmul(x6, x6), r7 = fmul(x7, x7);
  int i = 8, lim = n - (n & 7);
  for (; i < lim; i += 8) {
    float y;
    y = xval(snd, mean, base + i + 0); pk = fmaxf(pk, fabsf(y)); r0 = fadd(r0, fmul(y, y));
    y = xval(snd, mean, base + i + 1); pk = fmaxf(pk, fabsf(y)); r1 = fadd(r1, fmul(y, y));
    y = xval(snd, mean, base + i + 2); pk = fmaxf(pk, fabsf(y)); r2 = fadd(r2, fmul(y, y));
    y = xval(snd, mean, base + i + 3); pk = fmaxf(pk, fabsf(y)); r3 = fadd(r3, fmul(y, y));
    y = xval(snd, mean, base + i + 4); pk = fmaxf(pk, fabsf(y)); r4 = fadd(r4, fmul(y, y));
    y = xval(snd, mean, base + i + 5); pk = fmaxf(pk, fabsf(y)); r5 = fadd(r5, fmul(y, y));
    y = xval(snd, mean, base + i + 6); pk = fmaxf(pk, fabsf(y)); r6 = fadd(r6, fmul(y, y));
    y = xval(snd, mean, base + i + 7); pk = fmaxf(pk, fabsf(y)); r7 = fadd(r7, fmul(y, y));
  }
  float res = fadd(fadd(fadd(r0, r1), fadd(r2, r3)), fadd(fadd(r4, r5), fadd(r6, r7)));
  for (; i < n; ++i) {
    float y = xval(snd, mean, base + i);
    pk = fmaxf(pk, fabsf(y));
    res = fadd(res, fmul(y, y));
  }
  return res;
}

// Full pairwise for n <= 266 (matches the recursive split: n2 = (n>>1) & ~7).
__device__ float pw_sq_pk(const float* snd, float mean, ll base, int n, float& pk) {
  if (n <= 128) return pw_blk(snd, mean, base, n, pk);
  int n2 = (n >> 1); n2 -= (n2 & 7);           // 64..128
  float a = pw_blk(snd, mean, base, n2, pk);
  int m = n - n2;
  float b;
  if (m <= 128) {
    b = pw_blk(snd, mean, base + n2, m, pk);
  } else {                                      // n in [257,266]: m in [129,138]
    int m2 = (m >> 1); m2 -= (m2 & 7);          // = 64
    float b1 = pw_blk(snd, mean, base + n2, m2, pk);
    float b2 = pw_blk(snd, mean, base + n2 + m2, m - m2, pk);
    b = fadd(b1, b2);
  }
  return fadd(a, b);
}

__device__ __forceinline__ float tsel(int seg, float t0, float t1, float t2, float t3, float t4) {
  return (seg == 0) ? t0 : (seg == 1) ? t1 : (seg == 2) ? t2 : (seg == 3) ? t3 : t4;
}

// BLAS-sgemv mimic (identical arithmetic to the passing version): 8-lane f32 FMA
// accumulation, pairwise combine. Template elements broadcast via shfl.
// ALL 64 LANES MUST BE ACTIVE when calling this (shfl inside).
__device__ float dot_shfl(const float* snd, float mean, ll sb, float divr,
                          float t0, float t1, float t2, float t3, float t4, int w) {
  float a0 = 0.f, a1 = 0.f, a2 = 0.f, a3 = 0.f, a4 = 0.f, a5 = 0.f, a6 = 0.f, a7 = 0.f;
  int lim = w - (w & 7);
  int k = 0;
  for (int seg = 0; seg < 5; ++seg) {
    float ts = tsel(seg, t0, t1, t2, t3, t4);
    int kend = (seg + 1) * 64; if (kend > lim) kend = lim;
    for (; k < kend; k += 8) {
      int kb = k & 63;
      a0 = __fmaf_rn(__fdiv_rn(xval(snd, mean, sb + k + 0), divr), __shfl(ts, kb + 0), a0);
      a1 = __fmaf_rn(__fdiv_rn(xval(snd, mean, sb + k + 1), divr), __shfl(ts, kb + 1), a1);
      a2 = __fmaf_rn(__fdiv_rn(xval(snd, mean, sb + k + 2), divr), __shfl(ts, kb + 2), a2);
      a3 = __fmaf_rn(__fdiv_rn(xval(snd, mean, sb + k + 3), divr), __shfl(ts, kb + 3), a3);
      a4 = __fmaf_rn(__fdiv_rn(xval(snd, mean, sb + k + 4), divr), __shfl(ts, kb + 4), a4);
      a5 = __fmaf_rn(__fdiv_rn(xval(snd, mean, sb + k + 5), divr), __shfl(ts, kb + 5), a5);
      a6 = __fmaf_rn(__fdiv_rn(xval(snd, mean, sb + k + 6), divr), __shfl(ts, kb + 6), a6);
      a7 = __fmaf_rn(__fdiv_rn(xval(snd, mean, sb + k + 7), divr), __shfl(ts, kb + 7), a7);
    }
    if (k >= lim) break;
  }
  {
    int seg = lim >> 6;
    float ts = tsel(seg, t0, t1, t2, t3, t4);
    int kb = lim & 63;
    if (lim + 0 < w) a0 = __fmaf_rn(__fdiv_rn(xval(snd, mean, sb + lim + 0), divr), __shfl(ts, kb + 0), a0);
    if (lim + 1 < w) a1 = __fmaf_rn(__fdiv_rn(xval(snd, mean, sb + lim + 1), divr), __shfl(ts, kb + 1), a1);
    if (lim + 2 < w) a2 = __fmaf_rn(__fdiv_rn(xval(snd, mean, sb + lim + 2), divr), __shfl(ts, kb + 2), a2);
    if (lim + 3 < w) a3 = __fmaf_rn(__fdiv_rn(xval(snd, mean, sb + lim + 3), divr), __shfl(ts, kb + 3), a3);
    if (lim + 4 < w) a4 = __fmaf_rn(__fdiv_rn(xval(snd, mean, sb + lim + 4), divr), __shfl(ts, kb + 4), a4);
    if (lim + 5 < w) a5 = __fmaf_rn(__fdiv_rn(xval(snd, mean, sb + lim + 5), divr), __shfl(ts, kb + 5), a5);
    if (lim + 6 < w) a6 = __fmaf_rn(__fdiv_rn(xval(snd, mean, sb + lim + 6), divr), __shfl(ts, kb + 6), a6);
  }
  return fadd(fadd(fadd(a0, a1), fadd(a2, a3)), fadd(fadd(a4, a5), fadd(a6, a7)));
}

// ---------- kernels ----------
__global__ void k_init(char* wsb) {
  Ctrl* c = (Ctrl*)wsb;
  int t = threadIdx.x;
  for (int b = t; b < 256; b += blockDim.x) c->hist[b] = 0;
  for (int b = t; b < 128; b += blockDim.x) c->chain_cnt[b] = 0;
  if (t == 0) {
    c->amax_bits = 0u; c->minf0_bits = 0xFFFFFFFFu;
    c->cnt_pos = 0; c->n_starts = 0; c->n_ends = 0; c->n_ops = 0;
    c->nregions = 0; c->n_peaks = 0; c->tail = 0;
  }
}

__global__ void k_sum_partial(const float* __restrict__ snd, ll T, char* wsb) {
  __shared__ double sd[256];
  double local = 0.0;
  ll stride = (ll)gridDim.x * blockDim.x;
  for (ll t = (ll)blockIdx.x * blockDim.x + threadIdx.x; t < T; t += stride)
    local += (double)snd[t];
  sd[threadIdx.x] = local; __syncthreads();
  for (int o = 128; o > 0; o >>= 1) {
    if ((int)threadIdx.x < o) sd[threadIdx.x] += sd[threadIdx.x + o];
    __syncthreads();
  }
  if (threadIdx.x == 0) ((double*)(wsb + PART_OFF))[blockIdx.x] = sd[0];
}

__global__ void k_sum_final(char* wsb, ll T, int nparts) {
  __shared__ double sd[256];
  double local = 0.0;
  const double* p = (const double*)(wsb + PART_OFF);
  for (int i = threadIdx.x; i < nparts; i += blockDim.x) local += p[i];
  sd[threadIdx.x] = local; __syncthreads();
  for (int o = 128; o > 0; o >>= 1) {
    if ((int)threadIdx.x < o) sd[threadIdx.x] += sd[threadIdx.x + o];
    __syncthreads();
  }
  if (threadIdx.x == 0) ((Ctrl*)wsb)->mean32 = (float)(sd[0] / (double)T);
}

// optional: cache exact f32 bits of f0 over all T (gated on ws_size)
__global__ void k_f0(const float* __restrict__ pitch, ll T, ll S, double ratio,
                     unsigned* __restrict__ bits) {
  ll stride = (ll)gridDim.x * blockDim.x;
  for (ll t = (ll)blockIdx.x * blockDim.x + threadIdx.x; t < T; t += stride)
    bits[t] = __float_as_uint(f0_at(pitch, t, S, ratio));
}

__global__ void k_scan(const float* __restrict__ snd, const float* __restrict__ pitch,
                       ll T, ll S, double ratio, char* wsb,
                       const unsigned* __restrict__ f0bits, int cached) {
  Ctrl* c = (Ctrl*)wsb;
  float mean = c->mean32;
  __shared__ unsigned smax[256]; __shared__ unsigned smin[256]; __shared__ int scnt[256];
  unsigned mymax = 0u, mymin = 0xFFFFFFFFu; int mycnt = 0;
  ll stride = (ll)gridDim.x * blockDim.x;
  for (ll t = (ll)blockIdx.x * blockDim.x + threadIdx.x; t < T; t += stride) {
    float xv = xval(snd, mean, t);
    unsigned ab = __float_as_uint(fabsf(xv));
    if (ab > mymax) mymax = ab;
    float f = cached ? __uint_as_float(f0bits[t]) : f0_at(pitch, t, S, ratio);
    bool pos = (f > 0.0f);
    if (pos) { ++mycnt; unsigned fb = __float_as_uint(f); if (fb < mymin) mymin = fb; }
    if (t >= 1) {
      float fp = cached ? __uint_as_float(f0bits[t - 1]) : f0_at(pitch, t - 1, S, ratio);
      bool posp = (fp > 0.0f);
      if (pos && (t == 1 || !posp)) {
        int id = atomicAdd(&c->n_starts, 1);
        if (id < MAXR) c->region_start[id] = (int)t;
      }
      if (!pos && posp && (t - 1) >= 1) {
        int id = atomicAdd(&c->n_ends, 1);
        if (id < MAXR) c->region_end[id] = (int)t;
      }
    }
    if (t == T - 1 && pos) {
      int id = atomicAdd(&c->n_ends, 1);
      if (id < MAXR) c->region_end[id] = (int)T;
    }
  }
  smax[threadIdx.x] = mymax; smin[threadIdx.x] = mymin; scnt[threadIdx.x] = mycnt;
  __syncthreads();
  for (int o = 128; o > 0; o >>= 1) {
    if ((int)threadIdx.x < o) {
      if (smax[threadIdx.x + o] > smax[threadIdx.x]) smax[threadIdx.x] = smax[threadIdx.x + o];
      if (smin[threadIdx.x + o] < smin[threadIdx.x]) smin[threadIdx.x] = smin[threadIdx.x + o];
      scnt[threadIdx.x] += scnt[threadIdx.x + o];
    }
    __syncthreads();
  }
  if (threadIdx.x == 0) {
    atomicMax(&c->amax_bits, smax[0]);
    atomicMin(&c->minf0_bits, smin[0]);
    atomicAdd(&c->cnt_pos, scnt[0]);
  }
}

__global__ void k_prep(char* wsb, const float* ps) {
  Ctrl* c = (Ctrl*)wsb;
  int ns = c->n_starts; if (ns > MAXR) ns = MAXR;
  int ne = c->n_ends; if (ne > MAXR) ne = MAXR;
  for (int a = 1; a < ns; ++a) {
    int v = c->region_start[a]; int b = a - 1;
    while (b >= 0 && c->region_start[b] > v) { c->region_start[b + 1] = c->region_start[b]; --b; }
    c->region_start[b + 1] = v;
  }
  for (int a = 1; a < ne; ++a) {
    int v = c->region_end[a]; int b = a - 1;
    while (b >= 0 && c->region_end[b] > v) { c->region_end[b + 1] = c->region_end[b]; --b; }
    c->region_end[b + 1] = v;
  }
  int nr = ns < ne ? ns : ne;
  c->nregions = nr;
  c->tail = (nr > 0) ? (ll)c->region_end[nr - 1] : 0;
  c->gpeak = (double)__uint_as_float(c->amax_bits);
  ll cnt = (ll)c->cnt_pos; if (cnt < 1) cnt = 1;
  c->k_rem = (cnt - 1) / 2;
  c->prefix = 0u; c->shift = 24;
  double p64 = (double)ps[0];
  c->ps64 = round(p64 * 1e7) / 1e7;
}

__global__ void k_hist(const float* __restrict__ pitch, ll T, ll S, double ratio, char* wsb,
                       const unsigned* __restrict__ f0bits, int cached) {
  Ctrl* c = (Ctrl*)wsb;
  __shared__ int h[256];
  for (int b = threadIdx.x; b < 256; b += blockDim.x) h[b] = 0;
  __syncthreads();
  int shift = c->shift;
  unsigned pref = c->prefix;
  unsigned himask = (shift == 24) ? 0u : ((~0u) << (shift + 8));
  ll stride = (ll)gridDim.x * blockDim.x;
  for (ll t = (ll)blockIdx.x * blockDim.x + threadIdx.x; t < T; t += stride) {
    float f; unsigned bits;
    if (cached) { bits = f0bits[t]; f = __uint_as_float(bits); }
    else { f = f0_at(pitch, t, S, ratio); bits = __float_as_uint(f); }
    if (f > 0.0f) {
      if ((bits & himask) == (pref & himask)) atomicAdd(&h[(bits >> shift) & 255], 1);
    }
  }
  __syncthreads();
  for (int b = threadIdx.x; b < 256; b += blockDim.x) if (h[b]) atomicAdd(&c->hist[b], h[b]);
}

__global__ void k_sel(char* wsb, const float* ps, const float* pr) {
  Ctrl* c = (Ctrl*)wsb;
  int shift = c->shift;
  ll k = c->k_rem;
  ll run = 0; int pick = 255;
  for (int b = 0; b < 256; ++b) {
    ll h = (ll)c->hist[b];
    if (run + h > k) { pick = b; break; }
    run += h;
  }
  c->prefix |= ((unsigned)pick) << shift;
  c->k_rem = k - run;
  for (int b = 0; b < 256; ++b) c->hist[b] = 0;
  if (shift == 0) {
    float mraw = __uint_as_float(c->prefix);
    c->median_raw = mraw;
    double md = dmul((double)mraw, c->ps64);
    float md32 = (float)md;
    c->md32 = md32;
    float minf = __uint_as_float(c->minf0_bits);
    float u = fmul(minf, ps[0]);
    float sc = fadd(md32, fmul(fsub(u, md32), pr[0]));
    c->minv_scaled32 = sc;
    c->max_w = 20000.0 / (double)sc;
  }
  c->shift = shift - 8;
}

#define WALK_MAXI 400000

// Barrier-free walk: one wave per chain; wave-uniform state computed redundantly
// on all 64 lanes; template broadcast via shfl; argmax via shfl_xor butterfly.
__global__ __launch_bounds__(64) void k_walks(const float* __restrict__ snd,
                                              const float* __restrict__ pitch,
                                              ll T, ll S, double ratio, char* wsb) {
  Ctrl* c = (Ctrl*)wsb;
  int chain = blockIdx.x;
  int reg = chain >> 1, dir = chain & 1;  // dir 0 = left walk, 1 = right walk
  if (reg >= c->nregions) return;
  int* mybuf = ((int*)(wsb + CHAINS_OFF)) + (ll)chain * MAXCHAIN;
  ll left = (ll)c->region_start[reg];
  ll right = (ll)c->region_end[reg];
  float mean = c->mean32;
  double gpeak = c->gpeak;
  int lane = threadIdx.x;

  // initial position (all lanes redundantly; identical deterministic arithmetic)
  ll i;
  {
    ll middle = (left + right) / 2;
    float f0m = f0_at(pitch, middle, S, ratio);
    int w0 = (int)(16000.0 / (double)f0m);
    ll s0 = middle - (ll)(w0 / 2); if (s0 < 0) s0 = 0;
    ll len = T - s0; if (len > (ll)w0) len = (ll)w0;
    float mn = 0.f, mx = 0.f; ll imn = 0, imx = 0; bool first = true;
    for (ll k = 0; k < len; ++k) {
      float v = xval(snd, mean, s0 + k);
      if (first) { mn = mx = v; imn = imx = 0; first = false; }
      else {
        if (v < mn) { mn = v; imn = k; }
        if (v > mx) { mx = v; imx = k; }
      }
    }
    if (mn == mx) i = middle;
    else i = s0 + ((fabs((double)mn) > fabs((double)mx)) ? imn : imx);
  }

  double added_right = -1e308;
  int cnt = 0;
  float pf_acc = 0.0f;
  bool stop = false;

  for (int iter = 0; iter < WALK_MAXI && !stop; ++iter) {
    float f0v = f0_at(pitch, i, S, ratio);
    int w = (int)(16000.0 / fmax((double)f0v, 60.0));  // <= 266
    ll cl, cr;
    if (dir == 0) {
      cl = (ll)dsub((double)i, dmul(1.75, (double)w)); if (cl < 0) cl = 0;
      cr = (ll)dsub((double)i, dmul(1.3, (double)w)); if (cr < 0) cr = 0;
    } else {
      cl = (ll)dadd((double)i, dmul(0.3, (double)w));
      cr = (ll)dadd((double)i, dmul(0.75, (double)w));
    }
    ll s = i - (ll)(w / 2); if (s < 0) s = 0;
    bool valid = !(cl == cr || (T - cl) < (ll)w || (s + (ll)w) > T);
    double corrd; ll ipos; double peakd;
    if (!valid) { corrd = -1.0; ipos = i; peakd = 0.0; }
    else {
      ll L = cr + (ll)w; if (L > T) L = T; L -= cl;
      int ncand = (int)(L - (ll)w + 1);           // 1..121 (< 128)
      // template norm (all lanes redundantly; broadcast loads)
      float dummy = 0.0f;
      float tn = __fsqrt_rn(pw_sq_pk(snd, mean, s, w, dummy));
      float tdiv = (float)fmax((double)tn, 1e-12);
      // normalized template in 5 regs/lane
      float t0v = 0.f, t1v = 0.f, t2v = 0.f, t3v = 0.f, t4v = 0.f;
      {
        int idx = lane;
        if (idx < w) t0v = __fdiv_rn(xval(snd, mean, s + idx), tdiv);
        idx = lane + 64;  if (idx < w) t1v = __fdiv_rn(xval(snd, mean, s + idx), tdiv);
        idx = lane + 128; if (idx < w) t2v = __fdiv_rn(xval(snd, mean, s + idx), tdiv);
        idx = lane + 192; if (idx < w) t3v = __fdiv_rn(xval(snd, mean, s + idx), tdiv);
        idx = lane + 256; if (idx < w) t4v = __fdiv_rn(xval(snd, mean, s + idx), tdiv);
      }
      // prefetch ~1KB toward movement direction (consumed after the dot loop)
      float pf0, pf1, pf2, pf3;
      {
        ll pb = dir ? (cl + (ll)w + (ll)ncand) : (cl - 1024);
        ll aa;
        aa = pb + lane;       if (aa < 0) aa = 0; if (aa > T - 1) aa = T - 1; pf0 = snd[aa];
        aa = pb + 64 + lane;  if (aa < 0) aa = 0; if (aa > T - 1) aa = T - 1; pf1 = snd[aa];
        aa = pb + 128 + lane; if (aa < 0) aa = 0; if (aa > T - 1) aa = T - 1; pf2 = snd[aa];
        aa = pb + 192 + lane; if (aa < 0) aa = 0; if (aa > T - 1) aa = T - 1; pf3 = snd[aa];
      }
      // candidate slot 0: r = lane (clamped base keeps all lanes active & in-bounds)
      int r0 = lane;
      int rc0 = (r0 < ncand) ? r0 : (ncand - 1);
      float pk0 = 0.0f;
      float nr0 = __fsqrt_rn(pw_sq_pk(snd, mean, cl + rc0, w, pk0));
      float divr0 = fmaxf(nr0, (float)1e-12);
      float co0 = dot_shfl(snd, mean, cl + rc0, divr0, t0v, t1v, t2v, t3v, t4v, w);
      // candidate slot 1 (only when ncand > 64; uniform branch)
      float pk1 = 0.0f, co1 = -INFINITY;
      if (ncand > 64) {
        int r1 = lane + 64;
        int rc1 = (r1 < ncand) ? r1 : (ncand - 1);
        float nr1 = __fsqrt_rn(pw_sq_pk(snd, mean, cl + rc1, w, pk1));
        float divr1 = fmaxf(nr1, (float)1e-12);
        co1 = dot_shfl(snd, mean, cl + rc1, divr1, t0v, t1v, t2v, t3v, t4v, w);
        if (r1 >= ncand) co1 = -INFINITY;
      }
      // fold the two slots (prefer higher corr; ties -> lower index)
      float bv = (r0 < ncand) ? co0 : -INFINITY;
      int bi = (r0 < ncand) ? r0 : 0x7FFFFFFF;
      {
        int i1 = lane + 64;
        if (co1 > bv || (co1 == bv && i1 < bi)) { bv = co1; bi = i1; }
      }
      // butterfly argmax (first-occurrence tie-break, matches serial scan)
      for (int off = 32; off > 0; off >>= 1) {
        float ov = __shfl_xor(bv, off);
        int oi = __shfl_xor(bi, off);
        if (ov > bv || (ov == bv && oi < bi)) { bv = ov; bi = oi; }
      }
      corrd = (double)bv;
      ipos = i + ((ll)bi + cl) - s;
      {
        int ol = bi & 63;
        float p0 = __shfl(pk0, ol);
        float p1 = __shfl(pk1, ol);
        peakd = (double)((bi < 64) ? p0 : p1);
      }
      pf_acc = fadd(pf_acc, fadd(fadd(pf0, pf1), fadd(pf2, pf3)));
    }
    // decision (all lanes redundantly; lane 0 writes)
    ll inew;
    if (dir == 0) {
      inew = (corrd == -1.0) ? (i - (ll)w) : ipos;
      if (inew < left) {
        if (corrd > 0.7 && peakd > dmul(0.023333, gpeak) &&
            (dsub((double)inew, added_right) > dmul(0.8, (double)w))) {
          if (cnt < MAXCHAIN) { if (lane == 0) mybuf[cnt] = (int)inew; ++cnt; }
        }
        stop = true;
      } else {
        if (corrd > 0.3 && (peakd == 0.0 || peakd > dmul(0.01, gpeak))) {
          if (dsub((double)inew, added_right) > dmul(0.8, (double)w)) {
            if (cnt < MAXCHAIN) { if (lane == 0) mybuf[cnt] = (int)inew; ++cnt; }
          }
        }
        i = inew;
      }
    } else {
      inew = (corrd == -1.0) ? (i + (ll)w) : ipos;
      if (inew >= right) {
        if (corrd > 0.7 && peakd > dmul(0.023333, gpeak)) {
          if (cnt < MAXCHAIN) { if (lane == 0) mybuf[cnt] = (int)inew; ++cnt; }
        }
        stop = true;
      } else {
        if (corrd > 0.3 && (peakd == 0.0 || peakd > dmul(0.01, gpeak))) {
          if (cnt < MAXCHAIN) { if (lane == 0) mybuf[cnt] = (int)inew; ++cnt; }
          added_right = (double)inew;
        }
        i = inew;
      }
    }
  }
  asm volatile("" :: "v"(pf_acc));  // keep prefetch loads live
  if (lane == 0) c->chain_cnt[chain] = cnt;
}

__global__ void k_offsets(char* wsb) {
  Ctrl* c = (Ctrl*)wsb;
  int off = 0;
  for (int ch = 0; ch < 128; ++ch) {
    c->chain_off[ch] = off;
    off += c->chain_cnt[ch];
  }
  c->chain_off[128] = off;
  c->n_peaks = (off > MAXP) ? MAXP : off;
}

__global__ void k_gather(char* wsb, ll T) {
  Ctrl* c = (Ctrl*)wsb;
  int chain = blockIdx.x;
  int cnt = c->chain_cnt[chain];
  int off = c->chain_off[chain];
  const int* mybuf = ((const int*)(wsb + CHAINS_OFF)) + (ll)chain * MAXCHAIN;
  int* peaks = (int*)(wsb + PEAKS_OFF);
  int dir = chain & 1;
  for (int k = threadIdx.x; k < cnt; k += blockDim.x) {
    if (off + k < MAXP) {
      int v = dir ? mybuf[k] : mybuf[cnt - 1 - k];  // left chains stored descending
      if (v < 0) v = 0;
      if ((ll)v > T - 1) v = (int)(T - 1);
      peaks[off + k] = v;
    }
  }
}

__global__ void k_psola(const float* __restrict__ pitch, ll T, ll S, double ratio,
                        char* wsb, const float* ps, const float* pr) {
  if (threadIdx.x != 0) return;
  Ctrl* c = (Ctrl*)wsb;
  int r = blockIdx.x;
  if (r >= c->nregions) return;
  const int* peaks = (const int*)(wsb + PEAKS_OFF);
  int np = c->n_peaks;
  int4* ops = (int4*)(wsb + OPS_OFF);
  ll prev_end = (r == 0) ? 0 : (ll)c->region_end[r - 1];
  ll lv = (ll)c->region_start[r], rv = (ll)c->region_end[r];
  double max_w = c->max_w;
  float md32 = c->md32, psv = ps[0], prv = pr[0];

  ll gapn = lv - prev_end;
  if (gapn > 0) {
    int o = atomicAdd(&c->n_ops, 1);
    if (o < MAXOPS) ops[o] = make_int4((int)prev_end, (int)prev_end, (int)gapn, (int)gapn);
  }
  if (np <= 0) return;
  int j = 0;
  for (long itc = 0; itc < 2000000 && lv < rv; ++itc) {
    float fs = f0s_at(pitch, lv, S, ratio, psv, prv, md32);
    int period = (int)(16000.0 / fmax((double)fs, 60.0));
    int lw = period / 2, rw = period / 2;
    while (j < np && (ll)peaks[j] < lv) ++j;
    ll dl = (j > 0) ? (lv - (ll)peaks[j - 1]) : LLONG_MAX;
    ll dr = (j < np) ? ((ll)peaks[j] - lv) : LLONG_MAX;
    int p;
    if (dl <= dr) {
      int q = j - 1; int v = peaks[q];
      while (q > 0 && peaks[q - 1] == v) --q;
      p = q;
    } else {
      int q = j; int v = peaks[q];
      while (q > 0 && peaks[q - 1] == v) --q;
      p = q;
    }
    if (p > 0) {
      ll g = (ll)peaks[p] - (ll)peaks[p - 1];
      if ((double)g <= max_w && g < (ll)lw) lw = (int)g;
    }
    if (p < np - 1) {
      ll g = (ll)peaks[p + 1] - (ll)peaks[p];
      if ((double)g <= max_w && g < (ll)rw) rw = (int)g;
    }
    ll li = (ll)peaks[p] - (ll)lw; if (li < 0) li = 0;
    ll ri = (ll)peaks[p] + (ll)rw;
    ll ival = (ri - li) / 2;
    if (ival <= 0) { lv += (period > 1 ? (ll)period : 1); continue; }
    ll a = lv - ival, b = lv + ival;
    ll st = (a < 0) ? ((a + T > 0) ? a + T : 0) : ((a < T) ? a : T);
    ll sp = (b < 0) ? ((b + T > 0) ? b + T : 0) : ((b < T) ? b : T);
    ll dst_len = sp - st; if (dst_len < 0) dst_len = 0;
    ll se = li + 2 * ival; if (se > T) se = T;
    ll src_len = se - li; if (src_len < 0) src_len = 0;
    ll seglen = dst_len < src_len ? dst_len : src_len;
    if (seglen > 0) {
      int o = atomicAdd(&c->n_ops, 1);
      if (o < MAXOPS) ops[o] = make_int4((int)st, (int)li, (int)seglen, (int)(2 * ival));
    }
    lv += 2 * ival;
  }
}

__global__ void k_scatter(const float* __restrict__ snd, char* wsb, float* out, ll T) {
  Ctrl* c = (Ctrl*)wsb;
  float mean = c->mean32;
  int nops = c->n_ops; if (nops > MAXOPS) nops = MAXOPS;
  const int4* ops = (const int4*)(wsb + OPS_OFF);
  for (int o = blockIdx.x; o < nops; o += gridDim.x) {
    int4 op = ops[o];
    ll dst = (ll)op.x, src = (ll)op.y; int n = op.z, m = op.w;
    for (int k = threadIdx.x; k < n; k += blockDim.x) {
      double ang = dmul(TWOPI, (double)k) / (double)m;
      float w32 = (float)dsub(0.5, dmul(0.5, cos(ang)));
      float val = fmul(w32, xval(snd, mean, src + k));
      atomicAdd(&out[dst + k], val);
    }
  }
}

__global__ void k_final(const float* __restrict__ snd, char* wsb, float* out, ll T) {
  Ctrl* c = (Ctrl*)wsb;
  float mean = c->mean32;
  ll tail = c->tail;
  ll stride = (ll)gridDim.x * blockDim.x;
  for (ll t = (ll)blockIdx.x * blockDim.x + threadIdx.x; t < T; t += stride)
    if (t >= tail) out[t] = xval(snd, mean, t);
}

extern "C" void kernel_launch(void* const* d_in, const int* in_sizes, int n_in,
                              void* d_out, int out_size, void* d_ws, size_t ws_size,
                              hipStream_t stream) {
  ll T = (ll)in_sizes[0];
  ll S = (ll)in_sizes[1];
  const float* snd = (const float*)d_in[0];
  const float* pitch = (const float*)d_in[1];
  const float* ps = (const float*)d_in[2];
  const float* pr = (const float*)d_in[3];
  float* out = (float*)d_out;
  char* wsb = (char*)d_ws;
  double ratio = (double)S / (double)T;

  size_t f0_need = F0_OFF + (size_t)T * 4;
  int cached = (ws_size >= f0_need) ? 1 : 0;
  unsigned* f0bits = (unsigned*)(wsb + F0_OFF);

  k_init<<<1, 256, 0, stream>>>(wsb);
  k_sum_partial<<<1024, 256, 0, stream>>>(snd, T, wsb);
  k_sum_final<<<1, 256, 0, stream>>>(wsb, T, 1024);
  if (cached) k_f0<<<2048, 256, 0, stream>>>(pitch, T, S, ratio, f0bits);
  k_scan<<<2048, 256, 0, stream>>>(snd, pitch, T, S, ratio, wsb, f0bits, cached);
  k_prep<<<1, 1, 0, stream>>>(wsb, ps);
  for (int pass = 0; pass < 4; ++pass) {
    k_hist<<<2048, 256, 0, stream>>>(pitch, T, S, ratio, wsb, f0bits, cached);
    k_sel<<<1, 1, 0, stream>>>(wsb, ps, pr);
  }
  k_walks<<<128, 64, 0, stream>>>(snd, pitch, T, S, ratio, wsb);
  k_offsets<<<1, 1, 0, stream>>>(wsb);
  k_gather<<<128, 64, 0, stream>>>(wsb, T);
  k_psola<<<64, 64, 0, stream>>>(pitch, T, S, ratio, wsb, ps, pr);
  hipMemsetAsync(d_out, 0, (size_t)out_size * sizeof(float), stream);
  k_scatter<<<8192, 128, 0, stream>>>(snd, wsb, out, T);
  k_final<<<2048, 256, 0, stream>>>(snd, wsb, out, T);
}

// Round 3
// 16895.514 us; speedup vs baseline: 1.5970x; 1.1010x over previous
//
#include <hip/hip_runtime.h>
#include <math.h>
#include <limits.h>

typedef long long ll;

#define MAXCHAIN 4096
#define MAXP 49152
#define MAXOPS 49152
#define MAXR 64
#define PART_OFF 4096
#define CHAINS_OFF 16384
#define PEAKS_OFF (CHAINS_OFF + 128 * MAXCHAIN * 4)
#define OPS_OFF (PEAKS_OFF + MAXP * 4)
#define F0_OFF (OPS_OFF + (size_t)MAXOPS * 16)

static __device__ const double TWOPI = 6.283185307179586;

struct Ctrl {
  double gpeak, max_w, ps64;
  long long k_rem, tail;
  float mean32, median_raw, md32, minv_scaled32;
  unsigned amax_bits, minf0_bits, prefix;
  int cnt_pos, shift, n_starts, n_ends, nregions, n_peaks, n_ops;
  int hist[256];
  int region_start[MAXR], region_end[MAXR];
  int chain_cnt[128];
  int chain_off[129];
};

// ---------- exact-arith helpers (no FMA contraction) ----------
__device__ __forceinline__ double dmul(double a, double b) { return __dmul_rn(a, b); }
__device__ __forceinline__ double dadd(double a, double b) { return __dadd_rn(a, b); }
__device__ __forceinline__ double dsub(double a, double b) { return __dadd_rn(a, -b); }
__device__ __forceinline__ float fmul(float a, float b) { return __fmul_rn(a, b); }
__device__ __forceinline__ float fadd(float a, float b) { return __fadd_rn(a, b); }
__device__ __forceinline__ float fsub(float a, float b) { return __fadd_rn(a, -b); }

__device__ __forceinline__ float xval(const float* snd, float mean, ll t) {
  return fsub(snd[t], mean);
}

// f0 = linear interp of pitch, computed exactly as numpy (f64 ops, one f32 round)
__device__ float f0_at(const float* pitch, ll t, ll S, double ratio) {
  double pos = dsub(dmul(dadd((double)t, 0.5), ratio), 0.5);
  double hi = (double)(S - 1);
  pos = fmin(fmax(pos, 0.0), hi);
  double fl = floor(pos);
  ll lo = (ll)fl;
  if (lo < 0) lo = 0;
  if (lo > S - 1) lo = S - 1;
  ll hii = lo + 1; if (hii > S - 1) hii = S - 1;
  double frac = dsub(pos, fl);
  double om = dsub(1.0, frac);
  double v = dadd(dmul((double)pitch[lo], om), dmul((double)pitch[hii], frac));
  return (float)v;
}

// ---- numpy pairwise sum-of-squares over an LDS buffer (n <= 266), + max|x| ----
__device__ float pw_blk_l(const float* __restrict__ buf, int base, int n, float& pk) {
  if (n < 8) {
    float res = 0.0f;
    for (int i = 0; i < n; ++i) {
      float x = buf[base + i];
      pk = fmaxf(pk, fabsf(x));
      res = fadd(res, fmul(x, x));
    }
    return res;
  }
  float x0 = buf[base + 0], x1 = buf[base + 1], x2 = buf[base + 2], x3 = buf[base + 3],
        x4 = buf[base + 4], x5 = buf[base + 5], x6 = buf[base + 6], x7 = buf[base + 7];
  pk = fmaxf(pk, fabsf(x0)); pk = fmaxf(pk, fabsf(x1));
  pk = fmaxf(pk, fabsf(x2)); pk = fmaxf(pk, fabsf(x3));
  pk = fmaxf(pk, fabsf(x4)); pk = fmaxf(pk, fabsf(x5));
  pk = fmaxf(pk, fabsf(x6)); pk = fmaxf(pk, fabsf(x7));
  float r0 = fmul(x0, x0), r1 = fmul(x1, x1), r2 = fmul(x2, x2), r3 = fmul(x3, x3);
  float r4 = fmul(x4, x4), r5 = fmul(x5, x5), r6 = fmul(x6, x6), r7 = fmul(x7, x7);
  int i = 8, lim = n - (n & 7);
  for (; i < lim; i += 8) {
    float y;
    y = buf[base + i + 0]; pk = fmaxf(pk, fabsf(y)); r0 = fadd(r0, fmul(y, y));
    y = buf[base + i + 1]; pk = fmaxf(pk, fabsf(y)); r1 = fadd(r1, fmul(y, y));
    y = buf[base + i + 2]; pk = fmaxf(pk, fabsf(y)); r2 = fadd(r2, fmul(y, y));
    y = buf[base + i + 3]; pk = fmaxf(pk, fabsf(y)); r3 = fadd(r3, fmul(y, y));
    y = buf[base + i + 4]; pk = fmaxf(pk, fabsf(y)); r4 = fadd(r4, fmul(y, y));
    y = buf[base + i + 5]; pk = fmaxf(pk, fabsf(y)); r5 = fadd(r5, fmul(y, y));
    y = buf[base + i + 6]; pk = fmaxf(pk, fabsf(y)); r6 = fadd(r6, fmul(y, y));
    y = buf[base + i + 7]; pk = fmaxf(pk, fabsf(y)); r7 = fadd(r7, fmul(y, y));
  }
  float res = fadd(fadd(fadd(r0, r1), fadd(r2, r3)), fadd(fadd(r4, r5), fadd(r6, r7)));
  for (; i < n; ++i) {
    float y = buf[base + i];
    pk = fmaxf(pk, fabsf(y));
    res = fadd(res, fmul(y, y));
  }
  return res;
}

__device__ float pw_sq_pk_l(const float* __restrict__ buf, int base, int n, float& pk) {
  if (n <= 128) return pw_blk_l(buf, base, n, pk);
  int n2 = (n >> 1); n2 -= (n2 & 7);
  float a = pw_blk_l(buf, base, n2, pk);
  int m = n - n2;
  float b;
  if (m <= 128) {
    b = pw_blk_l(buf, base + n2, m, pk);
  } else {
    int m2 = (m >> 1); m2 -= (m2 & 7);
    float b1 = pw_blk_l(buf, base + n2, m2, pk);
    float b2 = pw_blk_l(buf, base + n2 + m2, m - m2, pk);
    b = fadd(b1, b2);
  }
  return fadd(a, b);
}

// BLAS-sgemv mimic over LDS: identical op order/rounding to the passing version.
__device__ float dot_lds(const float* __restrict__ buf, int base, float divr,
                         const float* __restrict__ tm, int w) {
  float a0 = 0.f, a1 = 0.f, a2 = 0.f, a3 = 0.f, a4 = 0.f, a5 = 0.f, a6 = 0.f, a7 = 0.f;
  int lim = w - (w & 7);
  int k = 0;
  for (; k < lim; k += 8) {
    a0 = __fmaf_rn(__fdiv_rn(buf[base + k + 0], divr), tm[k + 0], a0);
    a1 = __fmaf_rn(__fdiv_rn(buf[base + k + 1], divr), tm[k + 1], a1);
    a2 = __fmaf_rn(__fdiv_rn(buf[base + k + 2], divr), tm[k + 2], a2);
    a3 = __fmaf_rn(__fdiv_rn(buf[base + k + 3], divr), tm[k + 3], a3);
    a4 = __fmaf_rn(__fdiv_rn(buf[base + k + 4], divr), tm[k + 4], a4);
    a5 = __fmaf_rn(__fdiv_rn(buf[base + k + 5], divr), tm[k + 5], a5);
    a6 = __fmaf_rn(__fdiv_rn(buf[base + k + 6], divr), tm[k + 6], a6);
    a7 = __fmaf_rn(__fdiv_rn(buf[base + k + 7], divr), tm[k + 7], a7);
  }
  if (k + 0 < w) a0 = __fmaf_rn(__fdiv_rn(buf[base + k + 0], divr), tm[k + 0], a0);
  if (k + 1 < w) a1 = __fmaf_rn(__fdiv_rn(buf[base + k + 1], divr), tm[k + 1], a1);
  if (k + 2 < w) a2 = __fmaf_rn(__fdiv_rn(buf[base + k + 2], divr), tm[k + 2], a2);
  if (k + 3 < w) a3 = __fmaf_rn(__fdiv_rn(buf[base + k + 3], divr), tm[k + 3], a3);
  if (k + 4 < w) a4 = __fmaf_rn(__fdiv_rn(buf[base + k + 4], divr), tm[k + 4], a4);
  if (k + 5 < w) a5 = __fmaf_rn(__fdiv_rn(buf[base + k + 5], divr), tm[k + 5], a5);
  if (k + 6 < w) a6 = __fmaf_rn(__fdiv_rn(buf[base + k + 6], divr), tm[k + 6], a6);
  return fadd(fadd(fadd(a0, a1), fadd(a2, a3)), fadd(fadd(a4, a5), fadd(a6, a7)));
}

// ---------- kernels ----------
__global__ void k_init(char* wsb) {
  Ctrl* c = (Ctrl*)wsb;
  int t = threadIdx.x;
  for (int b = t; b < 256; b += blockDim.x) c->hist[b] = 0;
  for (int b = t; b < 128; b += blockDim.x) c->chain_cnt[b] = 0;
  if (t == 0) {
    c->amax_bits = 0u; c->minf0_bits = 0xFFFFFFFFu;
    c->cnt_pos = 0; c->n_starts = 0; c->n_ends = 0; c->n_ops = 0;
    c->nregions = 0; c->n_peaks = 0; c->tail = 0;
  }
}

__global__ void k_sum_partial(const float* __restrict__ snd, ll T, char* wsb) {
  __shared__ double sd[256];
  double local = 0.0;
  ll stride = (ll)gridDim.x * blockDim.x;
  for (ll t = (ll)blockIdx.x * blockDim.x + threadIdx.x; t < T; t += stride)
    local += (double)snd[t];
  sd[threadIdx.x] = local; __syncthreads();
  for (int o = 128; o > 0; o >>= 1) {
    if ((int)threadIdx.x < o) sd[threadIdx.x] += sd[threadIdx.x + o];
    __syncthreads();
  }
  if (threadIdx.x == 0) ((double*)(wsb + PART_OFF))[blockIdx.x] = sd[0];
}

__global__ void k_sum_final(char* wsb, ll T, int nparts) {
  __shared__ double sd[256];
  double local = 0.0;
  const double* p = (const double*)(wsb + PART_OFF);
  for (int i = threadIdx.x; i < nparts; i += blockDim.x) local += p[i];
  sd[threadIdx.x] = local; __syncthreads();
  for (int o = 128; o > 0; o >>= 1) {
    if ((int)threadIdx.x < o) sd[threadIdx.x] += sd[threadIdx.x + o];
    __syncthreads();
  }
  if (threadIdx.x == 0) ((Ctrl*)wsb)->mean32 = (float)(sd[0] / (double)T);
}

// cache exact f32 bits of f0 over all T (gated on ws_size)
__global__ void k_f0(const float* __restrict__ pitch, ll T, ll S, double ratio,
                     unsigned* __restrict__ bits) {
  ll stride = (ll)gridDim.x * blockDim.x;
  for (ll t = (ll)blockIdx.x * blockDim.x + threadIdx.x; t < T; t += stride)
    bits[t] = __float_as_uint(f0_at(pitch, t, S, ratio));
}

__global__ void k_scan(const float* __restrict__ snd, const float* __restrict__ pitch,
                       ll T, ll S, double ratio, char* wsb,
                       const unsigned* __restrict__ f0bits, int cached) {
  Ctrl* c = (Ctrl*)wsb;
  float mean = c->mean32;
  __shared__ unsigned smax[256]; __shared__ unsigned smin[256]; __shared__ int scnt[256];
  unsigned mymax = 0u, mymin = 0xFFFFFFFFu; int mycnt = 0;
  ll stride = (ll)gridDim.x * blockDim.x;
  for (ll t = (ll)blockIdx.x * blockDim.x + threadIdx.x; t < T; t += stride) {
    float xv = xval(snd, mean, t);
    unsigned ab = __float_as_uint(fabsf(xv));
    if (ab > mymax) mymax = ab;
    float f = cached ? __uint_as_float(f0bits[t]) : f0_at(pitch, t, S, ratio);
    bool pos = (f > 0.0f);
    if (pos) { ++mycnt; unsigned fb = __float_as_uint(f); if (fb < mymin) mymin = fb; }
    if (t >= 1) {
      float fp = cached ? __uint_as_float(f0bits[t - 1]) : f0_at(pitch, t - 1, S, ratio);
      bool posp = (fp > 0.0f);
      if (pos && (t == 1 || !posp)) {
        int id = atomicAdd(&c->n_starts, 1);
        if (id < MAXR) c->region_start[id] = (int)t;
      }
      if (!pos && posp && (t - 1) >= 1) {
        int id = atomicAdd(&c->n_ends, 1);
        if (id < MAXR) c->region_end[id] = (int)t;
      }
    }
    if (t == T - 1 && pos) {
      int id = atomicAdd(&c->n_ends, 1);
      if (id < MAXR) c->region_end[id] = (int)T;
    }
  }
  smax[threadIdx.x] = mymax; smin[threadIdx.x] = mymin; scnt[threadIdx.x] = mycnt;
  __syncthreads();
  for (int o = 128; o > 0; o >>= 1) {
    if ((int)threadIdx.x < o) {
      if (smax[threadIdx.x + o] > smax[threadIdx.x]) smax[threadIdx.x] = smax[threadIdx.x + o];
      if (smin[threadIdx.x + o] < smin[threadIdx.x]) smin[threadIdx.x] = smin[threadIdx.x + o];
      scnt[threadIdx.x] += scnt[threadIdx.x + o];
    }
    __syncthreads();
  }
  if (threadIdx.x == 0) {
    atomicMax(&c->amax_bits, smax[0]);
    atomicMin(&c->minf0_bits, smin[0]);
    atomicAdd(&c->cnt_pos, scnt[0]);
  }
}

__global__ void k_prep(char* wsb, const float* ps) {
  Ctrl* c = (Ctrl*)wsb;
  int ns = c->n_starts; if (ns > MAXR) ns = MAXR;
  int ne = c->n_ends; if (ne > MAXR) ne = MAXR;
  for (int a = 1; a < ns; ++a) {
    int v = c->region_start[a]; int b = a - 1;
    while (b >= 0 && c->region_start[b] > v) { c->region_start[b + 1] = c->region_start[b]; --b; }
    c->region_start[b + 1] = v;
  }
  for (int a = 1; a < ne; ++a) {
    int v = c->region_end[a]; int b = a - 1;
    while (b >= 0 && c->region_end[b] > v) { c->region_end[b + 1] = c->region_end[b]; --b; }
    c->region_end[b + 1] = v;
  }
  int nr = ns < ne ? ns : ne;
  c->nregions = nr;
  c->tail = (nr > 0) ? (ll)c->region_end[nr - 1] : 0;
  c->gpeak = (double)__uint_as_float(c->amax_bits);
  ll cnt = (ll)c->cnt_pos; if (cnt < 1) cnt = 1;
  c->k_rem = (cnt - 1) / 2;
  c->prefix = 0u; c->shift = 24;
  double p64 = (double)ps[0];
  c->ps64 = round(p64 * 1e7) / 1e7;
}

__global__ void k_hist(const float* __restrict__ pitch, ll T, ll S, double ratio, char* wsb,
                       const unsigned* __restrict__ f0bits, int cached) {
  Ctrl* c = (Ctrl*)wsb;
  __shared__ int h[256];
  for (int b = threadIdx.x; b < 256; b += blockDim.x) h[b] = 0;
  __syncthreads();
  int shift = c->shift;
  unsigned pref = c->prefix;
  unsigned himask = (shift == 24) ? 0u : ((~0u) << (shift + 8));
  ll stride = (ll)gridDim.x * blockDim.x;
  for (ll t = (ll)blockIdx.x * blockDim.x + threadIdx.x; t < T; t += stride) {
    float f; unsigned bits;
    if (cached) { bits = f0bits[t]; f = __uint_as_float(bits); }
    else { f = f0_at(pitch, t, S, ratio); bits = __float_as_uint(f); }
    if (f > 0.0f) {
      if ((bits & himask) == (pref & himask)) atomicAdd(&h[(bits >> shift) & 255], 1);
    }
  }
  __syncthreads();
  for (int b = threadIdx.x; b < 256; b += blockDim.x) if (h[b]) atomicAdd(&c->hist[b], h[b]);
}

__global__ void k_sel(char* wsb, const float* ps, const float* pr) {
  Ctrl* c = (Ctrl*)wsb;
  int shift = c->shift;
  ll k = c->k_rem;
  ll run = 0; int pick = 255;
  for (int b = 0; b < 256; ++b) {
    ll h = (ll)c->hist[b];
    if (run + h > k) { pick = b; break; }
    run += h;
  }
  c->prefix |= ((unsigned)pick) << shift;
  c->k_rem = k - run;
  for (int b = 0; b < 256; ++b) c->hist[b] = 0;
  if (shift == 0) {
    float mraw = __uint_as_float(c->prefix);
    c->median_raw = mraw;
    double md = dmul((double)mraw, c->ps64);
    float md32 = (float)md;
    c->md32 = md32;
    float minf = __uint_as_float(c->minf0_bits);
    float u = fmul(minf, ps[0]);
    float sc = fadd(md32, fmul(fsub(u, md32), pr[0]));
    c->minv_scaled32 = sc;
    c->max_w = 20000.0 / (double)sc;
  }
  c->shift = shift - 8;
}

#define WALK_MAXI 400000

// One wave per chain. Per step: stage the whole window into LDS with coalesced
// loads (one latency round), then norms/dot all read LDS. Template broadcast
// via LDS read (replaces bpermute shfls). Argmax via shfl_xor butterfly.
__global__ __launch_bounds__(64) void k_walks(const float* __restrict__ snd,
                                              const float* __restrict__ pitch,
                                              ll T, ll S, double ratio, char* wsb,
                                              const unsigned* __restrict__ f0bits, int cached) {
  Ctrl* c = (Ctrl*)wsb;
  int chain = blockIdx.x;
  int reg = chain >> 1, dir = chain & 1;  // dir 0 = left walk, 1 = right walk
  if (reg >= c->nregions) return;
  int* mybuf = ((int*)(wsb + CHAINS_OFF)) + (ll)chain * MAXCHAIN;
  ll left = (ll)c->region_start[reg];
  ll right = (ll)c->region_end[reg];
  float mean = c->mean32;
  double gpeak = c->gpeak;
  int lane = threadIdx.x;

  __shared__ float lx[608];   // staged mean-subtracted window
  __shared__ float ltm[272];  // normalized template

  // initial position (all lanes redundantly; identical deterministic arithmetic)
  ll i;
  {
    ll middle = (left + right) / 2;
    float f0m = cached ? __uint_as_float(f0bits[middle]) : f0_at(pitch, middle, S, ratio);
    int w0 = (int)(16000.0 / (double)f0m);
    ll s0 = middle - (ll)(w0 / 2); if (s0 < 0) s0 = 0;
    ll len = T - s0; if (len > (ll)w0) len = (ll)w0;
    float mn = 0.f, mx = 0.f; ll imn = 0, imx = 0; bool first = true;
    for (ll k = 0; k < len; ++k) {
      float v = xval(snd, mean, s0 + k);
      if (first) { mn = mx = v; imn = imx = 0; first = false; }
      else {
        if (v < mn) { mn = v; imn = k; }
        if (v > mx) { mx = v; imx = k; }
      }
    }
    if (mn == mx) i = middle;
    else i = s0 + ((fabs((double)mn) > fabs((double)mx)) ? imn : imx);
  }

  double added_right = -1e308;
  int cnt = 0;
  bool stop = false;

  for (int iter = 0; iter < WALK_MAXI && !stop; ++iter) {
    float f0v = cached ? __uint_as_float(f0bits[i]) : f0_at(pitch, i, S, ratio);
    int w = (int)(16000.0 / fmax((double)f0v, 60.0));  // <= 266
    ll cl, cr;
    if (dir == 0) {
      cl = (ll)dsub((double)i, dmul(1.75, (double)w)); if (cl < 0) cl = 0;
      cr = (ll)dsub((double)i, dmul(1.3, (double)w)); if (cr < 0) cr = 0;
    } else {
      cl = (ll)dadd((double)i, dmul(0.3, (double)w));
      cr = (ll)dadd((double)i, dmul(0.75, (double)w));
    }
    ll s = i - (ll)(w / 2); if (s < 0) s = 0;
    bool valid = !(cl == cr || (T - cl) < (ll)w || (s + (ll)w) > T);
    double corrd; ll ipos; double peakd;
    if (!valid) { corrd = -1.0; ipos = i; peakd = 0.0; }
    else {
      ll L = cr + (ll)w; if (L > T) L = T; L -= cl;
      int ncand = (int)(L - (ll)w + 1);           // 1..121
      // stage window [lo, hi) into LDS, mean-subtracted
      ll lo = (s < cl) ? s : cl;
      ll hiA = s + (ll)w;
      ll hiB = cl + L;
      ll hi = (hiA > hiB) ? hiA : hiB;
      int len = (int)(hi - lo);
      __syncthreads();  // guard vs previous iteration's LDS reads
      for (int k = lane; k < len; k += 64) lx[k] = fsub(snd[lo + k], mean);
      __syncthreads();
      int toff = (int)(s - lo);
      int coff = (int)(cl - lo);
      // template norm (all lanes redundantly; LDS broadcast reads)
      float dummy = 0.0f;
      float tn = __fsqrt_rn(pw_sq_pk_l(lx, toff, w, dummy));
      float tdiv = (float)fmax((double)tn, 1e-12);
      // normalized template -> LDS
      for (int k = lane; k < w; k += 64) ltm[k] = __fdiv_rn(lx[toff + k], tdiv);
      __syncthreads();
      // candidate slot 0: r = lane (clamped keeps all lanes in-bounds)
      int r0 = lane;
      int rc0 = (r0 < ncand) ? r0 : (ncand - 1);
      float pk0 = 0.0f;
      float nr0 = __fsqrt_rn(pw_sq_pk_l(lx, coff + rc0, w, pk0));
      float divr0 = fmaxf(nr0, (float)1e-12);
      float co0 = dot_lds(lx, coff + rc0, divr0, ltm, w);
      // candidate slot 1 (uniform branch)
      float pk1 = 0.0f, co1 = -INFINITY;
      if (ncand > 64) {
        int r1 = lane + 64;
        int rc1 = (r1 < ncand) ? r1 : (ncand - 1);
        float nr1 = __fsqrt_rn(pw_sq_pk_l(lx, coff + rc1, w, pk1));
        float divr1 = fmaxf(nr1, (float)1e-12);
        co1 = dot_lds(lx, coff + rc1, divr1, ltm, w);
        if (r1 >= ncand) co1 = -INFINITY;
      }
      // fold slots (prefer higher corr; ties -> lower index)
      float bv = (r0 < ncand) ? co0 : -INFINITY;
      int bi = (r0 < ncand) ? r0 : 0x7FFFFFFF;
      {
        int i1 = lane + 64;
        if (co1 > bv || (co1 == bv && i1 < bi)) { bv = co1; bi = i1; }
      }
      // butterfly argmax (first-occurrence tie-break, matches serial scan)
      for (int off = 32; off > 0; off >>= 1) {
        float ov = __shfl_xor(bv, off);
        int oi = __shfl_xor(bi, off);
        if (ov > bv || (ov == bv && oi < bi)) { bv = ov; bi = oi; }
      }
      corrd = (double)bv;
      ipos = i + ((ll)bi + cl) - s;
      {
        int ol = bi & 63;
        float p0 = __shfl(pk0, ol);
        float p1 = __shfl(pk1, ol);
        peakd = (double)((bi < 64) ? p0 : p1);
      }
    }
    // decision (all lanes redundantly; lane 0 writes)
    ll inew;
    if (dir == 0) {
      inew = (corrd == -1.0) ? (i - (ll)w) : ipos;
      if (inew < left) {
        if (corrd > 0.7 && peakd > dmul(0.023333, gpeak) &&
            (dsub((double)inew, added_right) > dmul(0.8, (double)w))) {
          if (cnt < MAXCHAIN) { if (lane == 0) mybuf[cnt] = (int)inew; ++cnt; }
        }
        stop = true;
      } else {
        if (corrd > 0.3 && (peakd == 0.0 || peakd > dmul(0.01, gpeak))) {
          if (dsub((double)inew, added_right) > dmul(0.8, (double)w)) {
            if (cnt < MAXCHAIN) { if (lane == 0) mybuf[cnt] = (int)inew; ++cnt; }
          }
        }
        i = inew;
      }
    } else {
      inew = (corrd == -1.0) ? (i + (ll)w) : ipos;
      if (inew >= right) {
        if (corrd > 0.7 && peakd > dmul(0.023333, gpeak)) {
          if (cnt < MAXCHAIN) { if (lane == 0) mybuf[cnt] = (int)inew; ++cnt; }
        }
        stop = true;
      } else {
        if (corrd > 0.3 && (peakd == 0.0 || peakd > dmul(0.01, gpeak))) {
          if (cnt < MAXCHAIN) { if (lane == 0) mybuf[cnt] = (int)inew; ++cnt; }
          added_right = (double)inew;
        }
        i = inew;
      }
    }
  }
  if (lane == 0) c->chain_cnt[chain] = cnt;
}

__global__ void k_offsets(char* wsb) {
  Ctrl* c = (Ctrl*)wsb;
  int off = 0;
  for (int ch = 0; ch < 128; ++ch) {
    c->chain_off[ch] = off;
    off += c->chain_cnt[ch];
  }
  c->chain_off[128] = off;
  c->n_peaks = (off > MAXP) ? MAXP : off;
}

__global__ void k_gather(char* wsb, ll T) {
  Ctrl* c = (Ctrl*)wsb;
  int chain = blockIdx.x;
  int cnt = c->chain_cnt[chain];
  int off = c->chain_off[chain];
  const int* mybuf = ((const int*)(wsb + CHAINS_OFF)) + (ll)chain * MAXCHAIN;
  int* peaks = (int*)(wsb + PEAKS_OFF);
  int dir = chain & 1;
  for (int k = threadIdx.x; k < cnt; k += blockDim.x) {
    if (off + k < MAXP) {
      int v = dir ? mybuf[k] : mybuf[cnt - 1 - k];  // left chains stored descending
      if (v < 0) v = 0;
      if ((ll)v > T - 1) v = (int)(T - 1);
      peaks[off + k] = v;
    }
  }
}

__global__ void k_psola(const float* __restrict__ pitch, ll T, ll S, double ratio,
                        char* wsb, const float* ps, const float* pr,
                        const unsigned* __restrict__ f0bits, int cached) {
  if (threadIdx.x != 0) return;
  Ctrl* c = (Ctrl*)wsb;
  int r = blockIdx.x;
  if (r >= c->nregions) return;
  const int* peaks = (const int*)(wsb + PEAKS_OFF);
  int np = c->n_peaks;
  int4* ops = (int4*)(wsb + OPS_OFF);
  ll prev_end = (r == 0) ? 0 : (ll)c->region_end[r - 1];
  ll lv = (ll)c->region_start[r], rv = (ll)c->region_end[r];
  double max_w = c->max_w;
  float md32 = c->md32, psv = ps[0], prv = pr[0];

  ll gapn = lv - prev_end;
  if (gapn > 0) {
    int o = atomicAdd(&c->n_ops, 1);
    if (o < MAXOPS) ops[o] = make_int4((int)prev_end, (int)prev_end, (int)gapn, (int)gapn);
  }
  if (np <= 0) return;
  // binary search: first index with peaks[idx] >= lv (replaces O(np) linear scan)
  int j;
  {
    int loJ = 0, hiJ = np;
    while (loJ < hiJ) {
      int mid = (loJ + hiJ) >> 1;
      if ((ll)peaks[mid] < lv) loJ = mid + 1; else hiJ = mid;
    }
    j = loJ;
  }
  for (long itc = 0; itc < 2000000 && lv < rv; ++itc) {
    float f = cached ? __uint_as_float(f0bits[lv]) : f0_at(pitch, lv, S, ratio);
    float u = fmul(f, psv);
    float fs = (!(u > 0.0f)) ? 0.0f : fadd(md32, fmul(fsub(u, md32), prv));
    int period = (int)(16000.0 / fmax((double)fs, 60.0));
    int lw = period / 2, rw = period / 2;
    while (j < np && (ll)peaks[j] < lv) ++j;
    ll dl = (j > 0) ? (lv - (ll)peaks[j - 1]) : LLONG_MAX;
    ll dr = (j < np) ? ((ll)peaks[j] - lv) : LLONG_MAX;
    int p;
    if (dl <= dr) {
      int q = j - 1; int v = peaks[q];
      while (q > 0 && peaks[q - 1] == v) --q;
      p = q;
    } else {
      int q = j; int v = peaks[q];
      while (q > 0 && peaks[q - 1] == v) --q;
      p = q;
    }
    if (p > 0) {
      ll g = (ll)peaks[p] - (ll)peaks[p - 1];
      if ((double)g <= max_w && g < (ll)lw) lw = (int)g;
    }
    if (p < np - 1) {
      ll g = (ll)peaks[p + 1] - (ll)peaks[p];
      if ((double)g <= max_w && g < (ll)rw) rw = (int)g;
    }
    ll li = (ll)peaks[p] - (ll)lw; if (li < 0) li = 0;
    ll ri = (ll)peaks[p] + (ll)rw;
    ll ival = (ri - li) / 2;
    if (ival <= 0) { lv += (period > 1 ? (ll)period : 1); continue; }
    ll a = lv - ival, b = lv + ival;
    ll st = (a < 0) ? ((a + T > 0) ? a + T : 0) : ((a < T) ? a : T);
    ll sp = (b < 0) ? ((b + T > 0) ? b + T : 0) : ((b < T) ? b : T);
    ll dst_len = sp - st; if (dst_len < 0) dst_len = 0;
    ll se = li + 2 * ival; if (se > T) se = T;
    ll src_len = se - li; if (src_len < 0) src_len = 0;
    ll seglen = dst_len < src_len ? dst_len : src_len;
    if (seglen > 0) {
      int o = atomicAdd(&c->n_ops, 1);
      if (o < MAXOPS) ops[o] = make_int4((int)st, (int)li, (int)seglen, (int)(2 * ival));
    }
    lv += 2 * ival;
  }
}

__global__ void k_scatter(const float* __restrict__ snd, char* wsb, float* out, ll T) {
  Ctrl* c = (Ctrl*)wsb;
  float mean = c->mean32;
  int nops = c->n_ops; if (nops > MAXOPS) nops = MAXOPS;
  const int4* ops = (const int4*)(wsb + OPS_OFF);
  for (int o = blockIdx.x; o < nops; o += gridDim.x) {
    int4 op = ops[o];
    ll dst = (ll)op.x, src = (ll)op.y; int n = op.z, m = op.w;
    for (int k = threadIdx.x; k < n; k += blockDim.x) {
      double ang = dmul(TWOPI, (double)k) / (double)m;
      float w32 = (float)dsub(0.5, dmul(0.5, cos(ang)));
      float val = fmul(w32, xval(snd, mean, src + k));
      atomicAdd(&out[dst + k], val);
    }
  }
}

__global__ void k_final(const float* __restrict__ snd, char* wsb, float* out, ll T) {
  Ctrl* c = (Ctrl*)wsb;
  float mean = c->mean32;
  ll tail = c->tail;
  ll stride = (ll)gridDim.x * blockDim.x;
  for (ll t = (ll)blockIdx.x * blockDim.x + threadIdx.x; t < T; t += stride)
    if (t >= tail) out[t] = xval(snd, mean, t);
}

extern "C" void kernel_launch(void* const* d_in, const int* in_sizes, int n_in,
                              void* d_out, int out_size, void* d_ws, size_t ws_size,
                              hipStream_t stream) {
  ll T = (ll)in_sizes[0];
  ll S = (ll)in_sizes[1];
  const float* snd = (const float*)d_in[0];
  const float* pitch = (const float*)d_in[1];
  const float* ps = (const float*)d_in[2];
  const float* pr = (const float*)d_in[3];
  float* out = (float*)d_out;
  char* wsb = (char*)d_ws;
  double ratio = (double)S / (double)T;

  size_t f0_need = F0_OFF + (size_t)T * 4;
  int cached = (ws_size >= f0_need) ? 1 : 0;
  unsigned* f0bits = (unsigned*)(wsb + F0_OFF);

  k_init<<<1, 256, 0, stream>>>(wsb);
  k_sum_partial<<<1024, 256, 0, stream>>>(snd, T, wsb);
  k_sum_final<<<1, 256, 0, stream>>>(wsb, T, 1024);
  if (cached) k_f0<<<2048, 256, 0, stream>>>(pitch, T, S, ratio, f0bits);
  k_scan<<<2048, 256, 0, stream>>>(snd, pitch, T, S, ratio, wsb, f0bits, cached);
  k_prep<<<1, 1, 0, stream>>>(wsb, ps);
  for (int pass = 0; pass < 4; ++pass) {
    k_hist<<<2048, 256, 0, stream>>>(pitch, T, S, ratio, wsb, f0bits, cached);
    k_sel<<<1, 1, 0, stream>>>(wsb, ps, pr);
  }
  k_walks<<<128, 64, 0, stream>>>(snd, pitch, T, S, ratio, wsb, f0bits, cached);
  k_offsets<<<1, 1, 0, stream>>>(wsb);
  k_gather<<<128, 64, 0, stream>>>(wsb, T);
  k_psola<<<64, 64, 0, stream>>>(pitch, T, S, ratio, wsb, ps, pr, f0bits, cached);
  hipMemsetAsync(d_out, 0, (size_t)out_size * sizeof(float), stream);
  k_scatter<<<8192, 128, 0, stream>>>(snd, wsb, out, T);
  k_final<<<2048, 256, 0, stream>>>(snd, wsb, out, T);
}

// Round 4
// 14167.255 us; speedup vs baseline: 1.9045x; 1.1926x over previous
//
#include <hip/hip_runtime.h>
#include <math.h>
#include <limits.h>

typedef long long ll;

#define MAXCHAIN 4096
#define MAXP 49152
#define MAXOPS 49152
#define MAXR 64
#define PART_OFF 4096
#define CHAINS_OFF 16384
#define PEAKS_OFF (CHAINS_OFF + 128 * MAXCHAIN * 4)
#define OPS_OFF (PEAKS_OFF + MAXP * 4)
#define F0_OFF (OPS_OFF + (size_t)MAXOPS * 16)

static __device__ const double TWOPI = 6.283185307179586;

struct Ctrl {
  double gpeak, max_w, ps64;
  long long k_rem, tail;
  float mean32, median_raw, md32, minv_scaled32;
  unsigned amax_bits, minf0_bits, prefix;
  int cnt_pos, shift, n_starts, n_ends, nregions, n_peaks, n_ops;
  int hist[256];
  int region_start[MAXR], region_end[MAXR];
  int chain_cnt[128];
  int chain_off[129];
};

// ---------- exact-arith helpers (no FMA contraction) ----------
__device__ __forceinline__ double dmul(double a, double b) { return __dmul_rn(a, b); }
__device__ __forceinline__ double dadd(double a, double b) { return __dadd_rn(a, b); }
__device__ __forceinline__ double dsub(double a, double b) { return __dadd_rn(a, -b); }
__device__ __forceinline__ float fmul(float a, float b) { return __fmul_rn(a, b); }
__device__ __forceinline__ float fadd(float a, float b) { return __fadd_rn(a, b); }
__device__ __forceinline__ float fsub(float a, float b) { return __fadd_rn(a, -b); }

__device__ __forceinline__ float xval(const float* snd, float mean, ll t) {
  return fsub(snd[t], mean);
}

// Markstein correctly-rounded division: r = RN(1/d) precomputed.
// q' = RN(x/d) bitwise == __fdiv_rn(x, d) for normal operands (RN mode).
__device__ __forceinline__ float div_exact(float x, float d, float r) {
  float q = __fmul_rn(x, r);
  float e = __fmaf_rn(-d, q, x);
  return __fmaf_rn(e, r, q);
}

// f0 = linear interp of pitch, computed exactly as numpy (f64 ops, one f32 round)
__device__ float f0_at(const float* pitch, ll t, ll S, double ratio) {
  double pos = dsub(dmul(dadd((double)t, 0.5), ratio), 0.5);
  double hi = (double)(S - 1);
  pos = fmin(fmax(pos, 0.0), hi);
  double fl = floor(pos);
  ll lo = (ll)fl;
  if (lo < 0) lo = 0;
  if (lo > S - 1) lo = S - 1;
  ll hii = lo + 1; if (hii > S - 1) hii = S - 1;
  double frac = dsub(pos, fl);
  double om = dsub(1.0, frac);
  double v = dadd(dmul((double)pitch[lo], om), dmul((double)pitch[hii], frac));
  return (float)v;
}

// ---- numpy pairwise sum-of-squares over an LDS buffer (n <= 266), + max|x| ----
__device__ float pw_blk_l(const float* __restrict__ buf, int base, int n, float& pk) {
  if (n < 8) {
    float res = 0.0f;
    for (int i = 0; i < n; ++i) {
      float x = buf[base + i];
      pk = fmaxf(pk, fabsf(x));
      res = fadd(res, fmul(x, x));
    }
    return res;
  }
  float x0 = buf[base + 0], x1 = buf[base + 1], x2 = buf[base + 2], x3 = buf[base + 3],
        x4 = buf[base + 4], x5 = buf[base + 5], x6 = buf[base + 6], x7 = buf[base + 7];
  pk = fmaxf(pk, fabsf(x0)); pk = fmaxf(pk, fabsf(x1));
  pk = fmaxf(pk, fabsf(x2)); pk = fmaxf(pk, fabsf(x3));
  pk = fmaxf(pk, fabsf(x4)); pk = fmaxf(pk, fabsf(x5));
  pk = fmaxf(pk, fabsf(x6)); pk = fmaxf(pk, fabsf(x7));
  float r0 = fmul(x0, x0), r1 = fmul(x1, x1), r2 = fmul(x2, x2), r3 = fmul(x3, x3);
  float r4 = fmul(x4, x4), r5 = fmul(x5, x5), r6 = fmul(x6, x6), r7 = fmul(x7, x7);
  int i = 8, lim = n - (n & 7);
  for (; i < lim; i += 8) {
    float y;
    y = buf[base + i + 0]; pk = fmaxf(pk, fabsf(y)); r0 = fadd(r0, fmul(y, y));
    y = buf[base + i + 1]; pk = fmaxf(pk, fabsf(y)); r1 = fadd(r1, fmul(y, y));
    y = buf[base + i + 2]; pk = fmaxf(pk, fabsf(y)); r2 = fadd(r2, fmul(y, y));
    y = buf[base + i + 3]; pk = fmaxf(pk, fabsf(y)); r3 = fadd(r3, fmul(y, y));
    y = buf[base + i + 4]; pk = fmaxf(pk, fabsf(y)); r4 = fadd(r4, fmul(y, y));
    y = buf[base + i + 5]; pk = fmaxf(pk, fabsf(y)); r5 = fadd(r5, fmul(y, y));
    y = buf[base + i + 6]; pk = fmaxf(pk, fabsf(y)); r6 = fadd(r6, fmul(y, y));
    y = buf[base + i + 7]; pk = fmaxf(pk, fabsf(y)); r7 = fadd(r7, fmul(y, y));
  }
  float res = fadd(fadd(fadd(r0, r1), fadd(r2, r3)), fadd(fadd(r4, r5), fadd(r6, r7)));
  for (; i < n; ++i) {
    float y = buf[base + i];
    pk = fmaxf(pk, fabsf(y));
    res = fadd(res, fmul(y, y));
  }
  return res;
}

__device__ float pw_sq_pk_l(const float* __restrict__ buf, int base, int n, float& pk) {
  if (n <= 128) return pw_blk_l(buf, base, n, pk);
  int n2 = (n >> 1); n2 -= (n2 & 7);
  float a = pw_blk_l(buf, base, n2, pk);
  int m = n - n2;
  float b;
  if (m <= 128) {
    b = pw_blk_l(buf, base + n2, m, pk);
  } else {
    int m2 = (m >> 1); m2 -= (m2 & 7);
    float b1 = pw_blk_l(buf, base + n2, m2, pk);
    float b2 = pw_blk_l(buf, base + n2 + m2, m - m2, pk);
    b = fadd(b1, b2);
  }
  return fadd(a, b);
}

// BLAS-sgemv mimic over LDS. Division via Markstein (bitwise == __fdiv_rn).
__device__ float dot_lds(const float* __restrict__ buf, int base, float d, float r,
                         const float* __restrict__ tm, int w) {
  float a0 = 0.f, a1 = 0.f, a2 = 0.f, a3 = 0.f, a4 = 0.f, a5 = 0.f, a6 = 0.f, a7 = 0.f;
  int lim = w - (w & 7);
  int k = 0;
  for (; k < lim; k += 8) {
    a0 = __fmaf_rn(div_exact(buf[base + k + 0], d, r), tm[k + 0], a0);
    a1 = __fmaf_rn(div_exact(buf[base + k + 1], d, r), tm[k + 1], a1);
    a2 = __fmaf_rn(div_exact(buf[base + k + 2], d, r), tm[k + 2], a2);
    a3 = __fmaf_rn(div_exact(buf[base + k + 3], d, r), tm[k + 3], a3);
    a4 = __fmaf_rn(div_exact(buf[base + k + 4], d, r), tm[k + 4], a4);
    a5 = __fmaf_rn(div_exact(buf[base + k + 5], d, r), tm[k + 5], a5);
    a6 = __fmaf_rn(div_exact(buf[base + k + 6], d, r), tm[k + 6], a6);
    a7 = __fmaf_rn(div_exact(buf[base + k + 7], d, r), tm[k + 7], a7);
  }
  if (k + 0 < w) a0 = __fmaf_rn(div_exact(buf[base + k + 0], d, r), tm[k + 0], a0);
  if (k + 1 < w) a1 = __fmaf_rn(div_exact(buf[base + k + 1], d, r), tm[k + 1], a1);
  if (k + 2 < w) a2 = __fmaf_rn(div_exact(buf[base + k + 2], d, r), tm[k + 2], a2);
  if (k + 3 < w) a3 = __fmaf_rn(div_exact(buf[base + k + 3], d, r), tm[k + 3], a3);
  if (k + 4 < w) a4 = __fmaf_rn(div_exact(buf[base + k + 4], d, r), tm[k + 4], a4);
  if (k + 5 < w) a5 = __fmaf_rn(div_exact(buf[base + k + 5], d, r), tm[k + 5], a5);
  if (k + 6 < w) a6 = __fmaf_rn(div_exact(buf[base + k + 6], d, r), tm[k + 6], a6);
  return fadd(fadd(fadd(a0, a1), fadd(a2, a3)), fadd(fadd(a4, a5), fadd(a6, a7)));
}

// ---------- kernels ----------
__global__ void k_init(char* wsb) {
  Ctrl* c = (Ctrl*)wsb;
  int t = threadIdx.x;
  for (int b = t; b < 256; b += blockDim.x) c->hist[b] = 0;
  for (int b = t; b < 128; b += blockDim.x) c->chain_cnt[b] = 0;
  if (t == 0) {
    c->amax_bits = 0u; c->minf0_bits = 0xFFFFFFFFu;
    c->cnt_pos = 0; c->n_starts = 0; c->n_ends = 0; c->n_ops = 0;
    c->nregions = 0; c->n_peaks = 0; c->tail = 0;
  }
}

__global__ void k_sum_partial(const float* __restrict__ snd, ll T, char* wsb) {
  __shared__ double sd[256];
  double local = 0.0;
  ll stride = (ll)gridDim.x * blockDim.x;
  for (ll t = (ll)blockIdx.x * blockDim.x + threadIdx.x; t < T; t += stride)
    local += (double)snd[t];
  sd[threadIdx.x] = local; __syncthreads();
  for (int o = 128; o > 0; o >>= 1) {
    if ((int)threadIdx.x < o) sd[threadIdx.x] += sd[threadIdx.x + o];
    __syncthreads();
  }
  if (threadIdx.x == 0) ((double*)(wsb + PART_OFF))[blockIdx.x] = sd[0];
}

__global__ void k_sum_final(char* wsb, ll T, int nparts) {
  __shared__ double sd[256];
  double local = 0.0;
  const double* p = (const double*)(wsb + PART_OFF);
  for (int i = threadIdx.x; i < nparts; i += blockDim.x) local += p[i];
  sd[threadIdx.x] = local; __syncthreads();
  for (int o = 128; o > 0; o >>= 1) {
    if ((int)threadIdx.x < o) sd[threadIdx.x] += sd[threadIdx.x + o];
    __syncthreads();
  }
  if (threadIdx.x == 0) ((Ctrl*)wsb)->mean32 = (float)(sd[0] / (double)T);
}

// cache exact f32 bits of f0 over all T (gated on ws_size)
__global__ void k_f0(const float* __restrict__ pitch, ll T, ll S, double ratio,
                     unsigned* __restrict__ bits) {
  ll stride = (ll)gridDim.x * blockDim.x;
  for (ll t = (ll)blockIdx.x * blockDim.x + threadIdx.x; t < T; t += stride)
    bits[t] = __float_as_uint(f0_at(pitch, t, S, ratio));
}

__global__ void k_scan(const float* __restrict__ snd, const float* __restrict__ pitch,
                       ll T, ll S, double ratio, char* wsb,
                       const unsigned* __restrict__ f0bits, int cached) {
  Ctrl* c = (Ctrl*)wsb;
  float mean = c->mean32;
  __shared__ unsigned smax[256]; __shared__ unsigned smin[256]; __shared__ int scnt[256];
  unsigned mymax = 0u, mymin = 0xFFFFFFFFu; int mycnt = 0;
  ll stride = (ll)gridDim.x * blockDim.x;
  for (ll t = (ll)blockIdx.x * blockDim.x + threadIdx.x; t < T; t += stride) {
    float xv = xval(snd, mean, t);
    unsigned ab = __float_as_uint(fabsf(xv));
    if (ab > mymax) mymax = ab;
    float f = cached ? __uint_as_float(f0bits[t]) : f0_at(pitch, t, S, ratio);
    bool pos = (f > 0.0f);
    if (pos) { ++mycnt; unsigned fb = __float_as_uint(f); if (fb < mymin) mymin = fb; }
    if (t >= 1) {
      float fp = cached ? __uint_as_float(f0bits[t - 1]) : f0_at(pitch, t - 1, S, ratio);
      bool posp = (fp > 0.0f);
      if (pos && (t == 1 || !posp)) {
        int id = atomicAdd(&c->n_starts, 1);
        if (id < MAXR) c->region_start[id] = (int)t;
      }
      if (!pos && posp && (t - 1) >= 1) {
        int id = atomicAdd(&c->n_ends, 1);
        if (id < MAXR) c->region_end[id] = (int)t;
      }
    }
    if (t == T - 1 && pos) {
      int id = atomicAdd(&c->n_ends, 1);
      if (id < MAXR) c->region_end[id] = (int)T;
    }
  }
  smax[threadIdx.x] = mymax; smin[threadIdx.x] = mymin; scnt[threadIdx.x] = mycnt;
  __syncthreads();
  for (int o = 128; o > 0; o >>= 1) {
    if ((int)threadIdx.x < o) {
      if (smax[threadIdx.x + o] > smax[threadIdx.x]) smax[threadIdx.x] = smax[threadIdx.x + o];
      if (smin[threadIdx.x + o] < smin[threadIdx.x]) smin[threadIdx.x] = smin[threadIdx.x + o];
      scnt[threadIdx.x] += scnt[threadIdx.x + o];
    }
    __syncthreads();
  }
  if (threadIdx.x == 0) {
    atomicMax(&c->amax_bits, smax[0]);
    atomicMin(&c->minf0_bits, smin[0]);
    atomicAdd(&c->cnt_pos, scnt[0]);
  }
}

__global__ void k_prep(char* wsb, const float* ps) {
  Ctrl* c = (Ctrl*)wsb;
  int ns = c->n_starts; if (ns > MAXR) ns = MAXR;
  int ne = c->n_ends; if (ne > MAXR) ne = MAXR;
  for (int a = 1; a < ns; ++a) {
    int v = c->region_start[a]; int b = a - 1;
    while (b >= 0 && c->region_start[b] > v) { c->region_start[b + 1] = c->region_start[b]; --b; }
    c->region_start[b + 1] = v;
  }
  for (int a = 1; a < ne; ++a) {
    int v = c->region_end[a]; int b = a - 1;
    while (b >= 0 && c->region_end[b] > v) { c->region_end[b + 1] = c->region_end[b]; --b; }
    c->region_end[b + 1] = v;
  }
  int nr = ns < ne ? ns : ne;
  c->nregions = nr;
  c->tail = (nr > 0) ? (ll)c->region_end[nr - 1] : 0;
  c->gpeak = (double)__uint_as_float(c->amax_bits);
  ll cnt = (ll)c->cnt_pos; if (cnt < 1) cnt = 1;
  c->k_rem = (cnt - 1) / 2;
  c->prefix = 0u; c->shift = 24;
  double p64 = (double)ps[0];
  c->ps64 = round(p64 * 1e7) / 1e7;
}

__global__ void k_hist(const float* __restrict__ pitch, ll T, ll S, double ratio, char* wsb,
                       const unsigned* __restrict__ f0bits, int cached) {
  Ctrl* c = (Ctrl*)wsb;
  __shared__ int h[256];
  for (int b = threadIdx.x; b < 256; b += blockDim.x) h[b] = 0;
  __syncthreads();
  int shift = c->shift;
  unsigned pref = c->prefix;
  unsigned himask = (shift == 24) ? 0u : ((~0u) << (shift + 8));
  ll stride = (ll)gridDim.x * blockDim.x;
  for (ll t = (ll)blockIdx.x * blockDim.x + threadIdx.x; t < T; t += stride) {
    float f; unsigned bits;
    if (cached) { bits = f0bits[t]; f = __uint_as_float(bits); }
    else { f = f0_at(pitch, t, S, ratio); bits = __float_as_uint(f); }
    if (f > 0.0f) {
      if ((bits & himask) == (pref & himask)) atomicAdd(&h[(bits >> shift) & 255], 1);
    }
  }
  __syncthreads();
  for (int b = threadIdx.x; b < 256; b += blockDim.x) if (h[b]) atomicAdd(&c->hist[b], h[b]);
}

__global__ void k_sel(char* wsb, const float* ps, const float* pr) {
  Ctrl* c = (Ctrl*)wsb;
  int shift = c->shift;
  ll k = c->k_rem;
  ll run = 0; int pick = 255;
  for (int b = 0; b < 256; ++b) {
    ll h = (ll)c->hist[b];
    if (run + h > k) { pick = b; break; }
    run += h;
  }
  c->prefix |= ((unsigned)pick) << shift;
  c->k_rem = k - run;
  for (int b = 0; b < 256; ++b) c->hist[b] = 0;
  if (shift == 0) {
    float mraw = __uint_as_float(c->prefix);
    c->median_raw = mraw;
    double md = dmul((double)mraw, c->ps64);
    float md32 = (float)md;
    c->md32 = md32;
    float minf = __uint_as_float(c->minf0_bits);
    float u = fmul(minf, ps[0]);
    float sc = fadd(md32, fmul(fsub(u, md32), pr[0]));
    c->minv_scaled32 = sc;
    c->max_w = 20000.0 / (double)sc;
  }
  c->shift = shift - 8;
}

#define WALK_MAXI 400000

// One wave per chain; LDS-staged window; Markstein divisions; butterfly argmax.
__global__ __launch_bounds__(64) void k_walks(const float* __restrict__ snd,
                                              const float* __restrict__ pitch,
                                              ll T, ll S, double ratio, char* wsb,
                                              const unsigned* __restrict__ f0bits, int cached) {
  Ctrl* c = (Ctrl*)wsb;
  int chain = blockIdx.x;
  int reg = chain >> 1, dir = chain & 1;  // dir 0 = left walk, 1 = right walk
  if (reg >= c->nregions) return;
  int* mybuf = ((int*)(wsb + CHAINS_OFF)) + (ll)chain * MAXCHAIN;
  ll left = (ll)c->region_start[reg];
  ll right = (ll)c->region_end[reg];
  float mean = c->mean32;
  double gpeak = c->gpeak;
  int lane = threadIdx.x;

  __shared__ float lx[608];   // staged mean-subtracted window
  __shared__ float ltm[272];  // normalized template

  // initial position (all lanes redundantly; identical deterministic arithmetic)
  ll i;
  {
    ll middle = (left + right) / 2;
    float f0m = cached ? __uint_as_float(f0bits[middle]) : f0_at(pitch, middle, S, ratio);
    int w0 = (int)(16000.0 / (double)f0m);
    ll s0 = middle - (ll)(w0 / 2); if (s0 < 0) s0 = 0;
    ll len = T - s0; if (len > (ll)w0) len = (ll)w0;
    float mn = 0.f, mx = 0.f; ll imn = 0, imx = 0; bool first = true;
    for (ll k = 0; k < len; ++k) {
      float v = xval(snd, mean, s0 + k);
      if (first) { mn = mx = v; imn = imx = 0; first = false; }
      else {
        if (v < mn) { mn = v; imn = k; }
        if (v > mx) { mx = v; imx = k; }
      }
    }
    if (mn == mx) i = middle;
    else i = s0 + ((fabs((double)mn) > fabs((double)mx)) ? imn : imx);
  }

  double added_right = -1e308;
  int cnt = 0;
  bool stop = false;

  for (int iter = 0; iter < WALK_MAXI && !stop; ++iter) {
    float f0v = cached ? __uint_as_float(f0bits[i]) : f0_at(pitch, i, S, ratio);
    int w = (int)(16000.0 / fmax((double)f0v, 60.0));  // <= 266
    ll cl, cr;
    if (dir == 0) {
      cl = (ll)dsub((double)i, dmul(1.75, (double)w)); if (cl < 0) cl = 0;
      cr = (ll)dsub((double)i, dmul(1.3, (double)w)); if (cr < 0) cr = 0;
    } else {
      cl = (ll)dadd((double)i, dmul(0.3, (double)w));
      cr = (ll)dadd((double)i, dmul(0.75, (double)w));
    }
    ll s = i - (ll)(w / 2); if (s < 0) s = 0;
    bool valid = !(cl == cr || (T - cl) < (ll)w || (s + (ll)w) > T);
    double corrd; ll ipos; double peakd;
    if (!valid) { corrd = -1.0; ipos = i; peakd = 0.0; }
    else {
      ll L = cr + (ll)w; if (L > T) L = T; L -= cl;
      int ncand = (int)(L - (ll)w + 1);           // 1..121
      // stage window [lo, hi) into LDS, mean-subtracted
      ll lo = (s < cl) ? s : cl;
      ll hiA = s + (ll)w;
      ll hiB = cl + L;
      ll hi = (hiA > hiB) ? hiA : hiB;
      int len = (int)(hi - lo);
      __syncthreads();  // guard vs previous iteration's LDS reads
      for (int k = lane; k < len; k += 64) lx[k] = fsub(snd[lo + k], mean);
      __syncthreads();
      int toff = (int)(s - lo);
      int coff = (int)(cl - lo);
      // template norm (all lanes redundantly; LDS broadcast reads)
      float dummy = 0.0f;
      float tn = __fsqrt_rn(pw_sq_pk_l(lx, toff, w, dummy));
      float tdiv = (float)fmax((double)tn, 1e-12);
      float rt = __fdiv_rn(1.0f, tdiv);
      // normalized template -> LDS (Markstein division == __fdiv_rn bitwise)
      for (int k = lane; k < w; k += 64) ltm[k] = div_exact(lx[toff + k], tdiv, rt);
      __syncthreads();
      // candidate slot 0: r = lane (clamped keeps all lanes in-bounds)
      int r0 = lane;
      int rc0 = (r0 < ncand) ? r0 : (ncand - 1);
      float pk0 = 0.0f;
      float nr0 = __fsqrt_rn(pw_sq_pk_l(lx, coff + rc0, w, pk0));
      float divr0 = fmaxf(nr0, (float)1e-12);
      float rr0 = __fdiv_rn(1.0f, divr0);
      float co0 = dot_lds(lx, coff + rc0, divr0, rr0, ltm, w);
      // candidate slot 1 (uniform branch)
      float pk1 = 0.0f, co1 = -INFINITY;
      if (ncand > 64) {
        int r1 = lane + 64;
        int rc1 = (r1 < ncand) ? r1 : (ncand - 1);
        float nr1 = __fsqrt_rn(pw_sq_pk_l(lx, coff + rc1, w, pk1));
        float divr1 = fmaxf(nr1, (float)1e-12);
        float rr1 = __fdiv_rn(1.0f, divr1);
        co1 = dot_lds(lx, coff + rc1, divr1, rr1, ltm, w);
        if (r1 >= ncand) co1 = -INFINITY;
      }
      // fold slots (prefer higher corr; ties -> lower index)
      float bv = (r0 < ncand) ? co0 : -INFINITY;
      int bi = (r0 < ncand) ? r0 : 0x7FFFFFFF;
      {
        int i1 = lane + 64;
        if (co1 > bv || (co1 == bv && i1 < bi)) { bv = co1; bi = i1; }
      }
      // butterfly argmax (first-occurrence tie-break, matches serial scan)
      for (int off = 32; off > 0; off >>= 1) {
        float ov = __shfl_xor(bv, off);
        int oi = __shfl_xor(bi, off);
        if (ov > bv || (ov == bv && oi < bi)) { bv = ov; bi = oi; }
      }
      corrd = (double)bv;
      ipos = i + ((ll)bi + cl) - s;
      {
        int ol = bi & 63;
        float p0 = __shfl(pk0, ol);
        float p1 = __shfl(pk1, ol);
        peakd = (double)((bi < 64) ? p0 : p1);
      }
    }
    // decision (all lanes redundantly; lane 0 writes)
    ll inew;
    if (dir == 0) {
      inew = (corrd == -1.0) ? (i - (ll)w) : ipos;
      if (inew < left) {
        if (corrd > 0.7 && peakd > dmul(0.023333, gpeak) &&
            (dsub((double)inew, added_right) > dmul(0.8, (double)w))) {
          if (cnt < MAXCHAIN) { if (lane == 0) mybuf[cnt] = (int)inew; ++cnt; }
        }
        stop = true;
      } else {
        if (corrd > 0.3 && (peakd == 0.0 || peakd > dmul(0.01, gpeak))) {
          if (dsub((double)inew, added_right) > dmul(0.8, (double)w)) {
            if (cnt < MAXCHAIN) { if (lane == 0) mybuf[cnt] = (int)inew; ++cnt; }
          }
        }
        i = inew;
      }
    } else {
      inew = (corrd == -1.0) ? (i + (ll)w) : ipos;
      if (inew >= right) {
        if (corrd > 0.7 && peakd > dmul(0.023333, gpeak)) {
          if (cnt < MAXCHAIN) { if (lane == 0) mybuf[cnt] = (int)inew; ++cnt; }
        }
        stop = true;
      } else {
        if (corrd > 0.3 && (peakd == 0.0 || peakd > dmul(0.01, gpeak))) {
          if (cnt < MAXCHAIN) { if (lane == 0) mybuf[cnt] = (int)inew; ++cnt; }
          added_right = (double)inew;
        }
        i = inew;
      }
    }
  }
  if (lane == 0) c->chain_cnt[chain] = cnt;
}

__global__ void k_offsets(char* wsb) {
  Ctrl* c = (Ctrl*)wsb;
  int off = 0;
  for (int ch = 0; ch < 128; ++ch) {
    c->chain_off[ch] = off;
    off += c->chain_cnt[ch];
  }
  c->chain_off[128] = off;
  c->n_peaks = (off > MAXP) ? MAXP : off;
}

__global__ void k_gather(char* wsb, ll T) {
  Ctrl* c = (Ctrl*)wsb;
  int chain = blockIdx.x;
  int cnt = c->chain_cnt[chain];
  int off = c->chain_off[chain];
  const int* mybuf = ((const int*)(wsb + CHAINS_OFF)) + (ll)chain * MAXCHAIN;
  int* peaks = (int*)(wsb + PEAKS_OFF);
  int dir = chain & 1;
  for (int k = threadIdx.x; k < cnt; k += blockDim.x) {
    if (off + k < MAXP) {
      int v = dir ? mybuf[k] : mybuf[cnt - 1 - k];  // left chains stored descending
      if (v < 0) v = 0;
      if ((ll)v > T - 1) v = (int)(T - 1);
      peaks[off + k] = v;
    }
  }
}

#define PSLDS 3584

__global__ __launch_bounds__(64) void k_psola(const float* __restrict__ pitch, ll T, ll S,
                                              double ratio, char* wsb,
                                              const float* ps, const float* pr,
                                              const unsigned* __restrict__ f0bits, int cached) {
  Ctrl* c = (Ctrl*)wsb;
  int r = blockIdx.x;
  if (r >= c->nregions) return;
  const int* peaks = (const int*)(wsb + PEAKS_OFF);
  int np = c->n_peaks;
  int tid = threadIdx.x;
  ll left = (ll)c->region_start[r], right = (ll)c->region_end[r];

  __shared__ int lp[PSLDS];
  __shared__ int sh_g0, sh_g1, sh_use;

  if (np > 0) {
    if (tid == 0) {
      // lower_bound(left-512) and lower_bound(right+512), widened by 4 entries
      int lo = 0, hi = np;
      ll tgt = left - 512;
      while (lo < hi) { int m = (lo + hi) >> 1; if ((ll)peaks[m] < tgt) lo = m + 1; else hi = m; }
      int a = lo;
      lo = 0; hi = np; tgt = right + 512;
      while (lo < hi) { int m = (lo + hi) >> 1; if ((ll)peaks[m] < tgt) lo = m + 1; else hi = m; }
      int b = lo;
      a -= 4; if (a < 0) a = 0;
      b += 4; if (b > np) b = np;
      sh_g0 = a; sh_g1 = b; sh_use = (b - a <= PSLDS) ? 1 : 0;
    }
    __syncthreads();
    if (sh_use) {
      for (int k = sh_g0 + tid; k < sh_g1; k += 64) lp[k - sh_g0] = peaks[k];
    }
    __syncthreads();
  }
  if (tid != 0) return;

  int g0 = (np > 0 && sh_use) ? sh_g0 : 0;
  const int* pk = (np > 0 && sh_use) ? lp : peaks;
  // pk[idx - g0] == peaks[idx] for idx in [g0, g1)

  int4* ops = (int4*)(wsb + OPS_OFF);
  ll prev_end = (r == 0) ? 0 : (ll)c->region_end[r - 1];
  ll lv = left, rv = right;
  double max_w = c->max_w;
  float md32 = c->md32, psv = ps[0], prv = pr[0];

  ll gapn = lv - prev_end;
  if (gapn > 0) {
    int o = atomicAdd(&c->n_ops, 1);
    if (o < MAXOPS) ops[o] = make_int4((int)prev_end, (int)prev_end, (int)gapn, (int)gapn);
  }
  if (np <= 0) return;
  // binary search: first index with peaks[idx] >= lv
  int j;
  {
    int loJ = 0, hiJ = np;
    while (loJ < hiJ) {
      int mid = (loJ + hiJ) >> 1;
      if ((ll)peaks[mid] < lv) loJ = mid + 1; else hiJ = mid;
    }
    j = loJ;
  }
  for (long itc = 0; itc < 2000000 && lv < rv; ++itc) {
    float f = cached ? __uint_as_float(f0bits[lv]) : f0_at(pitch, lv, S, ratio);
    float u = fmul(f, psv);
    float fs = (!(u > 0.0f)) ? 0.0f : fadd(md32, fmul(fsub(u, md32), prv));
    int period = (int)(16000.0 / fmax((double)fs, 60.0));
    int lw = period / 2, rw = period / 2;
    while (j < np && (ll)pk[j - g0] < lv) ++j;
    ll dl = (j > 0) ? (lv - (ll)pk[j - 1 - g0]) : LLONG_MAX;
    ll dr = (j < np) ? ((ll)pk[j - g0] - lv) : LLONG_MAX;
    int p;
    if (dl <= dr) {
      int q = j - 1; int v = pk[q - g0];
      while (q > 0 && pk[q - 1 - g0] == v) --q;
      p = q;
    } else {
      int q = j; int v = pk[q - g0];
      while (q > 0 && pk[q - 1 - g0] == v) --q;
      p = q;
    }
    if (p > 0) {
      ll g = (ll)pk[p - g0] - (ll)pk[p - 1 - g0];
      if ((double)g <= max_w && g < (ll)lw) lw = (int)g;
    }
    if (p < np - 1) {
      ll g = (ll)pk[p + 1 - g0] - (ll)pk[p - g0];
      if ((double)g <= max_w && g < (ll)rw) rw = (int)g;
    }
    ll li = (ll)pk[p - g0] - (ll)lw; if (li < 0) li = 0;
    ll ri = (ll)pk[p - g0] + (ll)rw;
    ll ival = (ri - li) / 2;
    if (ival <= 0) { lv += (period > 1 ? (ll)period : 1); continue; }
    ll a = lv - ival, b = lv + ival;
    ll st = (a < 0) ? ((a + T > 0) ? a + T : 0) : ((a < T) ? a : T);
    ll sp = (b < 0) ? ((b + T > 0) ? b + T : 0) : ((b < T) ? b : T);
    ll dst_len = sp - st; if (dst_len < 0) dst_len = 0;
    ll se = li + 2 * ival; if (se > T) se = T;
    ll src_len = se - li; if (src_len < 0) src_len = 0;
    ll seglen = dst_len < src_len ? dst_len : src_len;
    if (seglen > 0) {
      int o = atomicAdd(&c->n_ops, 1);
      if (o < MAXOPS) ops[o] = make_int4((int)st, (int)li, (int)seglen, (int)(2 * ival));
    }
    lv += 2 * ival;
  }
}

__global__ void k_scatter(const float* __restrict__ snd, char* wsb, float* out, ll T) {
  Ctrl* c = (Ctrl*)wsb;
  float mean = c->mean32;
  int nops = c->n_ops; if (nops > MAXOPS) nops = MAXOPS;
  const int4* ops = (const int4*)(wsb + OPS_OFF);
  for (int o = blockIdx.x; o < nops; o += gridDim.x) {
    int4 op = ops[o];
    ll dst = (ll)op.x, src = (ll)op.y; int n = op.z, m = op.w;
    for (int k = threadIdx.x; k < n; k += blockDim.x) {
      double ang = dmul(TWOPI, (double)k) / (double)m;
      float w32 = (float)dsub(0.5, dmul(0.5, cos(ang)));
      float val = fmul(w32, xval(snd, mean, src + k));
      atomicAdd(&out[dst + k], val);
    }
  }
}

__global__ void k_final(const float* __restrict__ snd, char* wsb, float* out, ll T) {
  Ctrl* c = (Ctrl*)wsb;
  float mean = c->mean32;
  ll tail = c->tail;
  ll stride = (ll)gridDim.x * blockDim.x;
  for (ll t = (ll)blockIdx.x * blockDim.x + threadIdx.x; t < T; t += stride)
    if (t >= tail) out[t] = xval(snd, mean, t);
}

extern "C" void kernel_launch(void* const* d_in, const int* in_sizes, int n_in,
                              void* d_out, int out_size, void* d_ws, size_t ws_size,
                              hipStream_t stream) {
  ll T = (ll)in_sizes[0];
  ll S = (ll)in_sizes[1];
  const float* snd = (const float*)d_in[0];
  const float* pitch = (const float*)d_in[1];
  const float* ps = (const float*)d_in[2];
  const float* pr = (const float*)d_in[3];
  float* out = (float*)d_out;
  char* wsb = (char*)d_ws;
  double ratio = (double)S / (double)T;

  size_t f0_need = F0_OFF + (size_t)T * 4;
  int cached = (ws_size >= f0_need) ? 1 : 0;
  unsigned* f0bits = (unsigned*)(wsb + F0_OFF);

  k_init<<<1, 256, 0, stream>>>(wsb);
  k_sum_partial<<<1024, 256, 0, stream>>>(snd, T, wsb);
  k_sum_final<<<1, 256, 0, stream>>>(wsb, T, 1024);
  if (cached) k_f0<<<2048, 256, 0, stream>>>(pitch, T, S, ratio, f0bits);
  k_scan<<<2048, 256, 0, stream>>>(snd, pitch, T, S, ratio, wsb, f0bits, cached);
  k_prep<<<1, 1, 0, stream>>>(wsb, ps);
  for (int pass = 0; pass < 4; ++pass) {
    k_hist<<<2048, 256, 0, stream>>>(pitch, T, S, ratio, wsb, f0bits, cached);
    k_sel<<<1, 1, 0, stream>>>(wsb, ps, pr);
  }
  k_walks<<<128, 64, 0, stream>>>(snd, pitch, T, S, ratio, wsb, f0bits, cached);
  k_offsets<<<1, 1, 0, stream>>>(wsb);
  k_gather<<<128, 64, 0, stream>>>(wsb, T);
  k_psola<<<64, 64, 0, stream>>>(pitch, T, S, ratio, wsb, ps, pr, f0bits, cached);
  hipMemsetAsync(d_out, 0, (size_t)out_size * sizeof(float), stream);
  k_scatter<<<8192, 128, 0, stream>>>(snd, wsb, out, T);
  k_final<<<2048, 256, 0, stream>>>(snd, wsb, out, T);
}

// Round 5
// 13611.914 us; speedup vs baseline: 1.9822x; 1.0408x over previous
//
#include <hip/hip_runtime.h>
#include <math.h>
#include <limits.h>

typedef long long ll;

#define MAXCHAIN 4096
#define MAXP 49152
#define MAXOPS 49152
#define MAXR 64
#define PART_OFF 4096
#define CHAINS_OFF 16384
#define PEAKS_OFF (CHAINS_OFF + 128 * MAXCHAIN * 4)
#define OPS_OFF (PEAKS_OFF + MAXP * 4)
#define F0_OFF (OPS_OFF + (size_t)MAXOPS * 16)

static __device__ const double TWOPI = 6.283185307179586;

struct Ctrl {
  double gpeak, max_w, ps64;
  long long k_rem, tail;
  float mean32, median_raw, md32, minv_scaled32;
  unsigned amax_bits, minf0_bits, prefix;
  int cnt_pos, shift, n_starts, n_ends, nregions, n_peaks, n_ops, slab;
  int hist[256];
  int region_start[MAXR], region_end[MAXR];
  int chain_cnt[128];
  int chain_off[129];
  int region_ops[MAXR];
};

// ---------- exact-arith helpers (no FMA contraction) ----------
__device__ __forceinline__ double dmul(double a, double b) { return __dmul_rn(a, b); }
__device__ __forceinline__ double dadd(double a, double b) { return __dadd_rn(a, b); }
__device__ __forceinline__ double dsub(double a, double b) { return __dadd_rn(a, -b); }
__device__ __forceinline__ float fmul(float a, float b) { return __fmul_rn(a, b); }
__device__ __forceinline__ float fadd(float a, float b) { return __fadd_rn(a, b); }
__device__ __forceinline__ float fsub(float a, float b) { return __fadd_rn(a, -b); }

__device__ __forceinline__ float xval(const float* snd, float mean, ll t) {
  return fsub(snd[t], mean);
}

// Markstein correctly-rounded division: r = RN(1/d) precomputed.
__device__ __forceinline__ float div_exact(float x, float d, float r) {
  float q = __fmul_rn(x, r);
  float e = __fmaf_rn(-d, q, x);
  return __fmaf_rn(e, r, q);
}

// f0 = linear interp of pitch, computed exactly as numpy (f64 ops, one f32 round)
__device__ float f0_at(const float* pitch, ll t, ll S, double ratio) {
  double pos = dsub(dmul(dadd((double)t, 0.5), ratio), 0.5);
  double hi = (double)(S - 1);
  pos = fmin(fmax(pos, 0.0), hi);
  double fl = floor(pos);
  ll lo = (ll)fl;
  if (lo < 0) lo = 0;
  if (lo > S - 1) lo = S - 1;
  ll hii = lo + 1; if (hii > S - 1) hii = S - 1;
  double frac = dsub(pos, fl);
  double om = dsub(1.0, frac);
  double v = dadd(dmul((double)pitch[lo], om), dmul((double)pitch[hii], frac));
  return (float)v;
}

// frame index used by f0 interp at time t
__device__ __forceinline__ ll frame_lo(ll t, ll S, double ratio) {
  double pos = dsub(dmul(dadd((double)t, 0.5), ratio), 0.5);
  pos = fmin(fmax(pos, 0.0), (double)(S - 1));
  ll lo = (ll)floor(pos);
  if (lo < 0) lo = 0;
  if (lo > S - 1) lo = S - 1;
  return lo;
}

// identical arithmetic to f0_at; pitch values served from LDS slab [p0..p1]
__device__ __forceinline__ float f0_lds(const float* __restrict__ lpitch, int p0, int p1,
                                        const float* __restrict__ pitch,
                                        ll t, ll S, double ratio) {
  double pos = dsub(dmul(dadd((double)t, 0.5), ratio), 0.5);
  pos = fmin(fmax(pos, 0.0), (double)(S - 1));
  double fl = floor(pos);
  ll lo = (ll)fl;
  if (lo < 0) lo = 0;
  if (lo > S - 1) lo = S - 1;
  ll hii = lo + 1; if (hii > S - 1) hii = S - 1;
  double frac = dsub(pos, fl);
  double om = dsub(1.0, frac);
  float plo = (lo >= p0 && lo <= p1) ? lpitch[(int)(lo - p0)] : pitch[lo];
  float phi = (hii >= p0 && hii <= p1) ? lpitch[(int)(hii - p0)] : pitch[hii];
  return (float)dadd(dmul((double)plo, om), dmul((double)phi, frac));
}

// ---- numpy pairwise sum-of-squares over an LDS buffer (n <= 266), + max|x| ----
__device__ float pw_blk_l(const float* __restrict__ buf, int base, int n, float& pk) {
  if (n < 8) {
    float res = 0.0f;
    for (int i = 0; i < n; ++i) {
      float x = buf[base + i];
      pk = fmaxf(pk, fabsf(x));
      res = fadd(res, fmul(x, x));
    }
    return res;
  }
  float x0 = buf[base + 0], x1 = buf[base + 1], x2 = buf[base + 2], x3 = buf[base + 3],
        x4 = buf[base + 4], x5 = buf[base + 5], x6 = buf[base + 6], x7 = buf[base + 7];
  pk = fmaxf(pk, fabsf(x0)); pk = fmaxf(pk, fabsf(x1));
  pk = fmaxf(pk, fabsf(x2)); pk = fmaxf(pk, fabsf(x3));
  pk = fmaxf(pk, fabsf(x4)); pk = fmaxf(pk, fabsf(x5));
  pk = fmaxf(pk, fabsf(x6)); pk = fmaxf(pk, fabsf(x7));
  float r0 = fmul(x0, x0), r1 = fmul(x1, x1), r2 = fmul(x2, x2), r3 = fmul(x3, x3);
  float r4 = fmul(x4, x4), r5 = fmul(x5, x5), r6 = fmul(x6, x6), r7 = fmul(x7, x7);
  int i = 8, lim = n - (n & 7);
  for (; i < lim; i += 8) {
    float y;
    y = buf[base + i + 0]; pk = fmaxf(pk, fabsf(y)); r0 = fadd(r0, fmul(y, y));
    y = buf[base + i + 1]; pk = fmaxf(pk, fabsf(y)); r1 = fadd(r1, fmul(y, y));
    y = buf[base + i + 2]; pk = fmaxf(pk, fabsf(y)); r2 = fadd(r2, fmul(y, y));
    y = buf[base + i + 3]; pk = fmaxf(pk, fabsf(y)); r3 = fadd(r3, fmul(y, y));
    y = buf[base + i + 4]; pk = fmaxf(pk, fabsf(y)); r4 = fadd(r4, fmul(y, y));
    y = buf[base + i + 5]; pk = fmaxf(pk, fabsf(y)); r5 = fadd(r5, fmul(y, y));
    y = buf[base + i + 6]; pk = fmaxf(pk, fabsf(y)); r6 = fadd(r6, fmul(y, y));
    y = buf[base + i + 7]; pk = fmaxf(pk, fabsf(y)); r7 = fadd(r7, fmul(y, y));
  }
  float res = fadd(fadd(fadd(r0, r1), fadd(r2, r3)), fadd(fadd(r4, r5), fadd(r6, r7)));
  for (; i < n; ++i) {
    float y = buf[base + i];
    pk = fmaxf(pk, fabsf(y));
    res = fadd(res, fmul(y, y));
  }
  return res;
}

__device__ float pw_sq_pk_l(const float* __restrict__ buf, int base, int n, float& pk) {
  if (n <= 128) return pw_blk_l(buf, base, n, pk);
  int n2 = (n >> 1); n2 -= (n2 & 7);
  float a = pw_blk_l(buf, base, n2, pk);
  int m = n - n2;
  float b;
  if (m <= 128) {
    b = pw_blk_l(buf, base + n2, m, pk);
  } else {
    int m2 = (m >> 1); m2 -= (m2 & 7);
    float b1 = pw_blk_l(buf, base + n2, m2, pk);
    float b2 = pw_blk_l(buf, base + n2 + m2, m - m2, pk);
    b = fadd(b1, b2);
  }
  return fadd(a, b);
}

// BLAS-sgemv mimic over LDS. Division via Markstein (bitwise == __fdiv_rn).
__device__ float dot_lds(const float* __restrict__ buf, int base, float d, float r,
                         const float* __restrict__ tm, int w) {
  float a0 = 0.f, a1 = 0.f, a2 = 0.f, a3 = 0.f, a4 = 0.f, a5 = 0.f, a6 = 0.f, a7 = 0.f;
  int lim = w - (w & 7);
  int k = 0;
  for (; k < lim; k += 8) {
    a0 = __fmaf_rn(div_exact(buf[base + k + 0], d, r), tm[k + 0], a0);
    a1 = __fmaf_rn(div_exact(buf[base + k + 1], d, r), tm[k + 1], a1);
    a2 = __fmaf_rn(div_exact(buf[base + k + 2], d, r), tm[k + 2], a2);
    a3 = __fmaf_rn(div_exact(buf[base + k + 3], d, r), tm[k + 3], a3);
    a4 = __fmaf_rn(div_exact(buf[base + k + 4], d, r), tm[k + 4], a4);
    a5 = __fmaf_rn(div_exact(buf[base + k + 5], d, r), tm[k + 5], a5);
    a6 = __fmaf_rn(div_exact(buf[base + k + 6], d, r), tm[k + 6], a6);
    a7 = __fmaf_rn(div_exact(buf[base + k + 7], d, r), tm[k + 7], a7);
  }
  if (k + 0 < w) a0 = __fmaf_rn(div_exact(buf[base + k + 0], d, r), tm[k + 0], a0);
  if (k + 1 < w) a1 = __fmaf_rn(div_exact(buf[base + k + 1], d, r), tm[k + 1], a1);
  if (k + 2 < w) a2 = __fmaf_rn(div_exact(buf[base + k + 2], d, r), tm[k + 2], a2);
  if (k + 3 < w) a3 = __fmaf_rn(div_exact(buf[base + k + 3], d, r), tm[k + 3], a3);
  if (k + 4 < w) a4 = __fmaf_rn(div_exact(buf[base + k + 4], d, r), tm[k + 4], a4);
  if (k + 5 < w) a5 = __fmaf_rn(div_exact(buf[base + k + 5], d, r), tm[k + 5], a5);
  if (k + 6 < w) a6 = __fmaf_rn(div_exact(buf[base + k + 6], d, r), tm[k + 6], a6);
  return fadd(fadd(fadd(a0, a1), fadd(a2, a3)), fadd(fadd(a4, a5), fadd(a6, a7)));
}

// ---------- kernels ----------
__global__ void k_init(char* wsb) {
  Ctrl* c = (Ctrl*)wsb;
  int t = threadIdx.x;
  for (int b = t; b < 256; b += blockDim.x) c->hist[b] = 0;
  for (int b = t; b < 128; b += blockDim.x) c->chain_cnt[b] = 0;
  for (int b = t; b < MAXR; b += blockDim.x) c->region_ops[b] = 0;
  if (t == 0) {
    c->amax_bits = 0u; c->minf0_bits = 0xFFFFFFFFu;
    c->cnt_pos = 0; c->n_starts = 0; c->n_ends = 0; c->n_ops = 0;
    c->nregions = 0; c->n_peaks = 0; c->tail = 0; c->slab = MAXOPS;
  }
}

__global__ void k_sum_partial(const float* __restrict__ snd, ll T, char* wsb) {
  __shared__ double sd[256];
  double local = 0.0;
  ll stride = (ll)gridDim.x * blockDim.x;
  for (ll t = (ll)blockIdx.x * blockDim.x + threadIdx.x; t < T; t += stride)
    local += (double)snd[t];
  sd[threadIdx.x] = local; __syncthreads();
  for (int o = 128; o > 0; o >>= 1) {
    if ((int)threadIdx.x < o) sd[threadIdx.x] += sd[threadIdx.x + o];
    __syncthreads();
  }
  if (threadIdx.x == 0) ((double*)(wsb + PART_OFF))[blockIdx.x] = sd[0];
}

__global__ void k_sum_final(char* wsb, ll T, int nparts) {
  __shared__ double sd[256];
  double local = 0.0;
  const double* p = (const double*)(wsb + PART_OFF);
  for (int i = threadIdx.x; i < nparts; i += blockDim.x) local += p[i];
  sd[threadIdx.x] = local; __syncthreads();
  for (int o = 128; o > 0; o >>= 1) {
    if ((int)threadIdx.x < o) sd[threadIdx.x] += sd[threadIdx.x + o];
    __syncthreads();
  }
  if (threadIdx.x == 0) ((Ctrl*)wsb)->mean32 = (float)(sd[0] / (double)T);
}

// cache exact f32 bits of f0 over all T (used by scan/hist bulk passes)
__global__ void k_f0(const float* __restrict__ pitch, ll T, ll S, double ratio,
                     unsigned* __restrict__ bits) {
  ll stride = (ll)gridDim.x * blockDim.x;
  for (ll t = (ll)blockIdx.x * blockDim.x + threadIdx.x; t < T; t += stride)
    bits[t] = __float_as_uint(f0_at(pitch, t, S, ratio));
}

__global__ void k_scan(const float* __restrict__ snd, const float* __restrict__ pitch,
                       ll T, ll S, double ratio, char* wsb,
                       const unsigned* __restrict__ f0bits, int cached) {
  Ctrl* c = (Ctrl*)wsb;
  float mean = c->mean32;
  __shared__ unsigned smax[256]; __shared__ unsigned smin[256]; __shared__ int scnt[256];
  unsigned mymax = 0u, mymin = 0xFFFFFFFFu; int mycnt = 0;
  ll stride = (ll)gridDim.x * blockDim.x;
  for (ll t = (ll)blockIdx.x * blockDim.x + threadIdx.x; t < T; t += stride) {
    float xv = xval(snd, mean, t);
    unsigned ab = __float_as_uint(fabsf(xv));
    if (ab > mymax) mymax = ab;
    float f = cached ? __uint_as_float(f0bits[t]) : f0_at(pitch, t, S, ratio);
    bool pos = (f > 0.0f);
    if (pos) { ++mycnt; unsigned fb = __float_as_uint(f); if (fb < mymin) mymin = fb; }
    if (t >= 1) {
      float fp = cached ? __uint_as_float(f0bits[t - 1]) : f0_at(pitch, t - 1, S, ratio);
      bool posp = (fp > 0.0f);
      if (pos && (t == 1 || !posp)) {
        int id = atomicAdd(&c->n_starts, 1);
        if (id < MAXR) c->region_start[id] = (int)t;
      }
      if (!pos && posp && (t - 1) >= 1) {
        int id = atomicAdd(&c->n_ends, 1);
        if (id < MAXR) c->region_end[id] = (int)t;
      }
    }
    if (t == T - 1 && pos) {
      int id = atomicAdd(&c->n_ends, 1);
      if (id < MAXR) c->region_end[id] = (int)T;
    }
  }
  smax[threadIdx.x] = mymax; smin[threadIdx.x] = mymin; scnt[threadIdx.x] = mycnt;
  __syncthreads();
  for (int o = 128; o > 0; o >>= 1) {
    if ((int)threadIdx.x < o) {
      if (smax[threadIdx.x + o] > smax[threadIdx.x]) smax[threadIdx.x] = smax[threadIdx.x + o];
      if (smin[threadIdx.x + o] < smin[threadIdx.x]) smin[threadIdx.x] = smin[threadIdx.x + o];
      scnt[threadIdx.x] += scnt[threadIdx.x + o];
    }
    __syncthreads();
  }
  if (threadIdx.x == 0) {
    atomicMax(&c->amax_bits, smax[0]);
    atomicMin(&c->minf0_bits, smin[0]);
    atomicAdd(&c->cnt_pos, scnt[0]);
  }
}

__global__ void k_prep(char* wsb, const float* ps) {
  Ctrl* c = (Ctrl*)wsb;
  int ns = c->n_starts; if (ns > MAXR) ns = MAXR;
  int ne = c->n_ends; if (ne > MAXR) ne = MAXR;
  for (int a = 1; a < ns; ++a) {
    int v = c->region_start[a]; int b = a - 1;
    while (b >= 0 && c->region_start[b] > v) { c->region_start[b + 1] = c->region_start[b]; --b; }
    c->region_start[b + 1] = v;
  }
  for (int a = 1; a < ne; ++a) {
    int v = c->region_end[a]; int b = a - 1;
    while (b >= 0 && c->region_end[b] > v) { c->region_end[b + 1] = c->region_end[b]; --b; }
    c->region_end[b + 1] = v;
  }
  int nr = ns < ne ? ns : ne;
  c->nregions = nr;
  c->tail = (nr > 0) ? (ll)c->region_end[nr - 1] : 0;
  c->gpeak = (double)__uint_as_float(c->amax_bits);
  ll cnt = (ll)c->cnt_pos; if (cnt < 1) cnt = 1;
  c->k_rem = (cnt - 1) / 2;
  c->prefix = 0u; c->shift = 24;
  c->slab = MAXOPS / (nr > 0 ? nr : 1);
  double p64 = (double)ps[0];
  c->ps64 = round(p64 * 1e7) / 1e7;
}

__global__ void k_hist(const float* __restrict__ pitch, ll T, ll S, double ratio, char* wsb,
                       const unsigned* __restrict__ f0bits, int cached) {
  Ctrl* c = (Ctrl*)wsb;
  __shared__ int h[256];
  for (int b = threadIdx.x; b < 256; b += blockDim.x) h[b] = 0;
  __syncthreads();
  int shift = c->shift;
  unsigned pref = c->prefix;
  unsigned himask = (shift == 24) ? 0u : ((~0u) << (shift + 8));
  ll stride = (ll)gridDim.x * blockDim.x;
  for (ll t = (ll)blockIdx.x * blockDim.x + threadIdx.x; t < T; t += stride) {
    float f; unsigned bits;
    if (cached) { bits = f0bits[t]; f = __uint_as_float(bits); }
    else { f = f0_at(pitch, t, S, ratio); bits = __float_as_uint(f); }
    if (f > 0.0f) {
      if ((bits & himask) == (pref & himask)) atomicAdd(&h[(bits >> shift) & 255], 1);
    }
  }
  __syncthreads();
  for (int b = threadIdx.x; b < 256; b += blockDim.x) if (h[b]) atomicAdd(&c->hist[b], h[b]);
}

__global__ void k_sel(char* wsb, const float* ps, const float* pr) {
  Ctrl* c = (Ctrl*)wsb;
  int shift = c->shift;
  ll k = c->k_rem;
  ll run = 0; int pick = 255;
  for (int b = 0; b < 256; ++b) {
    ll h = (ll)c->hist[b];
    if (run + h > k) { pick = b; break; }
    run += h;
  }
  c->prefix |= ((unsigned)pick) << shift;
  c->k_rem = k - run;
  for (int b = 0; b < 256; ++b) c->hist[b] = 0;
  if (shift == 0) {
    float mraw = __uint_as_float(c->prefix);
    c->median_raw = mraw;
    double md = dmul((double)mraw, c->ps64);
    float md32 = (float)md;
    c->md32 = md32;
    float minf = __uint_as_float(c->minf0_bits);
    float u = fmul(minf, ps[0]);
    float sc = fadd(md32, fmul(fsub(u, md32), pr[0]));
    c->minv_scaled32 = sc;
    c->max_w = 20000.0 / (double)sc;
  }
  c->shift = shift - 8;
}

#define WALK_MAXI 400000
#define WPS 1664

// One wave per chain; pipelined register staging; LDS pitch slab for f0;
// Markstein divisions; butterfly argmax.
__global__ __launch_bounds__(64) void k_walks(const float* __restrict__ snd,
                                              const float* __restrict__ pitch,
                                              ll T, ll S, double ratio, char* wsb) {
  Ctrl* c = (Ctrl*)wsb;
  int chain = blockIdx.x;
  int reg = chain >> 1, dir = chain & 1;  // dir 0 = left walk, 1 = right walk
  if (reg >= c->nregions) return;
  int* mybuf = ((int*)(wsb + CHAINS_OFF)) + (ll)chain * MAXCHAIN;
  ll left = (ll)c->region_start[reg];
  ll right = (ll)c->region_end[reg];
  float mean = c->mean32;
  double gpeak = c->gpeak;
  int lane = threadIdx.x;

  __shared__ float lx[640];     // staged mean-subtracted window
  __shared__ float ltm[272];    // normalized template
  __shared__ float lpitch[WPS]; // pitch frames for this region

  // stage pitch frames covering f0 reads at t in [left, right]
  ll tA = left - 600; if (tA < 0) tA = 0;
  ll tB = right + 600; if (tB > T - 1) tB = T - 1;
  ll p0l = frame_lo(tA, S, ratio);
  ll p1l = frame_lo(tB, S, ratio) + 1; if (p1l > S - 1) p1l = S - 1;
  int p0 = (int)p0l, p1 = (int)p1l;
  int span = p1 - p0 + 1;
  bool puse = (span <= WPS);
  if (puse) {
    for (int k = lane; k < span; k += 64) lpitch[k] = pitch[p0 + k];
  } else { p0 = 0; p1 = -1; }  // force global fallback inside f0_lds
  __syncthreads();

  // initial position (all lanes redundantly; identical deterministic arithmetic)
  ll i;
  {
    ll middle = (left + right) / 2;
    float f0m = f0_lds(lpitch, p0, p1, pitch, middle, S, ratio);
    int w0 = (int)(16000.0 / (double)f0m);
    ll s0 = middle - (ll)(w0 / 2); if (s0 < 0) s0 = 0;
    ll len = T - s0; if (len > (ll)w0) len = (ll)w0;
    float mn = 0.f, mx = 0.f; ll imn = 0, imx = 0; bool first = true;
    for (ll k = 0; k < len; ++k) {
      float v = xval(snd, mean, s0 + k);
      if (first) { mn = mx = v; imn = imx = 0; first = false; }
      else {
        if (v < mn) { mn = v; imn = k; }
        if (v > mx) { mx = v; imx = k; }
      }
    }
    if (mn == mx) i = middle;
    else i = s0 + ((fabs((double)mn) > fabs((double)mx)) ? imn : imx);
  }

  double added_right = -1e308;
  int cnt = 0;
  bool stop = false;

  for (int iter = 0; iter < WALK_MAXI && !stop; ++iter) {
    float f0v = f0_lds(lpitch, p0, p1, pitch, i, S, ratio);
    int w = (int)(16000.0 / fmax((double)f0v, 60.0));  // <= 266
    ll cl, cr;
    if (dir == 0) {
      cl = (ll)dsub((double)i, dmul(1.75, (double)w)); if (cl < 0) cl = 0;
      cr = (ll)dsub((double)i, dmul(1.3, (double)w)); if (cr < 0) cr = 0;
    } else {
      cl = (ll)dadd((double)i, dmul(0.3, (double)w));
      cr = (ll)dadd((double)i, dmul(0.75, (double)w));
    }
    ll s = i - (ll)(w / 2); if (s < 0) s = 0;
    bool valid = !(cl == cr || (T - cl) < (ll)w || (s + (ll)w) > T);
    double corrd; ll ipos; double peakd;
    if (!valid) { corrd = -1.0; ipos = i; peakd = 0.0; }
    else {
      ll L = cr + (ll)w; if (L > T) L = T; L -= cl;
      int ncand = (int)(L - (ll)w + 1);           // 1..121
      // stage window [lo, hi) into LDS, mean-subtracted; len <= 599
      ll lo = (s < cl) ? s : cl;
      ll hiA = s + (ll)w;
      ll hiB = cl + L;
      ll hi = (hiA > hiB) ? hiA : hiB;
      int len = (int)(hi - lo);
      // phase 1: issue all loads (pipelined; clamped addresses stay in-bounds)
      float stg[10];
      #pragma unroll
      for (int j = 0; j < 10; ++j) {
        ll a = lo + (ll)(j * 64) + lane;
        if (a > T - 1) a = T - 1;
        stg[j] = snd[a];
      }
      __syncthreads();  // guard vs previous iteration's LDS reads
      // phase 2: write to LDS (single drain for all loads)
      #pragma unroll
      for (int j = 0; j < 10; ++j) {
        int k = j * 64 + lane;
        if (k < len) lx[k] = fsub(stg[j], mean);
      }
      __syncthreads();
      int toff = (int)(s - lo);
      int coff = (int)(cl - lo);
      // template norm (all lanes redundantly; LDS broadcast reads)
      float dummy = 0.0f;
      float tn = __fsqrt_rn(pw_sq_pk_l(lx, toff, w, dummy));
      float tdiv = (float)fmax((double)tn, 1e-12);
      float rt = __fdiv_rn(1.0f, tdiv);
      // normalized template -> LDS (Markstein division == __fdiv_rn bitwise)
      for (int k = lane; k < w; k += 64) ltm[k] = div_exact(lx[toff + k], tdiv, rt);
      __syncthreads();
      // candidate slot 0: r = lane (clamped keeps all lanes in-bounds)
      int r0 = lane;
      int rc0 = (r0 < ncand) ? r0 : (ncand - 1);
      float pk0 = 0.0f;
      float nr0 = __fsqrt_rn(pw_sq_pk_l(lx, coff + rc0, w, pk0));
      float divr0 = fmaxf(nr0, (float)1e-12);
      float rr0 = __fdiv_rn(1.0f, divr0);
      float co0 = dot_lds(lx, coff + rc0, divr0, rr0, ltm, w);
      // candidate slot 1 (uniform branch)
      float pk1 = 0.0f, co1 = -INFINITY;
      if (ncand > 64) {
        int r1 = lane + 64;
        int rc1 = (r1 < ncand) ? r1 : (ncand - 1);
        float nr1 = __fsqrt_rn(pw_sq_pk_l(lx, coff + rc1, w, pk1));
        float divr1 = fmaxf(nr1, (float)1e-12);
        float rr1 = __fdiv_rn(1.0f, divr1);
        co1 = dot_lds(lx, coff + rc1, divr1, rr1, ltm, w);
        if (r1 >= ncand) co1 = -INFINITY;
      }
      // fold slots (prefer higher corr; ties -> lower index)
      float bv = (r0 < ncand) ? co0 : -INFINITY;
      int bi = (r0 < ncand) ? r0 : 0x7FFFFFFF;
      {
        int i1 = lane + 64;
        if (co1 > bv || (co1 == bv && i1 < bi)) { bv = co1; bi = i1; }
      }
      // butterfly argmax (first-occurrence tie-break, matches serial scan)
      for (int off = 32; off > 0; off >>= 1) {
        float ov = __shfl_xor(bv, off);
        int oi = __shfl_xor(bi, off);
        if (ov > bv || (ov == bv && oi < bi)) { bv = ov; bi = oi; }
      }
      corrd = (double)bv;
      ipos = i + ((ll)bi + cl) - s;
      {
        int ol = bi & 63;
        float p0f = __shfl(pk0, ol);
        float p1f = __shfl(pk1, ol);
        peakd = (double)((bi < 64) ? p0f : p1f);
      }
    }
    // decision (all lanes redundantly; lane 0 writes)
    ll inew;
    if (dir == 0) {
      inew = (corrd == -1.0) ? (i - (ll)w) : ipos;
      if (inew < left) {
        if (corrd > 0.7 && peakd > dmul(0.023333, gpeak) &&
            (dsub((double)inew, added_right) > dmul(0.8, (double)w))) {
          if (cnt < MAXCHAIN) { if (lane == 0) mybuf[cnt] = (int)inew; ++cnt; }
        }
        stop = true;
      } else {
        if (corrd > 0.3 && (peakd == 0.0 || peakd > dmul(0.01, gpeak))) {
          if (dsub((double)inew, added_right) > dmul(0.8, (double)w)) {
            if (cnt < MAXCHAIN) { if (lane == 0) mybuf[cnt] = (int)inew; ++cnt; }
          }
        }
        i = inew;
      }
    } else {
      inew = (corrd == -1.0) ? (i + (ll)w) : ipos;
      if (inew >= right) {
        if (corrd > 0.7 && peakd > dmul(0.023333, gpeak)) {
          if (cnt < MAXCHAIN) { if (lane == 0) mybuf[cnt] = (int)inew; ++cnt; }
        }
        stop = true;
      } else {
        if (corrd > 0.3 && (peakd == 0.0 || peakd > dmul(0.01, gpeak))) {
          if (cnt < MAXCHAIN) { if (lane == 0) mybuf[cnt] = (int)inew; ++cnt; }
          added_right = (double)inew;
        }
        i = inew;
      }
    }
  }
  if (lane == 0) c->chain_cnt[chain] = cnt;
}

__global__ void k_offsets(char* wsb) {
  Ctrl* c = (Ctrl*)wsb;
  int off = 0;
  for (int ch = 0; ch < 128; ++ch) {
    c->chain_off[ch] = off;
    off += c->chain_cnt[ch];
  }
  c->chain_off[128] = off;
  c->n_peaks = (off > MAXP) ? MAXP : off;
}

__global__ void k_gather(char* wsb, ll T) {
  Ctrl* c = (Ctrl*)wsb;
  int chain = blockIdx.x;
  int cnt = c->chain_cnt[chain];
  int off = c->chain_off[chain];
  const int* mybuf = ((const int*)(wsb + CHAINS_OFF)) + (ll)chain * MAXCHAIN;
  int* peaks = (int*)(wsb + PEAKS_OFF);
  int dir = chain & 1;
  for (int k = threadIdx.x; k < cnt; k += blockDim.x) {
    if (off + k < MAXP) {
      int v = dir ? mybuf[k] : mybuf[cnt - 1 - k];  // left chains stored descending
      if (v < 0) v = 0;
      if ((ll)v > T - 1) v = (int)(T - 1);
      peaks[off + k] = v;
    }
  }
}

#define PSLDS 3584
#define PPS 2048

__global__ __launch_bounds__(64) void k_psola(const float* __restrict__ pitch, ll T, ll S,
                                              double ratio, char* wsb,
                                              const float* ps, const float* pr) {
  Ctrl* c = (Ctrl*)wsb;
  int r = blockIdx.x;
  if (r >= c->nregions) return;
  const int* peaks = (const int*)(wsb + PEAKS_OFF);
  int np = c->n_peaks;
  int tid = threadIdx.x;
  ll left = (ll)c->region_start[r], right = (ll)c->region_end[r];

  __shared__ int lp[PSLDS];
  __shared__ float lpitch[PPS];
  __shared__ int sh_g0, sh_g1, sh_use;

  // stage pitch frames for f0 reads at lv in [left, right)
  ll tA = left - 600; if (tA < 0) tA = 0;
  ll tB = right + 600; if (tB > T - 1) tB = T - 1;
  ll p0l = frame_lo(tA, S, ratio);
  ll p1l = frame_lo(tB, S, ratio) + 1; if (p1l > S - 1) p1l = S - 1;
  int p0 = (int)p0l, p1 = (int)p1l;
  int span = p1 - p0 + 1;
  if (span <= PPS) {
    for (int k = tid; k < span; k += 64) lpitch[k] = pitch[p0 + k];
  } else { p0 = 0; p1 = -1; }

  if (np > 0) {
    if (tid == 0) {
      int lo = 0, hi = np;
      ll tgt = left - 512;
      while (lo < hi) { int m = (lo + hi) >> 1; if ((ll)peaks[m] < tgt) lo = m + 1; else hi = m; }
      int a = lo;
      lo = 0; hi = np; tgt = right + 512;
      while (lo < hi) { int m = (lo + hi) >> 1; if ((ll)peaks[m] < tgt) lo = m + 1; else hi = m; }
      int b = lo;
      a -= 4; if (a < 0) a = 0;
      b += 4; if (b > np) b = np;
      sh_g0 = a; sh_g1 = b; sh_use = (b - a <= PSLDS) ? 1 : 0;
    }
    __syncthreads();
    if (sh_use) {
      for (int k = sh_g0 + tid; k < sh_g1; k += 64) lp[k - sh_g0] = peaks[k];
    }
  }
  __syncthreads();
  if (tid != 0) return;

  int g0 = (np > 0 && sh_use) ? sh_g0 : 0;
  const int* pk = (np > 0 && sh_use) ? lp : peaks;

  int slab = c->slab;
  int4* myops = ((int4*)(wsb + OPS_OFF)) + (ll)r * slab;
  int cnt = 0;
  ll prev_end = (r == 0) ? 0 : (ll)c->region_end[r - 1];
  ll lv = left, rv = right;
  double max_w = c->max_w;
  float md32 = c->md32, psv = ps[0], prv = pr[0];

  ll gapn = lv - prev_end;
  if (gapn > 0) {
    if (cnt < slab) myops[cnt] = make_int4((int)prev_end, (int)prev_end, (int)gapn, (int)gapn);
    ++cnt;
  }
  if (np > 0) {
    int j;
    {
      int loJ = 0, hiJ = np;
      while (loJ < hiJ) {
        int mid = (loJ + hiJ) >> 1;
        if ((ll)peaks[mid] < lv) loJ = mid + 1; else hiJ = mid;
      }
      j = loJ;
    }
    for (long itc = 0; itc < 2000000 && lv < rv; ++itc) {
      float f = f0_lds(lpitch, p0, p1, pitch, lv, S, ratio);
      float u = fmul(f, psv);
      float fs = (!(u > 0.0f)) ? 0.0f : fadd(md32, fmul(fsub(u, md32), prv));
      int period = (int)(16000.0 / fmax((double)fs, 60.0));
      int lw = period / 2, rw = period / 2;
      while (j < np && (ll)pk[j - g0] < lv) ++j;
      ll dl = (j > 0) ? (lv - (ll)pk[j - 1 - g0]) : LLONG_MAX;
      ll dr = (j < np) ? ((ll)pk[j - g0] - lv) : LLONG_MAX;
      int p;
      if (dl <= dr) {
        int q = j - 1; int v = pk[q - g0];
        while (q > 0 && pk[q - 1 - g0] == v) --q;
        p = q;
      } else {
        int q = j; int v = pk[q - g0];
        while (q > 0 && pk[q - 1 - g0] == v) --q;
        p = q;
      }
      if (p > 0) {
        ll g = (ll)pk[p - g0] - (ll)pk[p - 1 - g0];
        if ((double)g <= max_w && g < (ll)lw) lw = (int)g;
      }
      if (p < np - 1) {
        ll g = (ll)pk[p + 1 - g0] - (ll)pk[p - g0];
        if ((double)g <= max_w && g < (ll)rw) rw = (int)g;
      }
      ll li = (ll)pk[p - g0] - (ll)lw; if (li < 0) li = 0;
      ll ri = (ll)pk[p - g0] + (ll)rw;
      ll ival = (ri - li) / 2;
      if (ival <= 0) { lv += (period > 1 ? (ll)period : 1); continue; }
      ll a = lv - ival, b = lv + ival;
      ll st = (a < 0) ? ((a + T > 0) ? a + T : 0) : ((a < T) ? a : T);
      ll sp = (b < 0) ? ((b + T > 0) ? b + T : 0) : ((b < T) ? b : T);
      ll dst_len = sp - st; if (dst_len < 0) dst_len = 0;
      ll se = li + 2 * ival; if (se > T) se = T;
      ll src_len = se - li; if (src_len < 0) src_len = 0;
      ll seglen = dst_len < src_len ? dst_len : src_len;
      if (seglen > 0) {
        if (cnt < slab) myops[cnt] = make_int4((int)st, (int)li, (int)seglen, (int)(2 * ival));
        ++cnt;
      }
      lv += 2 * ival;
    }
  }
  c->region_ops[r] = (cnt > slab) ? slab : cnt;
}

__global__ void k_scatter(const float* __restrict__ snd, char* wsb, float* out, ll T) {
  Ctrl* c = (Ctrl*)wsb;
  float mean = c->mean32;
  int nr = c->nregions; if (nr > MAXR) nr = MAXR;
  int slab = c->slab;
  const int4* ops = (const int4*)(wsb + OPS_OFF);
  ll total = (ll)nr * slab;
  for (ll idx = blockIdx.x; idx < total; idx += gridDim.x) {
    int r = (int)(idx / slab);
    int o = (int)(idx - (ll)r * slab);
    if (o >= c->region_ops[r]) continue;
    int4 op = ops[(ll)r * slab + o];
    ll dst = (ll)op.x, src = (ll)op.y; int n = op.z, m = op.w;
    for (int k = threadIdx.x; k < n; k += blockDim.x) {
      double ang = dmul(TWOPI, (double)k) / (double)m;
      float w32 = (float)dsub(0.5, dmul(0.5, cos(ang)));
      float val = fmul(w32, xval(snd, mean, src + k));
      atomicAdd(&out[dst + k], val);
    }
  }
}

__global__ void k_final(const float* __restrict__ snd, char* wsb, float* out, ll T) {
  Ctrl* c = (Ctrl*)wsb;
  float mean = c->mean32;
  ll tail = c->tail;
  ll stride = (ll)gridDim.x * blockDim.x;
  for (ll t = (ll)blockIdx.x * blockDim.x + threadIdx.x; t < T; t += stride)
    if (t >= tail) out[t] = xval(snd, mean, t);
}

extern "C" void kernel_launch(void* const* d_in, const int* in_sizes, int n_in,
                              void* d_out, int out_size, void* d_ws, size_t ws_size,
                              hipStream_t stream) {
  ll T = (ll)in_sizes[0];
  ll S = (ll)in_sizes[1];
  const float* snd = (const float*)d_in[0];
  const float* pitch = (const float*)d_in[1];
  const float* ps = (const float*)d_in[2];
  const float* pr = (const float*)d_in[3];
  float* out = (float*)d_out;
  char* wsb = (char*)d_ws;
  double ratio = (double)S / (double)T;

  size_t f0_need = F0_OFF + (size_t)T * 4;
  int cached = (ws_size >= f0_need) ? 1 : 0;
  unsigned* f0bits = (unsigned*)(wsb + F0_OFF);

  k_init<<<1, 256, 0, stream>>>(wsb);
  k_sum_partial<<<1024, 256, 0, stream>>>(snd, T, wsb);
  k_sum_final<<<1, 256, 0, stream>>>(wsb, T, 1024);
  if (cached) k_f0<<<2048, 256, 0, stream>>>(pitch, T, S, ratio, f0bits);
  k_scan<<<2048, 256, 0, stream>>>(snd, pitch, T, S, ratio, wsb, f0bits, cached);
  k_prep<<<1, 1, 0, stream>>>(wsb, ps);
  for (int pass = 0; pass < 4; ++pass) {
    k_hist<<<2048, 256, 0, stream>>>(pitch, T, S, ratio, wsb, f0bits, cached);
    k_sel<<<1, 1, 0, stream>>>(wsb, ps, pr);
  }
  k_walks<<<128, 64, 0, stream>>>(snd, pitch, T, S, ratio, wsb);
  k_offsets<<<1, 1, 0, stream>>>(wsb);
  k_gather<<<128, 64, 0, stream>>>(wsb, T);
  k_psola<<<64, 64, 0, stream>>>(pitch, T, S, ratio, wsb, ps, pr);
  hipMemsetAsync(d_out, 0, (size_t)out_size * sizeof(float), stream);
  k_scatter<<<8192, 128, 0, stream>>>(snd, wsb, out, T);
  k_final<<<2048, 256, 0, stream>>>(snd, wsb, out, T);
}

// Round 6
// 11711.172 us; speedup vs baseline: 2.3040x; 1.1623x over previous
//
#include <hip/hip_runtime.h>
#include <math.h>
#include <limits.h>

typedef long long ll;

#define MAXCHAIN 4096
#define MAXP 49152
#define MAXOPS 49152
#define MAXR 64
#define PART_OFF 4096
#define CHAINS_OFF 16384
#define PEAKS_OFF (CHAINS_OFF + 128 * MAXCHAIN * 4)
#define OPS_OFF (PEAKS_OFF + MAXP * 4)
#define F0_OFF (OPS_OFF + (size_t)MAXOPS * 16)

static __device__ const double TWOPI = 6.283185307179586;

struct Ctrl {
  double gpeak, max_w, ps64;
  long long k_rem, tail;
  float mean32, median_raw, md32, minv_scaled32;
  unsigned amax_bits, minf0_bits, prefix;
  int cnt_pos, shift, n_starts, n_ends, nregions, n_peaks, n_ops, slab;
  int hist[256];
  int region_start[MAXR], region_end[MAXR];
  int chain_cnt[128];
  int chain_off[129];
  int region_ops[MAXR];
};

// ---------- exact-arith helpers (no FMA contraction) ----------
__device__ __forceinline__ double dmul(double a, double b) { return __dmul_rn(a, b); }
__device__ __forceinline__ double dadd(double a, double b) { return __dadd_rn(a, b); }
__device__ __forceinline__ double dsub(double a, double b) { return __dadd_rn(a, -b); }
__device__ __forceinline__ float fmul(float a, float b) { return __fmul_rn(a, b); }
__device__ __forceinline__ float fadd(float a, float b) { return __fadd_rn(a, b); }
__device__ __forceinline__ float fsub(float a, float b) { return __fadd_rn(a, -b); }

__device__ __forceinline__ float xval(const float* snd, float mean, ll t) {
  return fsub(snd[t], mean);
}

// Markstein correctly-rounded division: r = RN(1/d) precomputed.
__device__ __forceinline__ float div_exact(float x, float d, float r) {
  float q = __fmul_rn(x, r);
  float e = __fmaf_rn(-d, q, x);
  return __fmaf_rn(e, r, q);
}

// f0 = linear interp of pitch, computed exactly as numpy (f64 ops, one f32 round)
__device__ float f0_at(const float* pitch, ll t, ll S, double ratio) {
  double pos = dsub(dmul(dadd((double)t, 0.5), ratio), 0.5);
  double hi = (double)(S - 1);
  pos = fmin(fmax(pos, 0.0), hi);
  double fl = floor(pos);
  ll lo = (ll)fl;
  if (lo < 0) lo = 0;
  if (lo > S - 1) lo = S - 1;
  ll hii = lo + 1; if (hii > S - 1) hii = S - 1;
  double frac = dsub(pos, fl);
  double om = dsub(1.0, frac);
  double v = dadd(dmul((double)pitch[lo], om), dmul((double)pitch[hii], frac));
  return (float)v;
}

// frame index used by f0 interp at time t
__device__ __forceinline__ ll frame_lo(ll t, ll S, double ratio) {
  double pos = dsub(dmul(dadd((double)t, 0.5), ratio), 0.5);
  pos = fmin(fmax(pos, 0.0), (double)(S - 1));
  ll lo = (ll)floor(pos);
  if (lo < 0) lo = 0;
  if (lo > S - 1) lo = S - 1;
  return lo;
}

// identical arithmetic to f0_at; pitch values served from LDS slab [p0..p1]
__device__ __forceinline__ float f0_lds(const float* __restrict__ lpitch, int p0, int p1,
                                        const float* __restrict__ pitch,
                                        ll t, ll S, double ratio) {
  double pos = dsub(dmul(dadd((double)t, 0.5), ratio), 0.5);
  pos = fmin(fmax(pos, 0.0), (double)(S - 1));
  double fl = floor(pos);
  ll lo = (ll)fl;
  if (lo < 0) lo = 0;
  if (lo > S - 1) lo = S - 1;
  ll hii = lo + 1; if (hii > S - 1) hii = S - 1;
  double frac = dsub(pos, fl);
  double om = dsub(1.0, frac);
  float plo = (lo >= p0 && lo <= p1) ? lpitch[(int)(lo - p0)] : pitch[lo];
  float phi = (hii >= p0 && hii <= p1) ? lpitch[(int)(hii - p0)] : pitch[hii];
  return (float)dadd(dmul((double)plo, om), dmul((double)phi, frac));
}

// ---- fused pairwise sum-of-squares for TWO same-length ranges (A: no pk, B: pk).
// Software-pipelined LDS loads; per-range arithmetic order identical to numpy's
// 8-accumulator pairwise scheme (chains independent -> fusion changes nothing).
__device__ void pw2_blk(const float* __restrict__ buf, int bA, int bB, int n,
                        float& outA, float& outB, float& pkB) {
  if (n < 8) {
    float ra = 0.f;
    for (int i = 0; i < n; ++i) { float x = buf[bA + i]; ra = fadd(ra, fmul(x, x)); }
    float rb = 0.f;
    for (int i = 0; i < n; ++i) {
      float x = buf[bB + i];
      pkB = fmaxf(pkB, fabsf(x));
      rb = fadd(rb, fmul(x, x));
    }
    outA = ra; outB = rb; return;
  }
  float ca[8], cb[8], na[8], nb[8], rA[8], rB[8];
  #pragma unroll
  for (int j = 0; j < 8; ++j) ca[j] = buf[bA + j];
  #pragma unroll
  for (int j = 0; j < 8; ++j) cb[j] = buf[bB + j];
  int lim = n - (n & 7);
  bool hn = (8 < lim);
  if (hn) {
    #pragma unroll
    for (int j = 0; j < 8; ++j) na[j] = buf[bA + 8 + j];
    #pragma unroll
    for (int j = 0; j < 8; ++j) nb[j] = buf[bB + 8 + j];
  }
  #pragma unroll
  for (int j = 0; j < 8; ++j) pkB = fmaxf(pkB, fabsf(cb[j]));
  #pragma unroll
  for (int j = 0; j < 8; ++j) rA[j] = fmul(ca[j], ca[j]);
  #pragma unroll
  for (int j = 0; j < 8; ++j) rB[j] = fmul(cb[j], cb[j]);
  for (int i = 8; i < lim; i += 8) {
    #pragma unroll
    for (int j = 0; j < 8; ++j) { ca[j] = na[j]; cb[j] = nb[j]; }
    bool hn2 = (i + 8 < lim);
    if (hn2) {
      #pragma unroll
      for (int j = 0; j < 8; ++j) na[j] = buf[bA + i + 8 + j];
      #pragma unroll
      for (int j = 0; j < 8; ++j) nb[j] = buf[bB + i + 8 + j];
    }
    #pragma unroll
    for (int j = 0; j < 8; ++j) {
      pkB = fmaxf(pkB, fabsf(cb[j]));
      rA[j] = fadd(rA[j], fmul(ca[j], ca[j]));
      rB[j] = fadd(rB[j], fmul(cb[j], cb[j]));
    }
  }
  float resA = fadd(fadd(fadd(rA[0], rA[1]), fadd(rA[2], rA[3])),
                    fadd(fadd(rA[4], rA[5]), fadd(rA[6], rA[7])));
  float resB = fadd(fadd(fadd(rB[0], rB[1]), fadd(rB[2], rB[3])),
                    fadd(fadd(rB[4], rB[5]), fadd(rB[6], rB[7])));
  for (int i = lim; i < n; ++i) {
    float xa = buf[bA + i];
    resA = fadd(resA, fmul(xa, xa));
    float xb = buf[bB + i];
    pkB = fmaxf(pkB, fabsf(xb));
    resB = fadd(resB, fmul(xb, xb));
  }
  outA = resA; outB = resB;
}

__device__ void pw2_sq(const float* __restrict__ buf, int bA, int bB, int n,
                       float& oA, float& oB, float& pkB) {
  if (n <= 128) { pw2_blk(buf, bA, bB, n, oA, oB, pkB); return; }
  int n2 = (n >> 1); n2 -= (n2 & 7);
  float a1, b1;
  pw2_blk(buf, bA, bB, n2, a1, b1, pkB);
  int m = n - n2;
  if (m <= 128) {
    float a2, b2;
    pw2_blk(buf, bA + n2, bB + n2, m, a2, b2, pkB);
    oA = fadd(a1, a2); oB = fadd(b1, b2);
  } else {
    int m2 = (m >> 1); m2 -= (m2 & 7);
    float a2a, b2a, a2b, b2b;
    pw2_blk(buf, bA + n2, bB + n2, m2, a2a, b2a, pkB);
    pw2_blk(buf, bA + n2 + m2, bB + n2 + m2, m - m2, a2b, b2b, pkB);
    oA = fadd(a1, fadd(a2a, a2b)); oB = fadd(b1, fadd(b2a, b2b));
  }
}

// single-range pipelined pairwise sum-of-squares + pk (slot-1 candidate norm)
__device__ float pw1_blk(const float* __restrict__ buf, int base, int n, float& pk) {
  if (n < 8) {
    float res = 0.0f;
    for (int i = 0; i < n; ++i) {
      float x = buf[base + i];
      pk = fmaxf(pk, fabsf(x));
      res = fadd(res, fmul(x, x));
    }
    return res;
  }
  float cb[8], nb[8], rB[8];
  #pragma unroll
  for (int j = 0; j < 8; ++j) cb[j] = buf[base + j];
  int lim = n - (n & 7);
  bool hn = (8 < lim);
  if (hn) {
    #pragma unroll
    for (int j = 0; j < 8; ++j) nb[j] = buf[base + 8 + j];
  }
  #pragma unroll
  for (int j = 0; j < 8; ++j) pk = fmaxf(pk, fabsf(cb[j]));
  #pragma unroll
  for (int j = 0; j < 8; ++j) rB[j] = fmul(cb[j], cb[j]);
  for (int i = 8; i < lim; i += 8) {
    #pragma unroll
    for (int j = 0; j < 8; ++j) cb[j] = nb[j];
    bool hn2 = (i + 8 < lim);
    if (hn2) {
      #pragma unroll
      for (int j = 0; j < 8; ++j) nb[j] = buf[base + i + 8 + j];
    }
    #pragma unroll
    for (int j = 0; j < 8; ++j) {
      pk = fmaxf(pk, fabsf(cb[j]));
      rB[j] = fadd(rB[j], fmul(cb[j], cb[j]));
    }
  }
  float res = fadd(fadd(fadd(rB[0], rB[1]), fadd(rB[2], rB[3])),
                   fadd(fadd(rB[4], rB[5]), fadd(rB[6], rB[7])));
  for (int i = lim; i < n; ++i) {
    float y = buf[base + i];
    pk = fmaxf(pk, fabsf(y));
    res = fadd(res, fmul(y, y));
  }
  return res;
}

__device__ float pw1_sq(const float* __restrict__ buf, int base, int n, float& pk) {
  if (n <= 128) return pw1_blk(buf, base, n, pk);
  int n2 = (n >> 1); n2 -= (n2 & 7);
  float a = pw1_blk(buf, base, n2, pk);
  int m = n - n2;
  float b;
  if (m <= 128) {
    b = pw1_blk(buf, base + n2, m, pk);
  } else {
    int m2 = (m >> 1); m2 -= (m2 & 7);
    float b1 = pw1_blk(buf, base + n2, m2, pk);
    float b2 = pw1_blk(buf, base + n2 + m2, m - m2, pk);
    b = fadd(b1, b2);
  }
  return fadd(a, b);
}

// BLAS-sgemv mimic over LDS, software-pipelined. Markstein division.
__device__ float dot_lds(const float* __restrict__ buf, int base, float d, float r,
                         const float* __restrict__ tm, int w) {
  float acc[8];
  #pragma unroll
  for (int j = 0; j < 8; ++j) acc[j] = 0.f;
  int lim = w - (w & 7);
  if (lim > 0) {
    float cs[8], ct[8], ns[8], nt[8];
    #pragma unroll
    for (int j = 0; j < 8; ++j) cs[j] = buf[base + j];
    #pragma unroll
    for (int j = 0; j < 8; ++j) ct[j] = tm[j];
    for (int k = 0; k < lim; k += 8) {
      bool hn = (k + 8 < lim);
      if (hn) {
        #pragma unroll
        for (int j = 0; j < 8; ++j) ns[j] = buf[base + k + 8 + j];
        #pragma unroll
        for (int j = 0; j < 8; ++j) nt[j] = tm[k + 8 + j];
      }
      #pragma unroll
      for (int j = 0; j < 8; ++j)
        acc[j] = __fmaf_rn(div_exact(cs[j], d, r), ct[j], acc[j]);
      if (hn) {
        #pragma unroll
        for (int j = 0; j < 8; ++j) { cs[j] = ns[j]; ct[j] = nt[j]; }
      }
    }
  }
  #pragma unroll
  for (int j = 0; j < 7; ++j)
    if (lim + j < w)
      acc[j] = __fmaf_rn(div_exact(buf[base + lim + j], d, r), tm[lim + j], acc[j]);
  return fadd(fadd(fadd(acc[0], acc[1]), fadd(acc[2], acc[3])),
              fadd(fadd(acc[4], acc[5]), fadd(acc[6], acc[7])));
}

// ---------- kernels ----------
__global__ void k_init(char* wsb) {
  Ctrl* c = (Ctrl*)wsb;
  int t = threadIdx.x;
  for (int b = t; b < 256; b += blockDim.x) c->hist[b] = 0;
  for (int b = t; b < 128; b += blockDim.x) c->chain_cnt[b] = 0;
  for (int b = t; b < MAXR; b += blockDim.x) c->region_ops[b] = 0;
  if (t == 0) {
    c->amax_bits = 0u; c->minf0_bits = 0xFFFFFFFFu;
    c->cnt_pos = 0; c->n_starts = 0; c->n_ends = 0; c->n_ops = 0;
    c->nregions = 0; c->n_peaks = 0; c->tail = 0; c->slab = MAXOPS;
  }
}

__global__ void k_sum_partial(const float* __restrict__ snd, ll T, char* wsb) {
  __shared__ double sd[256];
  double local = 0.0;
  ll stride = (ll)gridDim.x * blockDim.x;
  for (ll t = (ll)blockIdx.x * blockDim.x + threadIdx.x; t < T; t += stride)
    local += (double)snd[t];
  sd[threadIdx.x] = local; __syncthreads();
  for (int o = 128; o > 0; o >>= 1) {
    if ((int)threadIdx.x < o) sd[threadIdx.x] += sd[threadIdx.x + o];
    __syncthreads();
  }
  if (threadIdx.x == 0) ((double*)(wsb + PART_OFF))[blockIdx.x] = sd[0];
}

__global__ void k_sum_final(char* wsb, ll T, int nparts) {
  __shared__ double sd[256];
  double local = 0.0;
  const double* p = (const double*)(wsb + PART_OFF);
  for (int i = threadIdx.x; i < nparts; i += blockDim.x) local += p[i];
  sd[threadIdx.x] = local; __syncthreads();
  for (int o = 128; o > 0; o >>= 1) {
    if ((int)threadIdx.x < o) sd[threadIdx.x] += sd[threadIdx.x + o];
    __syncthreads();
  }
  if (threadIdx.x == 0) ((Ctrl*)wsb)->mean32 = (float)(sd[0] / (double)T);
}

// cache exact f32 bits of f0 over all T (used by scan/hist bulk passes)
__global__ void k_f0(const float* __restrict__ pitch, ll T, ll S, double ratio,
                     unsigned* __restrict__ bits) {
  ll stride = (ll)gridDim.x * blockDim.x;
  for (ll t = (ll)blockIdx.x * blockDim.x + threadIdx.x; t < T; t += stride)
    bits[t] = __float_as_uint(f0_at(pitch, t, S, ratio));
}

__global__ void k_scan(const float* __restrict__ snd, const float* __restrict__ pitch,
                       ll T, ll S, double ratio, char* wsb,
                       const unsigned* __restrict__ f0bits, int cached) {
  Ctrl* c = (Ctrl*)wsb;
  float mean = c->mean32;
  __shared__ unsigned smax[256]; __shared__ unsigned smin[256]; __shared__ int scnt[256];
  unsigned mymax = 0u, mymin = 0xFFFFFFFFu; int mycnt = 0;
  ll stride = (ll)gridDim.x * blockDim.x;
  for (ll t = (ll)blockIdx.x * blockDim.x + threadIdx.x; t < T; t += stride) {
    float xv = xval(snd, mean, t);
    unsigned ab = __float_as_uint(fabsf(xv));
    if (ab > mymax) mymax = ab;
    float f = cached ? __uint_as_float(f0bits[t]) : f0_at(pitch, t, S, ratio);
    bool pos = (f > 0.0f);
    if (pos) { ++mycnt; unsigned fb = __float_as_uint(f); if (fb < mymin) mymin = fb; }
    if (t >= 1) {
      float fp = cached ? __uint_as_float(f0bits[t - 1]) : f0_at(pitch, t - 1, S, ratio);
      bool posp = (fp > 0.0f);
      if (pos && (t == 1 || !posp)) {
        int id = atomicAdd(&c->n_starts, 1);
        if (id < MAXR) c->region_start[id] = (int)t;
      }
      if (!pos && posp && (t - 1) >= 1) {
        int id = atomicAdd(&c->n_ends, 1);
        if (id < MAXR) c->region_end[id] = (int)t;
      }
    }
    if (t == T - 1 && pos) {
      int id = atomicAdd(&c->n_ends, 1);
      if (id < MAXR) c->region_end[id] = (int)T;
    }
  }
  smax[threadIdx.x] = mymax; smin[threadIdx.x] = mymin; scnt[threadIdx.x] = mycnt;
  __syncthreads();
  for (int o = 128; o > 0; o >>= 1) {
    if ((int)threadIdx.x < o) {
      if (smax[threadIdx.x + o] > smax[threadIdx.x]) smax[threadIdx.x] = smax[threadIdx.x + o];
      if (smin[threadIdx.x + o] < smin[threadIdx.x]) smin[threadIdx.x] = smin[threadIdx.x + o];
      scnt[threadIdx.x] += scnt[threadIdx.x + o];
    }
    __syncthreads();
  }
  if (threadIdx.x == 0) {
    atomicMax(&c->amax_bits, smax[0]);
    atomicMin(&c->minf0_bits, smin[0]);
    atomicAdd(&c->cnt_pos, scnt[0]);
  }
}

__global__ void k_prep(char* wsb, const float* ps) {
  Ctrl* c = (Ctrl*)wsb;
  int ns = c->n_starts; if (ns > MAXR) ns = MAXR;
  int ne = c->n_ends; if (ne > MAXR) ne = MAXR;
  for (int a = 1; a < ns; ++a) {
    int v = c->region_start[a]; int b = a - 1;
    while (b >= 0 && c->region_start[b] > v) { c->region_start[b + 1] = c->region_start[b]; --b; }
    c->region_start[b + 1] = v;
  }
  for (int a = 1; a < ne; ++a) {
    int v = c->region_end[a]; int b = a - 1;
    while (b >= 0 && c->region_end[b] > v) { c->region_end[b + 1] = c->region_end[b]; --b; }
    c->region_end[b + 1] = v;
  }
  int nr = ns < ne ? ns : ne;
  c->nregions = nr;
  c->tail = (nr > 0) ? (ll)c->region_end[nr - 1] : 0;
  c->gpeak = (double)__uint_as_float(c->amax_bits);
  ll cnt = (ll)c->cnt_pos; if (cnt < 1) cnt = 1;
  c->k_rem = (cnt - 1) / 2;
  c->prefix = 0u; c->shift = 24;
  c->slab = MAXOPS / (nr > 0 ? nr : 1);
  double p64 = (double)ps[0];
  c->ps64 = round(p64 * 1e7) / 1e7;
}

__global__ void k_hist(const float* __restrict__ pitch, ll T, ll S, double ratio, char* wsb,
                       const unsigned* __restrict__ f0bits, int cached) {
  Ctrl* c = (Ctrl*)wsb;
  __shared__ int h[256];
  for (int b = threadIdx.x; b < 256; b += blockDim.x) h[b] = 0;
  __syncthreads();
  int shift = c->shift;
  unsigned pref = c->prefix;
  unsigned himask = (shift == 24) ? 0u : ((~0u) << (shift + 8));
  ll stride = (ll)gridDim.x * blockDim.x;
  for (ll t = (ll)blockIdx.x * blockDim.x + threadIdx.x; t < T; t += stride) {
    float f; unsigned bits;
    if (cached) { bits = f0bits[t]; f = __uint_as_float(bits); }
    else { f = f0_at(pitch, t, S, ratio); bits = __float_as_uint(f); }
    if (f > 0.0f) {
      if ((bits & himask) == (pref & himask)) atomicAdd(&h[(bits >> shift) & 255], 1);
    }
  }
  __syncthreads();
  for (int b = threadIdx.x; b < 256; b += blockDim.x) if (h[b]) atomicAdd(&c->hist[b], h[b]);
}

__global__ void k_sel(char* wsb, const float* ps, const float* pr) {
  Ctrl* c = (Ctrl*)wsb;
  int shift = c->shift;
  ll k = c->k_rem;
  ll run = 0; int pick = 255;
  for (int b = 0; b < 256; ++b) {
    ll h = (ll)c->hist[b];
    if (run + h > k) { pick = b; break; }
    run += h;
  }
  c->prefix |= ((unsigned)pick) << shift;
  c->k_rem = k - run;
  for (int b = 0; b < 256; ++b) c->hist[b] = 0;
  if (shift == 0) {
    float mraw = __uint_as_float(c->prefix);
    c->median_raw = mraw;
    double md = dmul((double)mraw, c->ps64);
    float md32 = (float)md;
    c->md32 = md32;
    float minf = __uint_as_float(c->minf0_bits);
    float u = fmul(minf, ps[0]);
    float sc = fadd(md32, fmul(fsub(u, md32), pr[0]));
    c->minv_scaled32 = sc;
    c->max_w = 20000.0 / (double)sc;
  }
  c->shift = shift - 8;
}

#define WALK_MAXI 400000
#define WPS 1664

// One wave per chain; pipelined register staging; LDS pitch slab for f0;
// fused+pipelined norms; pipelined dot; Markstein divisions; butterfly argmax.
__global__ __launch_bounds__(64) void k_walks(const float* __restrict__ snd,
                                              const float* __restrict__ pitch,
                                              ll T, ll S, double ratio, char* wsb) {
  Ctrl* c = (Ctrl*)wsb;
  int chain = blockIdx.x;
  int reg = chain >> 1, dir = chain & 1;  // dir 0 = left walk, 1 = right walk
  if (reg >= c->nregions) return;
  int* mybuf = ((int*)(wsb + CHAINS_OFF)) + (ll)chain * MAXCHAIN;
  ll left = (ll)c->region_start[reg];
  ll right = (ll)c->region_end[reg];
  float mean = c->mean32;
  double gpeak = c->gpeak;
  int lane = threadIdx.x;

  __shared__ float lx[640];     // staged mean-subtracted window
  __shared__ float ltm[272];    // normalized template
  __shared__ float lpitch[WPS]; // pitch frames for this region

  // stage pitch frames covering f0 reads at t in [left, right]
  ll tA = left - 600; if (tA < 0) tA = 0;
  ll tB = right + 600; if (tB > T - 1) tB = T - 1;
  ll p0l = frame_lo(tA, S, ratio);
  ll p1l = frame_lo(tB, S, ratio) + 1; if (p1l > S - 1) p1l = S - 1;
  int p0 = (int)p0l, p1 = (int)p1l;
  int span = p1 - p0 + 1;
  bool puse = (span <= WPS);
  if (puse) {
    for (int k = lane; k < span; k += 64) lpitch[k] = pitch[p0 + k];
  } else { p0 = 0; p1 = -1; }  // force global fallback inside f0_lds
  __syncthreads();

  // initial position (all lanes redundantly; identical deterministic arithmetic)
  ll i;
  {
    ll middle = (left + right) / 2;
    float f0m = f0_lds(lpitch, p0, p1, pitch, middle, S, ratio);
    int w0 = (int)(16000.0 / (double)f0m);
    ll s0 = middle - (ll)(w0 / 2); if (s0 < 0) s0 = 0;
    ll len = T - s0; if (len > (ll)w0) len = (ll)w0;
    float mn = 0.f, mx = 0.f; ll imn = 0, imx = 0; bool first = true;
    for (ll k = 0; k < len; ++k) {
      float v = xval(snd, mean, s0 + k);
      if (first) { mn = mx = v; imn = imx = 0; first = false; }
      else {
        if (v < mn) { mn = v; imn = k; }
        if (v > mx) { mx = v; imx = k; }
      }
    }
    if (mn == mx) i = middle;
    else i = s0 + ((fabs((double)mn) > fabs((double)mx)) ? imn : imx);
  }

  double added_right = -1e308;
  int cnt = 0;
  bool stop = false;

  for (int iter = 0; iter < WALK_MAXI && !stop; ++iter) {
    float f0v = f0_lds(lpitch, p0, p1, pitch, i, S, ratio);
    int w = (int)(16000.0 / fmax((double)f0v, 60.0));  // <= 266
    ll cl, cr;
    if (dir == 0) {
      cl = (ll)dsub((double)i, dmul(1.75, (double)w)); if (cl < 0) cl = 0;
      cr = (ll)dsub((double)i, dmul(1.3, (double)w)); if (cr < 0) cr = 0;
    } else {
      cl = (ll)dadd((double)i, dmul(0.3, (double)w));
      cr = (ll)dadd((double)i, dmul(0.75, (double)w));
    }
    ll s = i - (ll)(w / 2); if (s < 0) s = 0;
    bool valid = !(cl == cr || (T - cl) < (ll)w || (s + (ll)w) > T);
    double corrd; ll ipos; double peakd;
    if (!valid) { corrd = -1.0; ipos = i; peakd = 0.0; }
    else {
      ll L = cr + (ll)w; if (L > T) L = T; L -= cl;
      int ncand = (int)(L - (ll)w + 1);           // 1..121
      // stage window [lo, hi) into LDS, mean-subtracted; len <= 599
      ll lo = (s < cl) ? s : cl;
      ll hiA = s + (ll)w;
      ll hiB = cl + L;
      ll hi = (hiA > hiB) ? hiA : hiB;
      int len = (int)(hi - lo);
      // phase 1: issue all loads (pipelined; clamped addresses stay in-bounds)
      float stg[10];
      #pragma unroll
      for (int j = 0; j < 10; ++j) {
        ll a = lo + (ll)(j * 64) + lane;
        if (a > T - 1) a = T - 1;
        stg[j] = snd[a];
      }
      __syncthreads();  // guard vs previous iteration's LDS reads
      // phase 2: write to LDS (single drain for all loads)
      #pragma unroll
      for (int j = 0; j < 10; ++j) {
        int k = j * 64 + lane;
        if (k < len) lx[k] = fsub(stg[j], mean);
      }
      __syncthreads();
      int toff = (int)(s - lo);
      int coff = (int)(cl - lo);
      // fused template norm + slot-0 candidate norm (independent chains)
      int r0 = lane;
      int rc0 = (r0 < ncand) ? r0 : (ncand - 1);
      float pk0 = 0.0f;
      float tsq, csq0;
      pw2_sq(lx, toff, coff + rc0, w, tsq, csq0, pk0);
      float tn = __fsqrt_rn(tsq);
      float tdiv = (float)fmax((double)tn, 1e-12);
      float rt = __fdiv_rn(1.0f, tdiv);
      float nr0 = __fsqrt_rn(csq0);
      float divr0 = fmaxf(nr0, (float)1e-12);
      float rr0 = __fdiv_rn(1.0f, divr0);
      // slot-1 candidate norm (independent of template; before the barrier)
      float pk1 = 0.0f, divr1 = 1.0f, rr1 = 1.0f;
      int rc1 = 0;
      bool has1 = (ncand > 64);
      if (has1) {
        int r1 = lane + 64;
        rc1 = (r1 < ncand) ? r1 : (ncand - 1);
        float nr1 = __fsqrt_rn(pw1_sq(lx, coff + rc1, w, pk1));
        divr1 = fmaxf(nr1, (float)1e-12);
        rr1 = __fdiv_rn(1.0f, divr1);
      }
      // normalized template -> LDS (Markstein division == __fdiv_rn bitwise)
      for (int k = lane; k < w; k += 64) ltm[k] = div_exact(lx[toff + k], tdiv, rt);
      __syncthreads();
      // dots
      float co0 = dot_lds(lx, coff + rc0, divr0, rr0, ltm, w);
      float co1 = -INFINITY;
      if (has1) {
        co1 = dot_lds(lx, coff + rc1, divr1, rr1, ltm, w);
        if (lane + 64 >= ncand) co1 = -INFINITY;
      }
      // fold slots (prefer higher corr; ties -> lower index)
      float bv = (r0 < ncand) ? co0 : -INFINITY;
      int bi = (r0 < ncand) ? r0 : 0x7FFFFFFF;
      {
        int i1 = lane + 64;
        if (co1 > bv || (co1 == bv && i1 < bi)) { bv = co1; bi = i1; }
      }
      // butterfly argmax (first-occurrence tie-break, matches serial scan)
      for (int off = 32; off > 0; off >>= 1) {
        float ov = __shfl_xor(bv, off);
        int oi = __shfl_xor(bi, off);
        if (ov > bv || (ov == bv && oi < bi)) { bv = ov; bi = oi; }
      }
      corrd = (double)bv;
      ipos = i + ((ll)bi + cl) - s;
      {
        int ol = bi & 63;
        float p0f = __shfl(pk0, ol);
        float p1f = __shfl(pk1, ol);
        peakd = (double)((bi < 64) ? p0f : p1f);
      }
    }
    // decision (all lanes redundantly; lane 0 writes)
    ll inew;
    if (dir == 0) {
      inew = (corrd == -1.0) ? (i - (ll)w) : ipos;
      if (inew < left) {
        if (corrd > 0.7 && peakd > dmul(0.023333, gpeak) &&
            (dsub((double)inew, added_right) > dmul(0.8, (double)w))) {
          if (cnt < MAXCHAIN) { if (lane == 0) mybuf[cnt] = (int)inew; ++cnt; }
        }
        stop = true;
      } else {
        if (corrd > 0.3 && (peakd == 0.0 || peakd > dmul(0.01, gpeak))) {
          if (dsub((double)inew, added_right) > dmul(0.8, (double)w)) {
            if (cnt < MAXCHAIN) { if (lane == 0) mybuf[cnt] = (int)inew; ++cnt; }
          }
        }
        i = inew;
      }
    } else {
      inew = (corrd == -1.0) ? (i + (ll)w) : ipos;
      if (inew >= right) {
        if (corrd > 0.7 && peakd > dmul(0.023333, gpeak)) {
          if (cnt < MAXCHAIN) { if (lane == 0) mybuf[cnt] = (int)inew; ++cnt; }
        }
        stop = true;
      } else {
        if (corrd > 0.3 && (peakd == 0.0 || peakd > dmul(0.01, gpeak))) {
          if (cnt < MAXCHAIN) { if (lane == 0) mybuf[cnt] = (int)inew; ++cnt; }
          added_right = (double)inew;
        }
        i = inew;
      }
    }
  }
  if (lane == 0) c->chain_cnt[chain] = cnt;
}

__global__ void k_offsets(char* wsb) {
  Ctrl* c = (Ctrl*)wsb;
  int off = 0;
  for (int ch = 0; ch < 128; ++ch) {
    c->chain_off[ch] = off;
    off += c->chain_cnt[ch];
  }
  c->chain_off[128] = off;
  c->n_peaks = (off > MAXP) ? MAXP : off;
}

__global__ void k_gather(char* wsb, ll T) {
  Ctrl* c = (Ctrl*)wsb;
  int chain = blockIdx.x;
  int cnt = c->chain_cnt[chain];
  int off = c->chain_off[chain];
  const int* mybuf = ((const int*)(wsb + CHAINS_OFF)) + (ll)chain * MAXCHAIN;
  int* peaks = (int*)(wsb + PEAKS_OFF);
  int dir = chain & 1;
  for (int k = threadIdx.x; k < cnt; k += blockDim.x) {
    if (off + k < MAXP) {
      int v = dir ? mybuf[k] : mybuf[cnt - 1 - k];  // left chains stored descending
      if (v < 0) v = 0;
      if ((ll)v > T - 1) v = (int)(T - 1);
      peaks[off + k] = v;
    }
  }
}

#define PSLDS 3584
#define PPS 2048

__global__ __launch_bounds__(64) void k_psola(const float* __restrict__ pitch, ll T, ll S,
                                              double ratio, char* wsb,
                                              const float* ps, const float* pr) {
  Ctrl* c = (Ctrl*)wsb;
  int r = blockIdx.x;
  if (r >= c->nregions) return;
  const int* peaks = (const int*)(wsb + PEAKS_OFF);
  int np = c->n_peaks;
  int tid = threadIdx.x;
  ll left = (ll)c->region_start[r], right = (ll)c->region_end[r];

  __shared__ int lp[PSLDS];
  __shared__ float lpitch[PPS];
  __shared__ int sh_g0, sh_g1, sh_use;

  // stage pitch frames for f0 reads at lv in [left, right)
  ll tA = left - 600; if (tA < 0) tA = 0;
  ll tB = right + 600; if (tB > T - 1) tB = T - 1;
  ll p0l = frame_lo(tA, S, ratio);
  ll p1l = frame_lo(tB, S, ratio) + 1; if (p1l > S - 1) p1l = S - 1;
  int p0 = (int)p0l, p1 = (int)p1l;
  int span = p1 - p0 + 1;
  if (span <= PPS) {
    for (int k = tid; k < span; k += 64) lpitch[k] = pitch[p0 + k];
  } else { p0 = 0; p1 = -1; }

  if (np > 0) {
    if (tid == 0) {
      int lo = 0, hi = np;
      ll tgt = left - 512;
      while (lo < hi) { int m = (lo + hi) >> 1; if ((ll)peaks[m] < tgt) lo = m + 1; else hi = m; }
      int a = lo;
      lo = 0; hi = np; tgt = right + 512;
      while (lo < hi) { int m = (lo + hi) >> 1; if ((ll)peaks[m] < tgt) lo = m + 1; else hi = m; }
      int b = lo;
      a -= 4; if (a < 0) a = 0;
      b += 4; if (b > np) b = np;
      sh_g0 = a; sh_g1 = b; sh_use = (b - a <= PSLDS) ? 1 : 0;
    }
    __syncthreads();
    if (sh_use) {
      for (int k = sh_g0 + tid; k < sh_g1; k += 64) lp[k - sh_g0] = peaks[k];
    }
  }
  __syncthreads();
  if (tid != 0) return;

  int g0 = (np > 0 && sh_use) ? sh_g0 : 0;
  const int* pk = (np > 0 && sh_use) ? lp : peaks;

  int slab = c->slab;
  int4* myops = ((int4*)(wsb + OPS_OFF)) + (ll)r * slab;
  int cnt = 0;
  ll prev_end = (r == 0) ? 0 : (ll)c->region_end[r - 1];
  ll lv = left, rv = right;
  double max_w = c->max_w;
  float md32 = c->md32, psv = ps[0], prv = pr[0];

  ll gapn = lv - prev_end;
  if (gapn > 0) {
    if (cnt < slab) myops[cnt] = make_int4((int)prev_end, (int)prev_end, (int)gapn, (int)gapn);
    ++cnt;
  }
  if (np > 0) {
    int j;
    {
      int loJ = 0, hiJ = np;
      while (loJ < hiJ) {
        int mid = (loJ + hiJ) >> 1;
        if ((ll)peaks[mid] < lv) loJ = mid + 1; else hiJ = mid;
      }
      j = loJ;
    }
    for (long itc = 0; itc < 2000000 && lv < rv; ++itc) {
      float f = f0_lds(lpitch, p0, p1, pitch, lv, S, ratio);
      float u = fmul(f, psv);
      float fs = (!(u > 0.0f)) ? 0.0f : fadd(md32, fmul(fsub(u, md32), prv));
      int period = (int)(16000.0 / fmax((double)fs, 60.0));
      int lw = period / 2, rw = period / 2;
      while (j < np && (ll)pk[j - g0] < lv) ++j;
      ll dl = (j > 0) ? (lv - (ll)pk[j - 1 - g0]) : LLONG_MAX;
      ll dr = (j < np) ? ((ll)pk[j - g0] - lv) : LLONG_MAX;
      int p;
      if (dl <= dr) {
        int q = j - 1; int v = pk[q - g0];
        while (q > 0 && pk[q - 1 - g0] == v) --q;
        p = q;
      } else {
        int q = j; int v = pk[q - g0];
        while (q > 0 && pk[q - 1 - g0] == v) --q;
        p = q;
      }
      if (p > 0) {
        ll g = (ll)pk[p - g0] - (ll)pk[p - 1 - g0];
        if ((double)g <= max_w && g < (ll)lw) lw = (int)g;
      }
      if (p < np - 1) {
        ll g = (ll)pk[p + 1 - g0] - (ll)pk[p - g0];
        if ((double)g <= max_w && g < (ll)rw) rw = (int)g;
      }
      ll li = (ll)pk[p - g0] - (ll)lw; if (li < 0) li = 0;
      ll ri = (ll)pk[p - g0] + (ll)rw;
      ll ival = (ri - li) / 2;
      if (ival <= 0) { lv += (period > 1 ? (ll)period : 1); continue; }
      ll a = lv - ival, b = lv + ival;
      ll st = (a < 0) ? ((a + T > 0) ? a + T : 0) : ((a < T) ? a : T);
      ll sp = (b < 0) ? ((b + T > 0) ? b + T : 0) : ((b < T) ? b : T);
      ll dst_len = sp - st; if (dst_len < 0) dst_len = 0;
      ll se = li + 2 * ival; if (se > T) se = T;
      ll src_len = se - li; if (src_len < 0) src_len = 0;
      ll seglen = dst_len < src_len ? dst_len : src_len;
      if (seglen > 0) {
        if (cnt < slab) myops[cnt] = make_int4((int)st, (int)li, (int)seglen, (int)(2 * ival));
        ++cnt;
      }
      lv += 2 * ival;
    }
  }
  c->region_ops[r] = (cnt > slab) ? slab : cnt;
}

__global__ void k_scatter(const float* __restrict__ snd, char* wsb, float* out, ll T) {
  Ctrl* c = (Ctrl*)wsb;
  float mean = c->mean32;
  int nr = c->nregions; if (nr > MAXR) nr = MAXR;
  int slab = c->slab;
  const int4* ops = (const int4*)(wsb + OPS_OFF);
  ll total = (ll)nr * slab;
  for (ll idx = blockIdx.x; idx < total; idx += gridDim.x) {
    int r = (int)(idx / slab);
    int o = (int)(idx - (ll)r * slab);
    if (o >= c->region_ops[r]) continue;
    int4 op = ops[(ll)r * slab + o];
    ll dst = (ll)op.x, src = (ll)op.y; int n = op.z, m = op.w;
    for (int k = threadIdx.x; k < n; k += blockDim.x) {
      double ang = dmul(TWOPI, (double)k) / (double)m;
      float w32 = (float)dsub(0.5, dmul(0.5, cos(ang)));
      float val = fmul(w32, xval(snd, mean, src + k));
      atomicAdd(&out[dst + k], val);
    }
  }
}

__global__ void k_final(const float* __restrict__ snd, char* wsb, float* out, ll T) {
  Ctrl* c = (Ctrl*)wsb;
  float mean = c->mean32;
  ll tail = c->tail;
  ll stride = (ll)gridDim.x * blockDim.x;
  for (ll t = (ll)blockIdx.x * blockDim.x + threadIdx.x; t < T; t += stride)
    if (t >= tail) out[t] = xval(snd, mean, t);
}

extern "C" void kernel_launch(void* const* d_in, const int* in_sizes, int n_in,
                              void* d_out, int out_size, void* d_ws, size_t ws_size,
                              hipStream_t stream) {
  ll T = (ll)in_sizes[0];
  ll S = (ll)in_sizes[1];
  const float* snd = (const float*)d_in[0];
  const float* pitch = (const float*)d_in[1];
  const float* ps = (const float*)d_in[2];
  const float* pr = (const float*)d_in[3];
  float* out = (float*)d_out;
  char* wsb = (char*)d_ws;
  double ratio = (double)S / (double)T;

  size_t f0_need = F0_OFF + (size_t)T * 4;
  int cached = (ws_size >= f0_need) ? 1 : 0;
  unsigned* f0bits = (unsigned*)(wsb + F0_OFF);

  k_init<<<1, 256, 0, stream>>>(wsb);
  k_sum_partial<<<1024, 256, 0, stream>>>(snd, T, wsb);
  k_sum_final<<<1, 256, 0, stream>>>(wsb, T, 1024);
  if (cached) k_f0<<<2048, 256, 0, stream>>>(pitch, T, S, ratio, f0bits);
  k_scan<<<2048, 256, 0, stream>>>(snd, pitch, T, S, ratio, wsb, f0bits, cached);
  k_prep<<<1, 1, 0, stream>>>(wsb, ps);
  for (int pass = 0; pass < 4; ++pass) {
    k_hist<<<2048, 256, 0, stream>>>(pitch, T, S, ratio, wsb, f0bits, cached);
    k_sel<<<1, 1, 0, stream>>>(wsb, ps, pr);
  }
  k_walks<<<128, 64, 0, stream>>>(snd, pitch, T, S, ratio, wsb);
  k_offsets<<<1, 1, 0, stream>>>(wsb);
  k_gather<<<128, 64, 0, stream>>>(wsb, T);
  k_psola<<<64, 64, 0, stream>>>(pitch, T, S, ratio, wsb, ps, pr);
  hipMemsetAsync(d_out, 0, (size_t)out_size * sizeof(float), stream);
  k_scatter<<<8192, 128, 0, stream>>>(snd, wsb, out, T);
  k_final<<<2048, 256, 0, stream>>>(snd, wsb, out, T);
}